// Round 3
// baseline (50861.255 us; speedup 1.0000x reference)
//
#include <hip/hip_runtime.h>
#include <stdint.h>
#include <math.h>

typedef unsigned int u32;
typedef _Float16 f16;
typedef _Float16 h4 __attribute__((ext_vector_type(4)));
typedef _Float16 h2 __attribute__((ext_vector_type(2)));

// Problem constants
#define Vn     50000
#define DEMBn  200
#define Hn     150
#define NCn    119
#define NAn    103
#define NTn    11
#define Bn     32
#define Tn     512
#define LCn    50
#define LVn    50
#define ECn    600
#define EAn    500

__device__ __forceinline__ float sigm(float x){ return 1.0f / (1.0f + expf(-x)); }

// ---------------------------------------------------------------------------
// Tiled fp32 GEMM: C[M][N] = A[M][K] @ B[N][K]^T (+bias +rowbias)
// AMODE 0: A = up to 3 f32 sources, each [M][300]; source s = k/300;
//          B column for element k is bc[s] + (k - s*300)
// AMODE 1: A[m][k] = Etab[tok[m]][k] (f32 embedding gather), B col = k
// ---------------------------------------------------------------------------
template<int AMODE>
__global__ __launch_bounds__(256)
void gemm_k(const float* A0, const float* A1, const float* A2,
            const float* Etab, const int* tok,
            const float* Bm, int ldb, int bc0, int bc1, int bc2,
            const float* bias, const float* rowbias, int rb_div, int rb_stride,
            float* C, int M, int N, int K)
{
  __shared__ float As[8][132];
  __shared__ float Bs[8][132];
  __shared__ int tokS[128];
  int tid = threadIdx.x;
  int m0 = blockIdx.y * 128, n0 = blockIdx.x * 128;
  if (AMODE == 1){
    for (int i = tid; i < 128; i += 256){
      int m = m0 + i;
      tokS[i] = (m < M) ? tok[m] : 0;
    }
  }
  __syncthreads();
  float acc[8][8];
  #pragma unroll
  for (int i=0;i<8;i++)
    #pragma unroll
    for (int j=0;j<8;j++) acc[i][j] = 0.f;

  int tx = tid & 15, ty = tid >> 4;

  for (int k0 = 0; k0 < K; k0 += 8){
    #pragma unroll
    for (int r = 0; r < 4; r++){
      int i = tid + 256*r;          // [0,1024)
      int ml = i >> 3, kl = i & 7;
      int k = k0 + kl;
      {
        int m = m0 + ml;
        float v = 0.f;
        if (m < M && k < K){
          if (AMODE == 0){
            int s = k / 300; int kk = k - s*300;
            const float* Ap = (s==0) ? A0 : ((s==1) ? A1 : A2);
            v = Ap[(size_t)m*300 + kk];
          } else {
            v = Etab[(size_t)tokS[ml]*DEMBn + k];
          }
        }
        As[kl][ml] = v;
      }
      {
        int n = n0 + ml;
        float v = 0.f;
        if (n < N && k < K){
          int col;
          if (AMODE == 0){ int s = k / 300; int kk = k - s*300; col = ((s==0)?bc0:((s==1)?bc1:bc2)) + kk; }
          else col = k;
          v = Bm[(size_t)n*ldb + col];
        }
        Bs[kl][ml] = v;
      }
    }
    __syncthreads();
    #pragma unroll
    for (int kk = 0; kk < 8; kk++){
      float a[8], b[8];
      #pragma unroll
      for (int i=0;i<8;i++) a[i] = As[kk][ty*8+i];
      #pragma unroll
      for (int i=0;i<8;i++) b[i] = Bs[kk][tx*8+i];
      #pragma unroll
      for (int i=0;i<8;i++)
        #pragma unroll
        for (int j=0;j<8;j++) acc[i][j] += a[i]*b[j];
    }
    __syncthreads();
  }
  #pragma unroll
  for (int i=0;i<8;i++){
    int m = m0 + ty*8 + i; if (m >= M) continue;
    #pragma unroll
    for (int j=0;j<8;j++){
      int n = n0 + tx*8 + j; if (n >= N) continue;
      float v = acc[i][j];
      if (bias)    v += bias[n];
      if (rowbias) v += rowbias[(size_t)(m / rb_div)*rb_stride + n];
      C[(size_t)m*N + n] = v;
    }
  }
}

// ---------------------------------------------------------------------------
// Small-GRU recurrence (H=150): one block per (seq, dir). Whh f16 in LDS
// (weights ~N(0,0.08): f16 exact-range, rel err 2^-11).
// ---------------------------------------------------------------------------
__global__ __launch_bounds__(192)
void gru_small_k(const float* xs, int ncols,
                 const float* Whh, const float* bhh,
                 float* ys, float* meanOut, int T)
{
  const int KP = 156;
  __shared__ f16 Wl[3*150*156];     // 140,400 B
  __shared__ float bhl[456];
  __shared__ __align__(16) float hl[152];
  int tid = threadIdx.x;
  int seq = blockIdx.x, dir = blockIdx.y;

  for (int idx = tid; idx < 3*150*150; idx += 192){
    int g = idx / 22500, r = idx % 22500;
    int j = r / 150, k = r % 150;
    Wl[(g*150 + j)*KP + k] = (f16)Whh[(size_t)dir*67500 + idx];
  }
  for (int idx = tid; idx < 450; idx += 192) bhl[idx] = bhh[dir*450 + idx];
  if (tid < 152) hl[tid] = 0.f;
  __syncthreads();

  const f16 *wr = nullptr, *wz = nullptr, *wn = nullptr;
  float bR=0.f, bZ=0.f, bN=0.f;
  if (tid < 150){
    wr = &Wl[(0*150+tid)*KP];
    wz = &Wl[(1*150+tid)*KP];
    wn = &Wl[(2*150+tid)*KP];
    bR = bhl[tid]; bZ = bhl[150+tid]; bN = bhl[300+tid];
  }
  float msum = 0.f;
  size_t rowbase = (size_t)seq * T;
  for (int tt = 0; tt < T; tt++){
    int t = dir ? (T-1-tt) : tt;
    float aR=0.f, aZ=0.f, aN=0.f;
    if (tid < 150){
      for (int k = 0; k < 148; k += 4){
        float4 hv = *(const float4*)(hl + k);
        h4 r4 = *(const h4*)(wr + k);
        h4 z4 = *(const h4*)(wz + k);
        h4 n4 = *(const h4*)(wn + k);
        aR += (float)r4.x*hv.x + (float)r4.y*hv.y + (float)r4.z*hv.z + (float)r4.w*hv.w;
        aZ += (float)z4.x*hv.x + (float)z4.y*hv.y + (float)z4.z*hv.z + (float)z4.w*hv.w;
        aN += (float)n4.x*hv.x + (float)n4.y*hv.y + (float)n4.z*hv.z + (float)n4.w*hv.w;
      }
      {
        float2 hv = *(const float2*)(hl + 148);
        h2 r2 = *(const h2*)(wr + 148);
        h2 z2 = *(const h2*)(wz + 148);
        h2 n2 = *(const h2*)(wn + 148);
        aR += (float)r2.x*hv.x + (float)r2.y*hv.y;
        aZ += (float)z2.x*hv.x + (float)z2.y*hv.y;
        aN += (float)n2.x*hv.x + (float)n2.y*hv.y;
      }
    }
    __syncthreads();           // all reads of hl done
    if (tid < 150){
      const float* xp = xs + (rowbase + t)*(size_t)ncols + dir*450;
      float xr = xp[tid], xz = xp[150+tid], xn = xp[300+tid];
      float rr = sigm(xr + aR + bR);
      float zz = sigm(xz + aZ + bZ);
      float nn = tanhf(xn + rr*(aN + bN));
      float hn = (1.f - zz)*nn + zz*hl[tid];
      hl[tid] = hn;
      msum += hn;
      if (ys) ys[(rowbase + t)*(size_t)300 + dir*150 + tid] = hn;
    }
    __syncthreads();
  }
  if (meanOut && tid < 150)
    meanOut[(size_t)seq*300 + dir*150 + tid] = msum / (float)T;
}

// ---------------------------------------------------------------------------
// Big-GRU recurrence, ONE direction per launch. Grid (NJC, 8):
// block owns JB h-indices x 4 batch elems; W chunk f16 in LDS (155,104 B
// total -> 1 block/CU, <=120 blocks co-resident). KQ=4 k-partials reduced
// via quad shuffles (tid = cj*4 + ckq). Per-step group barrier via
// agent-scope atomics among the NJC blocks sharing bg; bounded spin.
// ---------------------------------------------------------------------------
__global__ __launch_bounds__(192)
void gru_big_k(const float* xs,          // per-dir xs [B*T][3*Hh]
               const float* Whh,         // per-dir [3*Hh][Hh]
               const float* bhh,         // per-dir [3*Hh]
               float* hbuf,              // [2][B][Hh], zeroed before launch
               float* meanOut, int mean_stride,   // pre-offset by dir*Hh
               u32* counters,            // 8 per launch (one per bg), zeroed
               int T, int Hh, int JB, int KPAD, int NJC, int HS, int reverse)
{
  __shared__ f16 Wl[72480];                 // 144,960 B (art: 3*40*604)
  __shared__ float bhl[136];
  __shared__ __align__(16) float hstage[2400];
  int tid = threadIdx.x;
  int jc = blockIdx.x, bg = blockIdx.y;
  int j0 = jc * JB;
  int H3 = 3 * Hh;

  for (int idx = tid; idx < 3*JB*Hh; idx += 192){
    int row = idx / Hh, k = idx - row*Hh;
    int g = row / JB, jj = row - g*JB;
    Wl[row*KPAD + k] = (f16)Whh[((size_t)g*Hh + j0 + jj)*(size_t)Hh + k];
  }
  for (int idx = tid; idx < 3*JB; idx += 192){
    int g = idx / JB, jj = idx - g*JB;
    bhl[idx] = bhh[g*Hh + j0 + jj];
  }
  __syncthreads();

  u32* cnt = counters + bg;
  int cj = tid >> 2, ckq = tid & 3;
  bool comp = (cj < JB);
  int k0 = 0, k1 = 0;
  if (comp){
    k0 = (ckq == 0) ? 0 : ((ckq*Hh/4) & ~3);
    k1 = (ckq == 3) ? Hh : ((((ckq+1)*Hh)/4) & ~3);
  }
  float br = 0.f, bz = 0.f, bn_ = 0.f;
  if (comp && ckq == 0){
    br = bhl[cj]; bz = bhl[JB+cj]; bn_ = bhl[2*JB+cj];
  }
  float msum[4] = {0.f, 0.f, 0.f, 0.f};

  for (int tt = 0; tt < T; tt++){
    int t = reverse ? (T-1-tt) : tt;
    int par = tt & 1;
    const float* hrd = hbuf + (size_t)par*Bn*Hh;
    float*       hwr = hbuf + (size_t)(1-par)*Bn*Hh;
    for (int idx = tid; idx < 4*Hh; idx += 192){
      int s = idx / Hh, k = idx - s*Hh;
      hstage[s*HS + k] = hrd[(size_t)(bg*4 + s)*Hh + k];
    }
    __syncthreads();
    float a0[4] = {0,0,0,0}, a1[4] = {0,0,0,0}, a2[4] = {0,0,0,0};
    if (comp){
      const f16* pr = &Wl[(0*JB+cj)*KPAD];
      const f16* pz = &Wl[(1*JB+cj)*KPAD];
      const f16* pn = &Wl[(2*JB+cj)*KPAD];
      int k = k0;
      for (; k + 4 <= k1; k += 4){
        h4 r4 = *(const h4*)(pr + k);
        h4 z4 = *(const h4*)(pz + k);
        h4 n4 = *(const h4*)(pn + k);
        float wr0=(float)r4.x, wr1=(float)r4.y, wr2=(float)r4.z, wr3=(float)r4.w;
        float wz0=(float)z4.x, wz1=(float)z4.y, wz2=(float)z4.z, wz3=(float)z4.w;
        float wn0=(float)n4.x, wn1=(float)n4.y, wn2=(float)n4.z, wn3=(float)n4.w;
        #pragma unroll
        for (int s=0;s<4;s++){
          float4 hv = *(const float4*)(hstage + s*HS + k);
          a0[s] += wr0*hv.x + wr1*hv.y + wr2*hv.z + wr3*hv.w;
          a1[s] += wz0*hv.x + wz1*hv.y + wz2*hv.z + wz3*hv.w;
          a2[s] += wn0*hv.x + wn1*hv.y + wn2*hv.z + wn3*hv.w;
        }
      }
      for (; k < k1; k++){
        float wr0=(float)pr[k], wz0=(float)pz[k], wn0=(float)pn[k];
        #pragma unroll
        for (int s=0;s<4;s++){
          float hv = hstage[s*HS + k];
          a0[s] += wr0*hv; a1[s] += wz0*hv; a2[s] += wn0*hv;
        }
      }
    }
    // quad reduction over ckq lanes (quads never straddle waves)
    #pragma unroll
    for (int s=0;s<4;s++){
      a0[s] += __shfl_xor(a0[s], 1); a0[s] += __shfl_xor(a0[s], 2);
      a1[s] += __shfl_xor(a1[s], 1); a1[s] += __shfl_xor(a1[s], 2);
      a2[s] += __shfl_xor(a2[s], 1); a2[s] += __shfl_xor(a2[s], 2);
    }
    if (comp && ckq == 0){
      int jg = j0 + cj;
      #pragma unroll
      for (int s=0;s<4;s++){
        int b = bg*4 + s;
        const float* xp = xs + ((size_t)b*T + t)*(size_t)H3;
        float xr = xp[jg], xz = xp[Hh+jg], xn = xp[2*Hh+jg];
        float rr = sigm(xr + a0[s] + br);
        float zz = sigm(xz + a1[s] + bz);
        float nn = tanhf(xn + rr*(a2[s] + bn_));
        float hn = (1.f - zz)*nn + zz*hstage[s*HS + jg];
        hwr[(size_t)b*Hh + jg] = hn;
        msum[s] += hn;
      }
    }
    __threadfence();
    __syncthreads();
    if (tid == 0){
      __hip_atomic_fetch_add(cnt, 1u, __ATOMIC_RELEASE, __HIP_MEMORY_SCOPE_AGENT);
      u32 target = (u32)NJC * (u32)(tt+1);
      int guard = 0;
      while (__hip_atomic_load(cnt, __ATOMIC_ACQUIRE, __HIP_MEMORY_SCOPE_AGENT) < target){
        __builtin_amdgcn_s_sleep(2);
        if (++guard > 2000000) break;   // failsafe: wrong result > GPU hang
      }
    }
    __syncthreads();
  }
  if (comp && ckq == 0){
    #pragma unroll
    for (int s=0;s<4;s++)
      meanOut[(size_t)(bg*4+s)*mean_stride + (j0+cj)] = msum[s] / (float)T;
  }
}

// ---------------------------------------------------------------------------
// mask_att + fact_sep fused: per (b, 8-t chunk).
// ---------------------------------------------------------------------------
__global__ __launch_bounds__(256)
void mask_att_k(const float* ctx, const float* vh, float* simOut, float* diffOut)
{
  __shared__ float vhl[50*300];
  __shared__ float ctxl[8*300];
  __shared__ float attl[8*52];
  __shared__ float scenl[8*300];
  __shared__ float ratio[8];
  int tid = threadIdx.x;
  int b = blockIdx.y, tc = blockIdx.x;
  size_t cbase = ((size_t)b*Tn + tc*8) * 300;
  for (int i = tid; i < 15000; i += 256) vhl[i] = vh[(size_t)b*15000 + i];
  for (int i = tid; i < 2400; i += 256)  ctxl[i] = ctx[cbase + i];
  __syncthreads();
  for (int p = tid; p < 400; p += 256){
    int ttl = p / 50, v = p % 50;
    const float* cp = ctxl + ttl*300;
    const float* vp = vhl + v*300;
    float acc = 0.f;
    for (int d = 0; d < 300; d++) acc += cp[d]*vp[d];
    attl[ttl*52 + v] = acc;
  }
  __syncthreads();
  if (tid < 8){
    float mx = -INFINITY;
    for (int v=0; v<50; v++){
      float a = attl[tid*52+v];
      float msk = (a == 0.f) ? -INFINITY : a;
      attl[tid*52+v] = msk;
      mx = fmaxf(mx, msk);
    }
    if (mx == -INFINITY){
      for (int v=0; v<50; v++) attl[tid*52+v] = 0.f;
    } else {
      float sum = 0.f;
      for (int v=0; v<50; v++){ float e = expf(attl[tid*52+v] - mx); attl[tid*52+v] = e; sum += e; }
      float inv = 1.f/sum;
      for (int v=0; v<50; v++) attl[tid*52+v] *= inv;
    }
  }
  __syncthreads();
  for (int p = tid; p < 2400; p += 256){
    int ttl = p / 300, d = p % 300;
    float acc = 0.f;
    for (int v=0; v<50; v++) acc += attl[ttl*52+v] * vhl[v*300+d];
    scenl[p] = acc;
  }
  __syncthreads();
  if (tid < 8){
    float x3=0.f, x4=0.f;
    for (int d=0; d<300; d++){ float s = scenl[tid*300+d]; x3 += ctxl[tid*300+d]*s; x4 += s*s; }
    ratio[tid] = x3 / (x4 + 1e-10f);
  }
  __syncthreads();
  for (int p = tid; p < 2400; p += 256){
    float sim = ratio[p/300] * scenl[p];
    simOut[cbase + p]  = sim;
    diffOut[cbase + p] = ctxl[p] - sim;
  }
}

// ---------------------------------------------------------------------------
// code_wise helpers
// ---------------------------------------------------------------------------
__global__ void rowmax_k(const float* S, float* out, int M, int N){
  int row = blockIdx.x*4 + (threadIdx.x >> 6);
  int lane = threadIdx.x & 63;
  if (row >= M) return;
  float mx = -INFINITY;
  for (int n = lane; n < N; n += 64) mx = fmaxf(mx, S[(size_t)row*N + n]);
  for (int off = 32; off; off >>= 1) mx = fmaxf(mx, __shfl_xor(mx, off, 64));
  if (lane == 0) out[row] = mx;
}

__global__ __launch_bounds__(256)
void softmaxT_k(const float* m, float* att){
  __shared__ float red[256];
  int b = blockIdx.x, tid = threadIdx.x;
  float v1 = m[b*512 + tid], v2 = m[b*512 + 256 + tid];
  red[tid] = fmaxf(v1, v2); __syncthreads();
  for (int s=128; s; s>>=1){ if (tid<s) red[tid] = fmaxf(red[tid], red[tid+s]); __syncthreads(); }
  float M = red[0]; __syncthreads();
  float e1 = expf(v1-M), e2 = expf(v2-M);
  red[tid] = e1+e2; __syncthreads();
  for (int s=128; s; s>>=1){ if (tid<s) red[tid] += red[tid+s]; __syncthreads(); }
  float inv = 1.f / red[0];
  att[b*512+tid] = e1*inv; att[b*512+256+tid] = e2*inv;
}

__global__ __launch_bounds__(256)
void wsum_k(const float* att, const float* dh, float* out){
  int b = blockIdx.x, tid = threadIdx.x;
  for (int d = tid; d < 300; d += 256){
    float acc = 0.f;
    for (int t = 0; t < 512; t++)
      acc += att[b*512+t] * dh[((size_t)b*512 + t)*300 + d];
    out[b*300+d] = acc;
  }
}

// ---------------------------------------------------------------------------
// graph_decomp helpers
// ---------------------------------------------------------------------------
__global__ void count_k(const int* src, int E, float* counts){
  int e = blockIdx.x*256 + threadIdx.x;
  if (e < E) atomicAdd(&counts[src[e]], 1.f);
}
__global__ void coef_k(const float* L, const int* src, const int* dst, int E, float* coef){
  int e = blockIdx.x*4 + (threadIdx.x >> 6);
  int lane = threadIdx.x & 63;
  if (e >= E) return;
  const float* Li = L + (size_t)src[e]*300;
  const float* Lj = L + (size_t)dst[e]*300;
  float num = 0.f, den = 0.f;
  for (int d = lane; d < 300; d += 64){ float lj = Lj[d]; num += Li[d]*lj; den += lj*lj; }
  for (int off = 32; off; off >>= 1){ num += __shfl_xor(num, off, 64); den += __shfl_xor(den, off, 64); }
  if (lane == 0) coef[e] = num / (den + 1e-10f);
}
__global__ void agg_k(const float* L, const int* src, const int* dst, const float* coef, int E, float* agg){
  int e = blockIdx.x;
  float c = coef[e];
  const float* Lj = L + (size_t)dst[e]*300;
  float* ag = agg + (size_t)src[e]*300;
  for (int d = threadIdx.x; d < 300; d += 256) atomicAdd(&ag[d], c*Lj[d]);
}
__global__ void upd_k(const float* L, const float* agg, const float* counts, float* out, int n){
  int i = blockIdx.x;
  float c = counts[i];
  for (int d = threadIdx.x; d < 300; d += 256){
    float v = L[(size_t)i*300+d];
    out[(size_t)i*300+d] = (c > 0.f) ? v - agg[(size_t)i*300+d]/fmaxf(c, 1.f) : v;
  }
}

// ---------------------------------------------------------------------------
// classifier heads (write f32 logits straight into d_out), argmax, gather
// ---------------------------------------------------------------------------
__global__ __launch_bounds__(128)
void logits_k(const float* A0, const float* A1, const float* A2, int srcw,
              const float* W, const float* bias, int C, int K,
              float* outF){
  int b = blockIdx.x, tid = threadIdx.x;
  for (int c = tid; c < C; c += 128){
    float acc = bias[c];
    const float* wp = W + (size_t)c*K;
    for (int k = 0; k < K; k++){
      int s = k / srcw; int kk = k - s*srcw;
      const float* Ap = (s==0) ? A0 : ((s==1) ? A1 : A2);
      acc += Ap[(size_t)b*srcw + kk] * wp[k];
    }
    outF[b*C + c] = acc;
  }
}
__global__ void argmax_k(const float* lf, int C, int* pred){
  int b = threadIdx.x;
  if (b < 32){
    const float* p = lf + (size_t)b*C;
    int best = 0; float bv = p[0];
    for (int c = 1; c < C; c++){ float v = p[c]; if (v > bv){ bv = v; best = c; } }
    pred[b] = best;
  }
}
__global__ void vtok_k(const int* table, const int* pred, int* vt, int L){
  int i = blockIdx.x*256 + threadIdx.x;
  if (i < 32*L) vt[i] = table[pred[i/L]*L + i%L];
}

// ---------------------------------------------------------------------------
extern "C" void kernel_launch(void* const* d_in, const int* in_sizes, int n_in,
                              void* d_out, int out_size, void* d_ws, size_t ws_size,
                              hipStream_t stream)
{
  (void)in_sizes; (void)n_in; (void)out_size;
  const float* E        = (const float*)d_in[0];
  const int* chTok    = (const int*)d_in[1];
  const int* arTok    = (const int*)d_in[2];
  const int* docs     = (const int*)d_in[3];
  const int* chVerd   = (const int*)d_in[4];
  const int* arVerd   = (const int*)d_in[5];
  const int* c_src    = (const int*)d_in[6];
  const int* c_dst    = (const int*)d_in[7];
  const int* a_src    = (const int*)d_in[8];
  const int* a_dst    = (const int*)d_in[9];
  const float* enc_Wih  = (const float*)d_in[10];
  const float* enc_Whh  = (const float*)d_in[11];
  const float* enc_bih  = (const float*)d_in[12];
  const float* enc_bhh  = (const float*)d_in[13];
  const float* ech_Wih  = (const float*)d_in[14];
  const float* ech_Whh  = (const float*)d_in[15];
  const float* ech_bih  = (const float*)d_in[16];
  const float* ech_bhh  = (const float*)d_in[17];
  const float* term_Wih = (const float*)d_in[18];
  const float* term_Whh = (const float*)d_in[19];
  const float* term_bih = (const float*)d_in[20];
  const float* term_bhh = (const float*)d_in[21];
  const float* art_Wih  = (const float*)d_in[22];
  const float* art_Whh  = (const float*)d_in[23];
  const float* art_bih  = (const float*)d_in[24];
  const float* art_bhh  = (const float*)d_in[25];
  const float* W_charge = (const float*)d_in[26];
  const float* b_charge = (const float*)d_in[27];
  const float* W_article= (const float*)d_in[28];
  const float* b_article= (const float*)d_in[29];
  const float* W_time   = (const float*)d_in[30];
  const float* b_time   = (const float*)d_in[31];
  float* out = (float*)d_out;
  float* OUTC = out;            // [32][119]
  float* OUTA = out + 3808;     // [32][103]
  float* OUTT = out + 7104;     // [32][11]

  char* wsb = (char*)d_ws;
  size_t off = 0;
  auto alloc = [&](size_t nf)->float* {
    float* p = (float*)(wsb + off);
    off += ((nf*4 + 255) & ~(size_t)255);
    return p;
  };
  float* ARENA = alloc(29491200ULL);        // 16384*1800 max (118 MB)
  float* SBUF  = ARENA;                     // alias: disjoint lifetime
  float* DH    = alloc(4915200);            // d_hidden [32][512][300]
  float* ADC   = alloc(4915200);            // adc, later dsc
  float* SEC   = alloc(4915200);
  float* SSC   = alloc(4915200);
  float* VHYS  = alloc(480000);             // [32][50][300]
  float* MECH  = alloc(66600);              // encch means [222][300]
  float* LC1   = alloc(35700);
  float* LC0   = alloc(35700);
  float* LA1   = alloc(30900);
  float* LA0   = alloc(30900);
  float* AGG   = alloc(35700);
  float* CNTS  = alloc(256);                // counts_c @0, counts_a @128
  float* COEF  = alloc(640);
  float* DHC   = alloc(9600);
  float* DA    = alloc(9600);
  float* DHNA  = alloc(9600);
  float* DB    = alloc(9600);
  float* MDH   = alloc(9600);               // mean_t d_hidden [32][300]
  float* MFA   = alloc(38400);              // fa mean [32][1200]
  float* MTH   = alloc(28800);              // th mean [32][900]
  float* RB    = alloc(115200);             // art rowbias [32][3600]
  float* RMX   = alloc(16384);
  float* ATTB  = alloc(16384);
  float* HBUF  = alloc(38400);              // [2][32][600] max
  u32*   CTRS  = (u32*)alloc(64);           // 4 launches x 8 groups
  int*   PREDC = (int*)alloc(64);
  int*   PREDA = (int*)alloc(64);
  int*   VTOK  = (int*)alloc(1600);
  int*   TCC   = (int*)alloc(11104);

  if (off > ws_size) return;   // diagnostic: leaves out==0 -> absmax==max|ref|

  hipMemsetAsync(CTRS, 0, 64*4, stream);
  hipMemsetAsync(CNTS, 0, 256*4, stream);

  // --- encch on charge+article token sequences (222 seqs, L=50) ---
  hipMemcpyAsync(TCC, chTok, NCn*LCn*4, hipMemcpyDeviceToDevice, stream);
  hipMemcpyAsync(TCC + NCn*LCn, arTok, NAn*LCn*4, hipMemcpyDeviceToDevice, stream);
  {
    dim3 g((900+127)/128, (11100+127)/128);
    gemm_k<1><<<g,256,0,stream>>>(nullptr,nullptr,nullptr, E, TCC,
        ech_Wih, 200, 0,0,0, ech_bih, nullptr, 1, 1, ARENA, 11100, 900, 200);
  }
  gru_small_k<<<dim3(222,2),192,0,stream>>>(ARENA, 900, ech_Whh, ech_bhh, nullptr, MECH, 50);

  // --- enc on documents ---
  {
    dim3 g((900+127)/128, (16384+127)/128);
    gemm_k<1><<<g,256,0,stream>>>(nullptr,nullptr,nullptr, E, docs,
        enc_Wih, 200, 0,0,0, enc_bih, nullptr, 1, 1, ARENA, 16384, 900, 200);
  }
  gru_small_k<<<dim3(32,2),192,0,stream>>>(ARENA, 900, enc_Whh, enc_bhh, DH, MDH, 512);

  // --- graph_decomp (charge, article), 2 layers each ---
  count_k<<<3,256,0,stream>>>(c_src, ECn, CNTS);
  count_k<<<2,256,0,stream>>>(a_src, EAn, CNTS+128);
  coef_k<<<150,256,0,stream>>>(MECH, c_src, c_dst, ECn, COEF);
  hipMemsetAsync(AGG, 0, 35700*4, stream);
  agg_k<<<ECn,256,0,stream>>>(MECH, c_src, c_dst, COEF, ECn, AGG);
  upd_k<<<NCn,256,0,stream>>>(MECH, AGG, CNTS, LC1, NCn);
  coef_k<<<150,256,0,stream>>>(LC1, c_src, c_dst, ECn, COEF);
  hipMemsetAsync(AGG, 0, 35700*4, stream);
  agg_k<<<ECn,256,0,stream>>>(LC1, c_src, c_dst, COEF, ECn, AGG);
  upd_k<<<NCn,256,0,stream>>>(LC1, AGG, CNTS, LC0, NCn);

  const float* MEAR = MECH + (size_t)NCn*300;
  coef_k<<<125,256,0,stream>>>(MEAR, a_src, a_dst, EAn, COEF);
  hipMemsetAsync(AGG, 0, 30900*4, stream);
  agg_k<<<EAn,256,0,stream>>>(MEAR, a_src, a_dst, COEF, EAn, AGG);
  upd_k<<<NAn,256,0,stream>>>(MEAR, AGG, CNTS+128, LA1, NAn);
  coef_k<<<125,256,0,stream>>>(LA1, a_src, a_dst, EAn, COEF);
  hipMemsetAsync(AGG, 0, 30900*4, stream);
  agg_k<<<EAn,256,0,stream>>>(LA1, a_src, a_dst, COEF, EAn, AGG);
  upd_k<<<NAn,256,0,stream>>>(LA1, AGG, CNTS+128, LA0, NAn);

  // --- code_wise x4 (S-buffer aliased into ARENA) ---
  auto codewise = [&](const float* q, int Nq, float* outv){
    dim3 g((Nq+127)/128, 128);
    gemm_k<0><<<g,256,0,stream>>>(DH, nullptr, nullptr, nullptr, nullptr,
        q, 300, 0,0,0, nullptr, nullptr, 1, 1, SBUF, 16384, Nq, 300);
    rowmax_k<<<4096,256,0,stream>>>(SBUF, RMX, 16384, Nq);
    softmaxT_k<<<32,256,0,stream>>>(RMX, ATTB);
    wsum_k<<<32,256,0,stream>>>(ATTB, DH, outv);
  };
  codewise(LC0,  NCn, DHC);    // new_charge
  codewise(MECH, NCn, DA);     // ori charge
  codewise(LA0,  NAn, DHNA);   // new_article
  codewise(MEAR, NAn, DB);     // ori article

  // --- charge head ---
  logits_k<<<32,128,0,stream>>>(MDH, DHC, DA, 300, W_charge, b_charge, NCn, 900, OUTC);
  argmax_k<<<1,64,0,stream>>>(OUTC, NCn, PREDC);

  // --- fact_sep #1 ---
  vtok_k<<<7,256,0,stream>>>(chVerd, PREDC, VTOK, LVn);
  {
    dim3 g((900+127)/128, (1600+127)/128);
    gemm_k<1><<<g,256,0,stream>>>(nullptr,nullptr,nullptr, E, VTOK,
        enc_Wih, 200, 0,0,0, enc_bih, nullptr, 1, 1, ARENA, 1600, 900, 200);
  }
  gru_small_k<<<dim3(32,2),192,0,stream>>>(ARENA, 900, enc_Whh, enc_bhh, VHYS, nullptr, 50);
  mask_att_k<<<dim3(64,32),256,0,stream>>>(DH, VHYS, ADC, SEC);

  // --- article bigru: rowbias (t-constant concat halves), then per-dir ---
  {
    dim3 g((3600+127)/128, 1);
    gemm_k<0><<<g,256,0,stream>>>(DHNA, DB, nullptr, nullptr, nullptr,
        art_Wih, 1200, 300, 900, 0, art_bih, nullptr, 1, 1, RB, 32, 3600, 600);
  }
  for (int dir = 0; dir < 2; dir++){
    dim3 g((1800+127)/128, 128);
    gemm_k<0><<<g,256,0,stream>>>(DH, ADC, nullptr, nullptr, nullptr,
        art_Wih + (size_t)dir*1800*1200, 1200, 0, 600, 0,
        nullptr, RB + dir*1800, 512, 3600, ARENA, 16384, 1800, 600);
    hipMemsetAsync(HBUF, 0, 38400*4, stream);
    gru_big_k<<<dim3(15,8),192,0,stream>>>(ARENA,
        art_Whh + (size_t)dir*1800*600, art_bhh + dir*1800,
        HBUF, MFA + dir*600, 1200, CTRS + dir*8,
        512, 600, 40, 604, 15, 600, dir);
  }
  logits_k<<<32,128,0,stream>>>(MFA, nullptr, nullptr, 1200, W_article, b_article, NAn, 1200, OUTA);
  argmax_k<<<1,64,0,stream>>>(OUTA, NAn, PREDA);

  // --- fact_sep #2 (context = sec_vector) ---
  vtok_k<<<7,256,0,stream>>>(arVerd, PREDA, VTOK, LVn);
  {
    dim3 g((900+127)/128, (1600+127)/128);
    gemm_k<1><<<g,256,0,stream>>>(nullptr,nullptr,nullptr, E, VTOK,
        enc_Wih, 200, 0,0,0, enc_bih, nullptr, 1, 1, ARENA, 1600, 900, 200);
  }
  gru_small_k<<<dim3(32,2),192,0,stream>>>(ARENA, 900, enc_Whh, enc_bhh, VHYS, nullptr, 50);
  mask_att_k<<<dim3(64,32),256,0,stream>>>(SEC, VHYS, SSC, ADC);   // ssc, dsc(=ADC)

  // --- term bigru, per-dir ---
  for (int dir = 0; dir < 2; dir++){
    dim3 g((1350+127)/128, 128);
    gemm_k<0><<<g,256,0,stream>>>(DH, SSC, ADC, nullptr, nullptr,
        term_Wih + (size_t)dir*1350*900, 900, 0, 300, 600,
        term_bih + dir*1350, nullptr, 1, 1, ARENA, 16384, 1350, 900);
    hipMemsetAsync(HBUF, 0, 38400*4, stream);
    gru_big_k<<<dim3(10,8),192,0,stream>>>(ARENA,
        term_Whh + (size_t)dir*1350*450, term_bhh + dir*1350,
        HBUF, MTH + dir*450, 900, CTRS + 16 + dir*8,
        512, 450, 45, 460, 10, 452, dir);
  }
  logits_k<<<32,128,0,stream>>>(MTH, nullptr, nullptr, 900, W_time, b_time, NTn, 900, OUTT);
}

// Round 4
// 44593.979 us; speedup vs baseline: 1.1405x; 1.1405x over previous
//
#include <hip/hip_runtime.h>
#include <stdint.h>
#include <math.h>

typedef unsigned int u32;
typedef _Float16 f16;
typedef _Float16 h4 __attribute__((ext_vector_type(4)));
typedef _Float16 h2 __attribute__((ext_vector_type(2)));

// Problem constants
#define Vn     50000
#define DEMBn  200
#define Hn     150
#define NCn    119
#define NAn    103
#define NTn    11
#define Bn     32
#define Tn     512
#define LCn    50
#define LVn    50
#define ECn    600
#define EAn    500

__device__ __forceinline__ float sigm(float x){ return 1.0f / (1.0f + expf(-x)); }

// LLC-coherent (agent-scope, relaxed) f32 load/store: lowered to sc1-flagged
// global ops that bypass the non-coherent per-XCD L1/L2 and are served by the
// die-level Infinity Cache. No wbl2/inv cache maintenance is emitted.
__device__ __forceinline__ float llc_loadf(const float* p){
  u32 v = __hip_atomic_load((const u32*)p, __ATOMIC_RELAXED, __HIP_MEMORY_SCOPE_AGENT);
  union { u32 i; float f; } u; u.i = v; return u.f;
}
__device__ __forceinline__ void llc_storef(float* p, float v){
  union { float f; u32 i; } u; u.f = v;
  __hip_atomic_store((u32*)p, u.i, __ATOMIC_RELAXED, __HIP_MEMORY_SCOPE_AGENT);
}

// ---------------------------------------------------------------------------
// Tiled fp32 GEMM: C[M][N] = A[M][K] @ B[N][K]^T (+bias +rowbias)
// AMODE 0: A = up to 3 f32 sources, each [M][300]; source s = k/300;
//          B column for element k is bc[s] + (k - s*300)
// AMODE 1: A[m][k] = Etab[tok[m]][k] (f32 embedding gather), B col = k
// ---------------------------------------------------------------------------
template<int AMODE>
__global__ __launch_bounds__(256)
void gemm_k(const float* A0, const float* A1, const float* A2,
            const float* Etab, const int* tok,
            const float* Bm, int ldb, int bc0, int bc1, int bc2,
            const float* bias, const float* rowbias, int rb_div, int rb_stride,
            float* C, int M, int N, int K)
{
  __shared__ float As[8][132];
  __shared__ float Bs[8][132];
  __shared__ int tokS[128];
  int tid = threadIdx.x;
  int m0 = blockIdx.y * 128, n0 = blockIdx.x * 128;
  if (AMODE == 1){
    for (int i = tid; i < 128; i += 256){
      int m = m0 + i;
      tokS[i] = (m < M) ? tok[m] : 0;
    }
  }
  __syncthreads();
  float acc[8][8];
  #pragma unroll
  for (int i=0;i<8;i++)
    #pragma unroll
    for (int j=0;j<8;j++) acc[i][j] = 0.f;

  int tx = tid & 15, ty = tid >> 4;

  for (int k0 = 0; k0 < K; k0 += 8){
    #pragma unroll
    for (int r = 0; r < 4; r++){
      int i = tid + 256*r;          // [0,1024)
      int ml = i >> 3, kl = i & 7;
      int k = k0 + kl;
      {
        int m = m0 + ml;
        float v = 0.f;
        if (m < M && k < K){
          if (AMODE == 0){
            int s = k / 300; int kk = k - s*300;
            const float* Ap = (s==0) ? A0 : ((s==1) ? A1 : A2);
            v = Ap[(size_t)m*300 + kk];
          } else {
            v = Etab[(size_t)tokS[ml]*DEMBn + k];
          }
        }
        As[kl][ml] = v;
      }
      {
        int n = n0 + ml;
        float v = 0.f;
        if (n < N && k < K){
          int col;
          if (AMODE == 0){ int s = k / 300; int kk = k - s*300; col = ((s==0)?bc0:((s==1)?bc1:bc2)) + kk; }
          else col = k;
          v = Bm[(size_t)n*ldb + col];
        }
        Bs[kl][ml] = v;
      }
    }
    __syncthreads();
    #pragma unroll
    for (int kk = 0; kk < 8; kk++){
      float a[8], b[8];
      #pragma unroll
      for (int i=0;i<8;i++) a[i] = As[kk][ty*8+i];
      #pragma unroll
      for (int i=0;i<8;i++) b[i] = Bs[kk][tx*8+i];
      #pragma unroll
      for (int i=0;i<8;i++)
        #pragma unroll
        for (int j=0;j<8;j++) acc[i][j] += a[i]*b[j];
    }
    __syncthreads();
  }
  #pragma unroll
  for (int i=0;i<8;i++){
    int m = m0 + ty*8 + i; if (m >= M) continue;
    #pragma unroll
    for (int j=0;j<8;j++){
      int n = n0 + tx*8 + j; if (n >= N) continue;
      float v = acc[i][j];
      if (bias)    v += bias[n];
      if (rowbias) v += rowbias[(size_t)(m / rb_div)*rb_stride + n];
      C[(size_t)m*N + n] = v;
    }
  }
}

// ---------------------------------------------------------------------------
// Small-GRU recurrence (H=150): one block per (seq, dir). Whh f16 in LDS.
// ---------------------------------------------------------------------------
__global__ __launch_bounds__(192)
void gru_small_k(const float* xs, int ncols,
                 const float* Whh, const float* bhh,
                 float* ys, float* meanOut, int T)
{
  const int KP = 156;
  __shared__ f16 Wl[3*150*156];     // 140,400 B
  __shared__ float bhl[456];
  __shared__ __align__(16) float hl[152];
  int tid = threadIdx.x;
  int seq = blockIdx.x, dir = blockIdx.y;

  for (int idx = tid; idx < 3*150*150; idx += 192){
    int g = idx / 22500, r = idx % 22500;
    int j = r / 150, k = r % 150;
    Wl[(g*150 + j)*KP + k] = (f16)Whh[(size_t)dir*67500 + idx];
  }
  for (int idx = tid; idx < 450; idx += 192) bhl[idx] = bhh[dir*450 + idx];
  if (tid < 152) hl[tid] = 0.f;
  __syncthreads();

  const f16 *wr = nullptr, *wz = nullptr, *wn = nullptr;
  float bR=0.f, bZ=0.f, bN=0.f;
  if (tid < 150){
    wr = &Wl[(0*150+tid)*KP];
    wz = &Wl[(1*150+tid)*KP];
    wn = &Wl[(2*150+tid)*KP];
    bR = bhl[tid]; bZ = bhl[150+tid]; bN = bhl[300+tid];
  }
  float msum = 0.f;
  size_t rowbase = (size_t)seq * T;
  for (int tt = 0; tt < T; tt++){
    int t = dir ? (T-1-tt) : tt;
    float aR=0.f, aZ=0.f, aN=0.f;
    if (tid < 150){
      for (int k = 0; k < 148; k += 4){
        float4 hv = *(const float4*)(hl + k);
        h4 r4 = *(const h4*)(wr + k);
        h4 z4 = *(const h4*)(wz + k);
        h4 n4 = *(const h4*)(wn + k);
        aR += (float)r4.x*hv.x + (float)r4.y*hv.y + (float)r4.z*hv.z + (float)r4.w*hv.w;
        aZ += (float)z4.x*hv.x + (float)z4.y*hv.y + (float)z4.z*hv.z + (float)z4.w*hv.w;
        aN += (float)n4.x*hv.x + (float)n4.y*hv.y + (float)n4.z*hv.z + (float)n4.w*hv.w;
      }
      {
        float2 hv = *(const float2*)(hl + 148);
        h2 r2 = *(const h2*)(wr + 148);
        h2 z2 = *(const h2*)(wz + 148);
        h2 n2 = *(const h2*)(wn + 148);
        aR += (float)r2.x*hv.x + (float)r2.y*hv.y;
        aZ += (float)z2.x*hv.x + (float)z2.y*hv.y;
        aN += (float)n2.x*hv.x + (float)n2.y*hv.y;
      }
    }
    __syncthreads();           // all reads of hl done
    if (tid < 150){
      const float* xp = xs + (rowbase + t)*(size_t)ncols + dir*450;
      float xr = xp[tid], xz = xp[150+tid], xn = xp[300+tid];
      float rr = sigm(xr + aR + bR);
      float zz = sigm(xz + aZ + bZ);
      float nn = tanhf(xn + rr*(aN + bN));
      float hn = (1.f - zz)*nn + zz*hl[tid];
      hl[tid] = hn;
      msum += hn;
      if (ys) ys[(rowbase + t)*(size_t)300 + dir*150 + tid] = hn;
    }
    __syncthreads();
  }
  if (meanOut && tid < 150)
    meanOut[(size_t)seq*300 + dir*150 + tid] = msum / (float)T;
}

// ---------------------------------------------------------------------------
// Big-GRU recurrence, ONE direction per launch. Grid (NJC, 8).
// h transported between blocks via LLC-coherent relaxed atomics (sc1 ops) —
// NO agent-scope fences -> no per-step buffer_wbl2 / buffer_inv.
// Visibility protocol per step: every wave drains its own stores with
// s_waitcnt(0), __syncthreads, then tid0 bumps the group counter (relaxed);
// consumers spin on relaxed loads of the counter, then read h via sc1 loads.
// ---------------------------------------------------------------------------
__global__ __launch_bounds__(192)
void gru_big_k(const float* xs,          // per-dir xs [B*T][3*Hh]
               const float* Whh,         // per-dir [3*Hh][Hh]
               const float* bhh,         // per-dir [3*Hh]
               float* hbuf,              // [2][B][Hh] (no init needed)
               float* meanOut, int mean_stride,   // pre-offset by dir*Hh
               u32* counters,            // 8 per launch (one per bg), zeroed
               int T, int Hh, int JB, int KPAD, int NJC, int HS, int reverse)
{
  __shared__ f16 Wl[72480];                 // 144,960 B (art: 3*40*604)
  __shared__ float bhl[136];
  __shared__ __align__(16) float hstage[2400];
  int tid = threadIdx.x;
  int jc = blockIdx.x, bg = blockIdx.y;
  int j0 = jc * JB;
  int H3 = 3 * Hh;

  for (int idx = tid; idx < 3*JB*Hh; idx += 192){
    int row = idx / Hh, k = idx - row*Hh;
    int g = row / JB, jj = row - g*JB;
    Wl[row*KPAD + k] = (f16)Whh[((size_t)g*Hh + j0 + jj)*(size_t)Hh + k];
  }
  for (int idx = tid; idx < 3*JB; idx += 192){
    int g = idx / JB, jj = idx - g*JB;
    bhl[idx] = bhh[g*Hh + j0 + jj];
  }
  __syncthreads();

  u32* cnt = counters + bg;
  int cj = tid >> 2, ckq = tid & 3;
  bool comp = (cj < JB);
  int k0 = 0, k1 = 0;
  if (comp){
    k0 = (ckq == 0) ? 0 : ((ckq*Hh/4) & ~3);
    k1 = (ckq == 3) ? Hh : ((((ckq+1)*Hh)/4) & ~3);
  }
  float br = 0.f, bz = 0.f, bn_ = 0.f;
  if (comp && ckq == 0){
    br = bhl[cj]; bz = bhl[JB+cj]; bn_ = bhl[2*JB+cj];
  }
  float msum[4] = {0.f, 0.f, 0.f, 0.f};

  for (int tt = 0; tt < T; tt++){
    int t = reverse ? (T-1-tt) : tt;
    int par = tt & 1;
    const float* hrd = hbuf + (size_t)par*Bn*Hh;
    float*       hwr = hbuf + (size_t)(1-par)*Bn*Hh;
    if (tt == 0){
      for (int idx = tid; idx < 4*Hh; idx += 192){
        int s = idx / Hh, k = idx - s*Hh;
        hstage[s*HS + k] = 0.f;
      }
    } else {
      for (int idx = tid; idx < 4*Hh; idx += 192){
        int s = idx / Hh, k = idx - s*Hh;
        hstage[s*HS + k] = llc_loadf(&hrd[(size_t)(bg*4 + s)*Hh + k]);
      }
    }
    __syncthreads();
    float a0[4] = {0,0,0,0}, a1[4] = {0,0,0,0}, a2[4] = {0,0,0,0};
    if (comp){
      const f16* pr = &Wl[(0*JB+cj)*KPAD];
      const f16* pz = &Wl[(1*JB+cj)*KPAD];
      const f16* pn = &Wl[(2*JB+cj)*KPAD];
      int k = k0;
      for (; k + 4 <= k1; k += 4){
        h4 r4 = *(const h4*)(pr + k);
        h4 z4 = *(const h4*)(pz + k);
        h4 n4 = *(const h4*)(pn + k);
        float wr0=(float)r4.x, wr1=(float)r4.y, wr2=(float)r4.z, wr3=(float)r4.w;
        float wz0=(float)z4.x, wz1=(float)z4.y, wz2=(float)z4.z, wz3=(float)z4.w;
        float wn0=(float)n4.x, wn1=(float)n4.y, wn2=(float)n4.z, wn3=(float)n4.w;
        #pragma unroll
        for (int s=0;s<4;s++){
          float4 hv = *(const float4*)(hstage + s*HS + k);
          a0[s] += wr0*hv.x + wr1*hv.y + wr2*hv.z + wr3*hv.w;
          a1[s] += wz0*hv.x + wz1*hv.y + wz2*hv.z + wz3*hv.w;
          a2[s] += wn0*hv.x + wn1*hv.y + wn2*hv.z + wn3*hv.w;
        }
      }
      for (; k < k1; k++){
        float wr0=(float)pr[k], wz0=(float)pz[k], wn0=(float)pn[k];
        #pragma unroll
        for (int s=0;s<4;s++){
          float hv = hstage[s*HS + k];
          a0[s] += wr0*hv; a1[s] += wz0*hv; a2[s] += wn0*hv;
        }
      }
    }
    // quad reduction over ckq lanes (quads never straddle waves)
    #pragma unroll
    for (int s=0;s<4;s++){
      a0[s] += __shfl_xor(a0[s], 1); a0[s] += __shfl_xor(a0[s], 2);
      a1[s] += __shfl_xor(a1[s], 1); a1[s] += __shfl_xor(a1[s], 2);
      a2[s] += __shfl_xor(a2[s], 1); a2[s] += __shfl_xor(a2[s], 2);
    }
    if (comp && ckq == 0){
      int jg = j0 + cj;
      #pragma unroll
      for (int s=0;s<4;s++){
        int b = bg*4 + s;
        const float* xp = xs + ((size_t)b*T + t)*(size_t)H3;
        float xr = xp[jg], xz = xp[Hh+jg], xn = xp[2*Hh+jg];
        float rr = sigm(xr + a0[s] + br);
        float zz = sigm(xz + a1[s] + bz);
        float nn = tanhf(xn + rr*(a2[s] + bn_));
        float hn = (1.f - zz)*nn + zz*hstage[s*HS + jg];
        llc_storef(&hwr[(size_t)b*Hh + jg], hn);
        msum[s] += hn;
      }
    }
    __builtin_amdgcn_s_waitcnt(0);   // per-wave: drain this wave's h stores
    __syncthreads();                 // all waves' stores now at LLC
    if (tid == 0){
      __hip_atomic_fetch_add(cnt, 1u, __ATOMIC_RELAXED, __HIP_MEMORY_SCOPE_AGENT);
      u32 target = (u32)NJC * (u32)(tt+1);
      int guard = 0;
      while (__hip_atomic_load(cnt, __ATOMIC_RELAXED, __HIP_MEMORY_SCOPE_AGENT) < target){
        __builtin_amdgcn_s_sleep(2);
        if (++guard > 2000000) break;   // failsafe: wrong result > GPU hang
      }
    }
    __syncthreads();
  }
  if (comp && ckq == 0){
    #pragma unroll
    for (int s=0;s<4;s++)
      meanOut[(size_t)(bg*4+s)*mean_stride + (j0+cj)] = msum[s] / (float)T;
  }
}

// ---------------------------------------------------------------------------
// mask_att + fact_sep fused: per (b, 8-t chunk).
// ---------------------------------------------------------------------------
__global__ __launch_bounds__(256)
void mask_att_k(const float* ctx, const float* vh, float* simOut, float* diffOut)
{
  __shared__ float vhl[50*300];
  __shared__ float ctxl[8*300];
  __shared__ float attl[8*52];
  __shared__ float scenl[8*300];
  __shared__ float ratio[8];
  int tid = threadIdx.x;
  int b = blockIdx.y, tc = blockIdx.x;
  size_t cbase = ((size_t)b*Tn + tc*8) * 300;
  for (int i = tid; i < 15000; i += 256) vhl[i] = vh[(size_t)b*15000 + i];
  for (int i = tid; i < 2400; i += 256)  ctxl[i] = ctx[cbase + i];
  __syncthreads();
  for (int p = tid; p < 400; p += 256){
    int ttl = p / 50, v = p % 50;
    const float* cp = ctxl + ttl*300;
    const float* vp = vhl + v*300;
    float acc = 0.f;
    for (int d = 0; d < 300; d++) acc += cp[d]*vp[d];
    attl[ttl*52 + v] = acc;
  }
  __syncthreads();
  if (tid < 8){
    float mx = -INFINITY;
    for (int v=0; v<50; v++){
      float a = attl[tid*52+v];
      float msk = (a == 0.f) ? -INFINITY : a;
      attl[tid*52+v] = msk;
      mx = fmaxf(mx, msk);
    }
    if (mx == -INFINITY){
      for (int v=0; v<50; v++) attl[tid*52+v] = 0.f;
    } else {
      float sum = 0.f;
      for (int v=0; v<50; v++){ float e = expf(attl[tid*52+v] - mx); attl[tid*52+v] = e; sum += e; }
      float inv = 1.f/sum;
      for (int v=0; v<50; v++) attl[tid*52+v] *= inv;
    }
  }
  __syncthreads();
  for (int p = tid; p < 2400; p += 256){
    int ttl = p / 300, d = p % 300;
    float acc = 0.f;
    for (int v=0; v<50; v++) acc += attl[ttl*52+v] * vhl[v*300+d];
    scenl[p] = acc;
  }
  __syncthreads();
  if (tid < 8){
    float x3=0.f, x4=0.f;
    for (int d=0; d<300; d++){ float s = scenl[tid*300+d]; x3 += ctxl[tid*300+d]*s; x4 += s*s; }
    ratio[tid] = x3 / (x4 + 1e-10f);
  }
  __syncthreads();
  for (int p = tid; p < 2400; p += 256){
    float sim = ratio[p/300] * scenl[p];
    simOut[cbase + p]  = sim;
    diffOut[cbase + p] = ctxl[p] - sim;
  }
}

// ---------------------------------------------------------------------------
// code_wise helpers
// ---------------------------------------------------------------------------
__global__ void rowmax_k(const float* S, float* out, int M, int N){
  int row = blockIdx.x*4 + (threadIdx.x >> 6);
  int lane = threadIdx.x & 63;
  if (row >= M) return;
  float mx = -INFINITY;
  for (int n = lane; n < N; n += 64) mx = fmaxf(mx, S[(size_t)row*N + n]);
  for (int off = 32; off; off >>= 1) mx = fmaxf(mx, __shfl_xor(mx, off, 64));
  if (lane == 0) out[row] = mx;
}

__global__ __launch_bounds__(256)
void softmaxT_k(const float* m, float* att){
  __shared__ float red[256];
  int b = blockIdx.x, tid = threadIdx.x;
  float v1 = m[b*512 + tid], v2 = m[b*512 + 256 + tid];
  red[tid] = fmaxf(v1, v2); __syncthreads();
  for (int s=128; s; s>>=1){ if (tid<s) red[tid] = fmaxf(red[tid], red[tid+s]); __syncthreads(); }
  float M = red[0]; __syncthreads();
  float e1 = expf(v1-M), e2 = expf(v2-M);
  red[tid] = e1+e2; __syncthreads();
  for (int s=128; s; s>>=1){ if (tid<s) red[tid] += red[tid+s]; __syncthreads(); }
  float inv = 1.f / red[0];
  att[b*512+tid] = e1*inv; att[b*512+256+tid] = e2*inv;
}

__global__ __launch_bounds__(256)
void wsum_k(const float* att, const float* dh, float* out){
  int b = blockIdx.x, tid = threadIdx.x;
  for (int d = tid; d < 300; d += 256){
    float acc = 0.f;
    for (int t = 0; t < 512; t++)
      acc += att[b*512+t] * dh[((size_t)b*512 + t)*300 + d];
    out[b*300+d] = acc;
  }
}

// ---------------------------------------------------------------------------
// graph_decomp helpers
// ---------------------------------------------------------------------------
__global__ void count_k(const int* src, int E, float* counts){
  int e = blockIdx.x*256 + threadIdx.x;
  if (e < E) atomicAdd(&counts[src[e]], 1.f);
}
__global__ void coef_k(const float* L, const int* src, const int* dst, int E, float* coef){
  int e = blockIdx.x*4 + (threadIdx.x >> 6);
  int lane = threadIdx.x & 63;
  if (e >= E) return;
  const float* Li = L + (size_t)src[e]*300;
  const float* Lj = L + (size_t)dst[e]*300;
  float num = 0.f, den = 0.f;
  for (int d = lane; d < 300; d += 64){ float lj = Lj[d]; num += Li[d]*lj; den += lj*lj; }
  for (int off = 32; off; off >>= 1){ num += __shfl_xor(num, off, 64); den += __shfl_xor(den, off, 64); }
  if (lane == 0) coef[e] = num / (den + 1e-10f);
}
__global__ void agg_k(const float* L, const int* src, const int* dst, const float* coef, int E, float* agg){
  int e = blockIdx.x;
  float c = coef[e];
  const float* Lj = L + (size_t)dst[e]*300;
  float* ag = agg + (size_t)src[e]*300;
  for (int d = threadIdx.x; d < 300; d += 256) atomicAdd(&ag[d], c*Lj[d]);
}
__global__ void upd_k(const float* L, const float* agg, const float* counts, float* out, int n){
  int i = blockIdx.x;
  float c = counts[i];
  for (int d = threadIdx.x; d < 300; d += 256){
    float v = L[(size_t)i*300+d];
    out[(size_t)i*300+d] = (c > 0.f) ? v - agg[(size_t)i*300+d]/fmaxf(c, 1.f) : v;
  }
}

// ---------------------------------------------------------------------------
// classifier heads (write f32 logits straight into d_out), argmax, gather
// ---------------------------------------------------------------------------
__global__ __launch_bounds__(128)
void logits_k(const float* A0, const float* A1, const float* A2, int srcw,
              const float* W, const float* bias, int C, int K,
              float* outF){
  int b = blockIdx.x, tid = threadIdx.x;
  for (int c = tid; c < C; c += 128){
    float acc = bias[c];
    const float* wp = W + (size_t)c*K;
    for (int k = 0; k < K; k++){
      int s = k / srcw; int kk = k - s*srcw;
      const float* Ap = (s==0) ? A0 : ((s==1) ? A1 : A2);
      acc += Ap[(size_t)b*srcw + kk] * wp[k];
    }
    outF[b*C + c] = acc;
  }
}
__global__ void argmax_k(const float* lf, int C, int* pred){
  int b = threadIdx.x;
  if (b < 32){
    const float* p = lf + (size_t)b*C;
    int best = 0; float bv = p[0];
    for (int c = 1; c < C; c++){ float v = p[c]; if (v > bv){ bv = v; best = c; } }
    pred[b] = best;
  }
}
__global__ void vtok_k(const int* table, const int* pred, int* vt, int L){
  int i = blockIdx.x*256 + threadIdx.x;
  if (i < 32*L) vt[i] = table[pred[i/L]*L + i%L];
}

// ---------------------------------------------------------------------------
extern "C" void kernel_launch(void* const* d_in, const int* in_sizes, int n_in,
                              void* d_out, int out_size, void* d_ws, size_t ws_size,
                              hipStream_t stream)
{
  (void)in_sizes; (void)n_in; (void)out_size;
  const float* E        = (const float*)d_in[0];
  const int* chTok    = (const int*)d_in[1];
  const int* arTok    = (const int*)d_in[2];
  const int* docs     = (const int*)d_in[3];
  const int* chVerd   = (const int*)d_in[4];
  const int* arVerd   = (const int*)d_in[5];
  const int* c_src    = (const int*)d_in[6];
  const int* c_dst    = (const int*)d_in[7];
  const int* a_src    = (const int*)d_in[8];
  const int* a_dst    = (const int*)d_in[9];
  const float* enc_Wih  = (const float*)d_in[10];
  const float* enc_Whh  = (const float*)d_in[11];
  const float* enc_bih  = (const float*)d_in[12];
  const float* enc_bhh  = (const float*)d_in[13];
  const float* ech_Wih  = (const float*)d_in[14];
  const float* ech_Whh  = (const float*)d_in[15];
  const float* ech_bih  = (const float*)d_in[16];
  const float* ech_bhh  = (const float*)d_in[17];
  const float* term_Wih = (const float*)d_in[18];
  const float* term_Whh = (const float*)d_in[19];
  const float* term_bih = (const float*)d_in[20];
  const float* term_bhh = (const float*)d_in[21];
  const float* art_Wih  = (const float*)d_in[22];
  const float* art_Whh  = (const float*)d_in[23];
  const float* art_bih  = (const float*)d_in[24];
  const float* art_bhh  = (const float*)d_in[25];
  const float* W_charge = (const float*)d_in[26];
  const float* b_charge = (const float*)d_in[27];
  const float* W_article= (const float*)d_in[28];
  const float* b_article= (const float*)d_in[29];
  const float* W_time   = (const float*)d_in[30];
  const float* b_time   = (const float*)d_in[31];
  float* out = (float*)d_out;
  float* OUTC = out;            // [32][119]
  float* OUTA = out + 3808;     // [32][103]
  float* OUTT = out + 7104;     // [32][11]

  char* wsb = (char*)d_ws;
  size_t off = 0;
  auto alloc = [&](size_t nf)->float* {
    float* p = (float*)(wsb + off);
    off += ((nf*4 + 255) & ~(size_t)255);
    return p;
  };
  float* ARENA = alloc(29491200ULL);        // 16384*1800 max (118 MB)
  float* SBUF  = ARENA;                     // alias: disjoint lifetime
  float* DH    = alloc(4915200);            // d_hidden [32][512][300]
  float* ADC   = alloc(4915200);            // adc, later dsc
  float* SEC   = alloc(4915200);
  float* SSC   = alloc(4915200);
  float* VHYS  = alloc(480000);             // [32][50][300]
  float* MECH  = alloc(66600);              // encch means [222][300]
  float* LC1   = alloc(35700);
  float* LC0   = alloc(35700);
  float* LA1   = alloc(30900);
  float* LA0   = alloc(30900);
  float* AGG   = alloc(35700);
  float* CNTS  = alloc(256);                // counts_c @0, counts_a @128
  float* COEF  = alloc(640);
  float* DHC   = alloc(9600);
  float* DA    = alloc(9600);
  float* DHNA  = alloc(9600);
  float* DB    = alloc(9600);
  float* MDH   = alloc(9600);               // mean_t d_hidden [32][300]
  float* MFA   = alloc(38400);              // fa mean [32][1200]
  float* MTH   = alloc(28800);              // th mean [32][900]
  float* RB    = alloc(115200);             // art rowbias [32][3600]
  float* RMX   = alloc(16384);
  float* ATTB  = alloc(16384);
  float* HBUF  = alloc(38400);              // [2][32][600] max
  u32*   CTRS  = (u32*)alloc(64);           // 4 launches x 8 groups
  int*   PREDC = (int*)alloc(64);
  int*   PREDA = (int*)alloc(64);
  int*   VTOK  = (int*)alloc(1600);
  int*   TCC   = (int*)alloc(11104);

  if (off > ws_size) return;   // diagnostic: leaves out==0 -> absmax==max|ref|

  hipMemsetAsync(CTRS, 0, 64*4, stream);
  hipMemsetAsync(CNTS, 0, 256*4, stream);

  // --- encch on charge+article token sequences (222 seqs, L=50) ---
  hipMemcpyAsync(TCC, chTok, NCn*LCn*4, hipMemcpyDeviceToDevice, stream);
  hipMemcpyAsync(TCC + NCn*LCn, arTok, NAn*LCn*4, hipMemcpyDeviceToDevice, stream);
  {
    dim3 g((900+127)/128, (11100+127)/128);
    gemm_k<1><<<g,256,0,stream>>>(nullptr,nullptr,nullptr, E, TCC,
        ech_Wih, 200, 0,0,0, ech_bih, nullptr, 1, 1, ARENA, 11100, 900, 200);
  }
  gru_small_k<<<dim3(222,2),192,0,stream>>>(ARENA, 900, ech_Whh, ech_bhh, nullptr, MECH, 50);

  // --- enc on documents ---
  {
    dim3 g((900+127)/128, (16384+127)/128);
    gemm_k<1><<<g,256,0,stream>>>(nullptr,nullptr,nullptr, E, docs,
        enc_Wih, 200, 0,0,0, enc_bih, nullptr, 1, 1, ARENA, 16384, 900, 200);
  }
  gru_small_k<<<dim3(32,2),192,0,stream>>>(ARENA, 900, enc_Whh, enc_bhh, DH, MDH, 512);

  // --- graph_decomp (charge, article), 2 layers each ---
  count_k<<<3,256,0,stream>>>(c_src, ECn, CNTS);
  count_k<<<2,256,0,stream>>>(a_src, EAn, CNTS+128);
  coef_k<<<150,256,0,stream>>>(MECH, c_src, c_dst, ECn, COEF);
  hipMemsetAsync(AGG, 0, 35700*4, stream);
  agg_k<<<ECn,256,0,stream>>>(MECH, c_src, c_dst, COEF, ECn, AGG);
  upd_k<<<NCn,256,0,stream>>>(MECH, AGG, CNTS, LC1, NCn);
  coef_k<<<150,256,0,stream>>>(LC1, c_src, c_dst, ECn, COEF);
  hipMemsetAsync(AGG, 0, 35700*4, stream);
  agg_k<<<ECn,256,0,stream>>>(LC1, c_src, c_dst, COEF, ECn, AGG);
  upd_k<<<NCn,256,0,stream>>>(LC1, AGG, CNTS, LC0, NCn);

  const float* MEAR = MECH + (size_t)NCn*300;
  coef_k<<<125,256,0,stream>>>(MEAR, a_src, a_dst, EAn, COEF);
  hipMemsetAsync(AGG, 0, 30900*4, stream);
  agg_k<<<EAn,256,0,stream>>>(MEAR, a_src, a_dst, COEF, EAn, AGG);
  upd_k<<<NAn,256,0,stream>>>(MEAR, AGG, CNTS+128, LA1, NAn);
  coef_k<<<125,256,0,stream>>>(LA1, a_src, a_dst, EAn, COEF);
  hipMemsetAsync(AGG, 0, 30900*4, stream);
  agg_k<<<EAn,256,0,stream>>>(LA1, a_src, a_dst, COEF, EAn, AGG);
  upd_k<<<NAn,256,0,stream>>>(LA1, AGG, CNTS+128, LA0, NAn);

  // --- code_wise x4 (S-buffer aliased into ARENA) ---
  auto codewise = [&](const float* q, int Nq, float* outv){
    dim3 g((Nq+127)/128, 128);
    gemm_k<0><<<g,256,0,stream>>>(DH, nullptr, nullptr, nullptr, nullptr,
        q, 300, 0,0,0, nullptr, nullptr, 1, 1, SBUF, 16384, Nq, 300);
    rowmax_k<<<4096,256,0,stream>>>(SBUF, RMX, 16384, Nq);
    softmaxT_k<<<32,256,0,stream>>>(RMX, ATTB);
    wsum_k<<<32,256,0,stream>>>(ATTB, DH, outv);
  };
  codewise(LC0,  NCn, DHC);    // new_charge
  codewise(MECH, NCn, DA);     // ori charge
  codewise(LA0,  NAn, DHNA);   // new_article
  codewise(MEAR, NAn, DB);     // ori article

  // --- charge head ---
  logits_k<<<32,128,0,stream>>>(MDH, DHC, DA, 300, W_charge, b_charge, NCn, 900, OUTC);
  argmax_k<<<1,64,0,stream>>>(OUTC, NCn, PREDC);

  // --- fact_sep #1 ---
  vtok_k<<<7,256,0,stream>>>(chVerd, PREDC, VTOK, LVn);
  {
    dim3 g((900+127)/128, (1600+127)/128);
    gemm_k<1><<<g,256,0,stream>>>(nullptr,nullptr,nullptr, E, VTOK,
        enc_Wih, 200, 0,0,0, enc_bih, nullptr, 1, 1, ARENA, 1600, 900, 200);
  }
  gru_small_k<<<dim3(32,2),192,0,stream>>>(ARENA, 900, enc_Whh, enc_bhh, VHYS, nullptr, 50);
  mask_att_k<<<dim3(64,32),256,0,stream>>>(DH, VHYS, ADC, SEC);

  // --- article bigru: rowbias (t-constant concat halves), then per-dir ---
  {
    dim3 g((3600+127)/128, 1);
    gemm_k<0><<<g,256,0,stream>>>(DHNA, DB, nullptr, nullptr, nullptr,
        art_Wih, 1200, 300, 900, 0, art_bih, nullptr, 1, 1, RB, 32, 3600, 600);
  }
  for (int dir = 0; dir < 2; dir++){
    dim3 g((1800+127)/128, 128);
    gemm_k<0><<<g,256,0,stream>>>(DH, ADC, nullptr, nullptr, nullptr,
        art_Wih + (size_t)dir*1800*1200, 1200, 0, 600, 0,
        nullptr, RB + dir*1800, 512, 3600, ARENA, 16384, 1800, 600);
    gru_big_k<<<dim3(15,8),192,0,stream>>>(ARENA,
        art_Whh + (size_t)dir*1800*600, art_bhh + dir*1800,
        HBUF, MFA + dir*600, 1200, CTRS + dir*8,
        512, 600, 40, 604, 15, 600, dir);
  }
  logits_k<<<32,128,0,stream>>>(MFA, nullptr, nullptr, 1200, W_article, b_article, NAn, 1200, OUTA);
  argmax_k<<<1,64,0,stream>>>(OUTA, NAn, PREDA);

  // --- fact_sep #2 (context = sec_vector) ---
  vtok_k<<<7,256,0,stream>>>(arVerd, PREDA, VTOK, LVn);
  {
    dim3 g((900+127)/128, (1600+127)/128);
    gemm_k<1><<<g,256,0,stream>>>(nullptr,nullptr,nullptr, E, VTOK,
        enc_Wih, 200, 0,0,0, enc_bih, nullptr, 1, 1, ARENA, 1600, 900, 200);
  }
  gru_small_k<<<dim3(32,2),192,0,stream>>>(ARENA, 900, enc_Whh, enc_bhh, VHYS, nullptr, 50);
  mask_att_k<<<dim3(64,32),256,0,stream>>>(SEC, VHYS, SSC, ADC);   // ssc, dsc(=ADC)

  // --- term bigru, per-dir ---
  for (int dir = 0; dir < 2; dir++){
    dim3 g((1350+127)/128, 128);
    gemm_k<0><<<g,256,0,stream>>>(DH, SSC, ADC, nullptr, nullptr,
        term_Wih + (size_t)dir*1350*900, 900, 0, 300, 600,
        term_bih + dir*1350, nullptr, 1, 1, ARENA, 16384, 1350, 900);
    gru_big_k<<<dim3(10,8),192,0,stream>>>(ARENA,
        term_Whh + (size_t)dir*1350*450, term_bhh + dir*1350,
        HBUF, MTH + dir*450, 900, CTRS + 16 + dir*8,
        512, 450, 45, 460, 10, 452, dir);
  }
  logits_k<<<32,128,0,stream>>>(MTH, nullptr, nullptr, 900, W_time, b_time, NTn, 900, OUTT);
}

// Round 5
// 41805.670 us; speedup vs baseline: 1.2166x; 1.0667x over previous
//
#include <hip/hip_runtime.h>
#include <stdint.h>
#include <math.h>

typedef unsigned int u32;
typedef _Float16 f16;
typedef _Float16 h4 __attribute__((ext_vector_type(4)));
typedef _Float16 h2 __attribute__((ext_vector_type(2)));

// Problem constants
#define Vn     50000
#define DEMBn  200
#define Hn     150
#define NCn    119
#define NAn    103
#define NTn    11
#define Bn     32
#define Tn     512
#define LCn    50
#define LVn    50
#define ECn    600
#define EAn    500

// Per-group barrier counters: one 256B region per (launch, bg) to avoid
// single-LLC-line hammering by all spinners (round-4 post-mortem).
#define CTR_STRIDE 64   // u32s = 256 B

__device__ __forceinline__ float sigm(float x){ return 1.0f / (1.0f + expf(-x)); }

// LLC-coherent (agent-scope, relaxed) f32 load/store: sc1-flagged global ops
// bypassing the non-coherent per-XCD L1/L2; no wbl2/inv is emitted.
__device__ __forceinline__ float llc_loadf(const float* p){
  u32 v = __hip_atomic_load((const u32*)p, __ATOMIC_RELAXED, __HIP_MEMORY_SCOPE_AGENT);
  union { u32 i; float f; } u; u.i = v; return u.f;
}
__device__ __forceinline__ void llc_storef(float* p, float v){
  union { float f; u32 i; } u; u.f = v;
  __hip_atomic_store((u32*)p, u.i, __ATOMIC_RELAXED, __HIP_MEMORY_SCOPE_AGENT);
}

// ---------------------------------------------------------------------------
// Tiled fp32 GEMM: C[M][N] = A[M][K] @ B[N][K]^T (+bias +rowbias)
// AMODE 0: A = up to 3 f32 sources, each [M][300]; source s = k/300;
//          B column for element k is bc[s] + (k - s*300)
// AMODE 1: A[m][k] = Etab[tok[m]][k] (f32 embedding gather), B col = k
// ---------------------------------------------------------------------------
template<int AMODE>
__global__ __launch_bounds__(256)
void gemm_k(const float* A0, const float* A1, const float* A2,
            const float* Etab, const int* tok,
            const float* Bm, int ldb, int bc0, int bc1, int bc2,
            const float* bias, const float* rowbias, int rb_div, int rb_stride,
            float* C, int M, int N, int K)
{
  __shared__ float As[8][132];
  __shared__ float Bs[8][132];
  __shared__ int tokS[128];
  int tid = threadIdx.x;
  int m0 = blockIdx.y * 128, n0 = blockIdx.x * 128;
  if (AMODE == 1){
    for (int i = tid; i < 128; i += 256){
      int m = m0 + i;
      tokS[i] = (m < M) ? tok[m] : 0;
    }
  }
  __syncthreads();
  float acc[8][8];
  #pragma unroll
  for (int i=0;i<8;i++)
    #pragma unroll
    for (int j=0;j<8;j++) acc[i][j] = 0.f;

  int tx = tid & 15, ty = tid >> 4;

  for (int k0 = 0; k0 < K; k0 += 8){
    #pragma unroll
    for (int r = 0; r < 4; r++){
      int i = tid + 256*r;          // [0,1024)
      int ml = i >> 3, kl = i & 7;
      int k = k0 + kl;
      {
        int m = m0 + ml;
        float v = 0.f;
        if (m < M && k < K){
          if (AMODE == 0){
            int s = k / 300; int kk = k - s*300;
            const float* Ap = (s==0) ? A0 : ((s==1) ? A1 : A2);
            v = Ap[(size_t)m*300 + kk];
          } else {
            v = Etab[(size_t)tokS[ml]*DEMBn + k];
          }
        }
        As[kl][ml] = v;
      }
      {
        int n = n0 + ml;
        float v = 0.f;
        if (n < N && k < K){
          int col;
          if (AMODE == 0){ int s = k / 300; int kk = k - s*300; col = ((s==0)?bc0:((s==1)?bc1:bc2)) + kk; }
          else col = k;
          v = Bm[(size_t)n*ldb + col];
        }
        Bs[kl][ml] = v;
      }
    }
    __syncthreads();
    #pragma unroll
    for (int kk = 0; kk < 8; kk++){
      float a[8], b[8];
      #pragma unroll
      for (int i=0;i<8;i++) a[i] = As[kk][ty*8+i];
      #pragma unroll
      for (int i=0;i<8;i++) b[i] = Bs[kk][tx*8+i];
      #pragma unroll
      for (int i=0;i<8;i++)
        #pragma unroll
        for (int j=0;j<8;j++) acc[i][j] += a[i]*b[j];
    }
    __syncthreads();
  }
  #pragma unroll
  for (int i=0;i<8;i++){
    int m = m0 + ty*8 + i; if (m >= M) continue;
    #pragma unroll
    for (int j=0;j<8;j++){
      int n = n0 + tx*8 + j; if (n >= N) continue;
      float v = acc[i][j];
      if (bias)    v += bias[n];
      if (rowbias) v += rowbias[(size_t)(m / rb_div)*rb_stride + n];
      C[(size_t)m*N + n] = v;
    }
  }
}

// ---------------------------------------------------------------------------
// Small-GRU recurrence (H=150): one block per (seq, dir). Whh f16 in LDS.
// ---------------------------------------------------------------------------
__global__ __launch_bounds__(192)
void gru_small_k(const float* xs, int ncols,
                 const float* Whh, const float* bhh,
                 float* ys, float* meanOut, int T)
{
  const int KP = 156;
  __shared__ f16 Wl[3*150*156];     // 140,400 B
  __shared__ float bhl[456];
  __shared__ __align__(16) float hl[152];
  int tid = threadIdx.x;
  int seq = blockIdx.x, dir = blockIdx.y;

  for (int idx = tid; idx < 3*150*150; idx += 192){
    int g = idx / 22500, r = idx % 22500;
    int j = r / 150, k = r % 150;
    Wl[(g*150 + j)*KP + k] = (f16)Whh[(size_t)dir*67500 + idx];
  }
  for (int idx = tid; idx < 450; idx += 192) bhl[idx] = bhh[dir*450 + idx];
  if (tid < 152) hl[tid] = 0.f;
  __syncthreads();

  const f16 *wr = nullptr, *wz = nullptr, *wn = nullptr;
  float bR=0.f, bZ=0.f, bN=0.f;
  if (tid < 150){
    wr = &Wl[(0*150+tid)*KP];
    wz = &Wl[(1*150+tid)*KP];
    wn = &Wl[(2*150+tid)*KP];
    bR = bhl[tid]; bZ = bhl[150+tid]; bN = bhl[300+tid];
  }
  float msum = 0.f;
  size_t rowbase = (size_t)seq * T;
  for (int tt = 0; tt < T; tt++){
    int t = dir ? (T-1-tt) : tt;
    float aR=0.f, aZ=0.f, aN=0.f;
    if (tid < 150){
      for (int k = 0; k < 148; k += 4){
        float4 hv = *(const float4*)(hl + k);
        h4 r4 = *(const h4*)(wr + k);
        h4 z4 = *(const h4*)(wz + k);
        h4 n4 = *(const h4*)(wn + k);
        aR += (float)r4.x*hv.x + (float)r4.y*hv.y + (float)r4.z*hv.z + (float)r4.w*hv.w;
        aZ += (float)z4.x*hv.x + (float)z4.y*hv.y + (float)z4.z*hv.z + (float)z4.w*hv.w;
        aN += (float)n4.x*hv.x + (float)n4.y*hv.y + (float)n4.z*hv.z + (float)n4.w*hv.w;
      }
      {
        float2 hv = *(const float2*)(hl + 148);
        h2 r2 = *(const h2*)(wr + 148);
        h2 z2 = *(const h2*)(wz + 148);
        h2 n2 = *(const h2*)(wn + 148);
        aR += (float)r2.x*hv.x + (float)r2.y*hv.y;
        aZ += (float)z2.x*hv.x + (float)z2.y*hv.y;
        aN += (float)n2.x*hv.x + (float)n2.y*hv.y;
      }
    }
    __syncthreads();           // all reads of hl done
    if (tid < 150){
      const float* xp = xs + (rowbase + t)*(size_t)ncols + dir*450;
      float xr = xp[tid], xz = xp[150+tid], xn = xp[300+tid];
      float rr = sigm(xr + aR + bR);
      float zz = sigm(xz + aZ + bZ);
      float nn = tanhf(xn + rr*(aN + bN));
      float hn = (1.f - zz)*nn + zz*hl[tid];
      hl[tid] = hn;
      msum += hn;
      if (ys) ys[(rowbase + t)*(size_t)300 + dir*150 + tid] = hn;
    }
    __syncthreads();
  }
  if (meanOut && tid < 150)
    meanOut[(size_t)seq*300 + dir*150 + tid] = msum / (float)T;
}

// ---------------------------------------------------------------------------
// Big-GRU recurrence, ONE direction per launch. Grid (NJC, 8).
// h transported between blocks via LLC-coherent relaxed atomics (sc1 ops).
// Per-step group barrier: counter per bg in its OWN 256B region (only the
// NJC blocks of one group poll a given line), s_sleep(4) poll interval.
// ---------------------------------------------------------------------------
__global__ __launch_bounds__(192)
void gru_big_k(const float* xs,          // per-dir xs [B*T][3*Hh]
               const float* Whh,         // per-dir [3*Hh][Hh]
               const float* bhh,         // per-dir [3*Hh]
               float* hbuf,              // [2][B][Hh] (no init needed)
               float* meanOut, int mean_stride,   // pre-offset by dir*Hh
               u32* counters,            // 8 x CTR_STRIDE u32 per launch, zeroed
               int T, int Hh, int JB, int KPAD, int NJC, int HS, int reverse)
{
  __shared__ f16 Wl[72480];                 // 144,960 B (art: 3*40*604)
  __shared__ float bhl[136];
  __shared__ __align__(16) float hstage[2400];
  int tid = threadIdx.x;
  int jc = blockIdx.x, bg = blockIdx.y;
  int j0 = jc * JB;
  int H3 = 3 * Hh;

  for (int idx = tid; idx < 3*JB*Hh; idx += 192){
    int row = idx / Hh, k = idx - row*Hh;
    int g = row / JB, jj = row - g*JB;
    Wl[row*KPAD + k] = (f16)Whh[((size_t)g*Hh + j0 + jj)*(size_t)Hh + k];
  }
  for (int idx = tid; idx < 3*JB; idx += 192){
    int g = idx / JB, jj = idx - g*JB;
    bhl[idx] = bhh[g*Hh + j0 + jj];
  }
  __syncthreads();

  u32* cnt = counters + (size_t)bg * CTR_STRIDE;
  int cj = tid >> 2, ckq = tid & 3;
  bool comp = (cj < JB);
  int k0 = 0, k1 = 0;
  if (comp){
    k0 = (ckq == 0) ? 0 : ((ckq*Hh/4) & ~3);
    k1 = (ckq == 3) ? Hh : ((((ckq+1)*Hh)/4) & ~3);
  }
  float br = 0.f, bz = 0.f, bn_ = 0.f;
  if (comp && ckq == 0){
    br = bhl[cj]; bz = bhl[JB+cj]; bn_ = bhl[2*JB+cj];
  }
  float msum[4] = {0.f, 0.f, 0.f, 0.f};

  for (int tt = 0; tt < T; tt++){
    int t = reverse ? (T-1-tt) : tt;
    int par = tt & 1;
    const float* hrd = hbuf + (size_t)par*Bn*Hh;
    float*       hwr = hbuf + (size_t)(1-par)*Bn*Hh;
    if (tt == 0){
      for (int idx = tid; idx < 4*Hh; idx += 192){
        int s = idx / Hh, k = idx - s*Hh;
        hstage[s*HS + k] = 0.f;
      }
    } else {
      for (int idx = tid; idx < 4*Hh; idx += 192){
        int s = idx / Hh, k = idx - s*Hh;
        hstage[s*HS + k] = llc_loadf(&hrd[(size_t)(bg*4 + s)*Hh + k]);
      }
    }
    __syncthreads();
    float a0[4] = {0,0,0,0}, a1[4] = {0,0,0,0}, a2[4] = {0,0,0,0};
    if (comp){
      const f16* pr = &Wl[(0*JB+cj)*KPAD];
      const f16* pz = &Wl[(1*JB+cj)*KPAD];
      const f16* pn = &Wl[(2*JB+cj)*KPAD];
      int k = k0;
      for (; k + 4 <= k1; k += 4){
        h4 r4 = *(const h4*)(pr + k);
        h4 z4 = *(const h4*)(pz + k);
        h4 n4 = *(const h4*)(pn + k);
        float wr0=(float)r4.x, wr1=(float)r4.y, wr2=(float)r4.z, wr3=(float)r4.w;
        float wz0=(float)z4.x, wz1=(float)z4.y, wz2=(float)z4.z, wz3=(float)z4.w;
        float wn0=(float)n4.x, wn1=(float)n4.y, wn2=(float)n4.z, wn3=(float)n4.w;
        #pragma unroll
        for (int s=0;s<4;s++){
          float4 hv = *(const float4*)(hstage + s*HS + k);
          a0[s] += wr0*hv.x + wr1*hv.y + wr2*hv.z + wr3*hv.w;
          a1[s] += wz0*hv.x + wz1*hv.y + wz2*hv.z + wz3*hv.w;
          a2[s] += wn0*hv.x + wn1*hv.y + wn2*hv.z + wn3*hv.w;
        }
      }
      for (; k < k1; k++){
        float wr0=(float)pr[k], wz0=(float)pz[k], wn0=(float)pn[k];
        #pragma unroll
        for (int s=0;s<4;s++){
          float hv = hstage[s*HS + k];
          a0[s] += wr0*hv; a1[s] += wz0*hv; a2[s] += wn0*hv;
        }
      }
    }
    // quad reduction over ckq lanes (quads never straddle waves)
    #pragma unroll
    for (int s=0;s<4;s++){
      a0[s] += __shfl_xor(a0[s], 1); a0[s] += __shfl_xor(a0[s], 2);
      a1[s] += __shfl_xor(a1[s], 1); a1[s] += __shfl_xor(a1[s], 2);
      a2[s] += __shfl_xor(a2[s], 1); a2[s] += __shfl_xor(a2[s], 2);
    }
    if (comp && ckq == 0){
      int jg = j0 + cj;
      #pragma unroll
      for (int s=0;s<4;s++){
        int b = bg*4 + s;
        const float* xp = xs + ((size_t)b*T + t)*(size_t)H3;
        float xr = xp[jg], xz = xp[Hh+jg], xn = xp[2*Hh+jg];
        float rr = sigm(xr + a0[s] + br);
        float zz = sigm(xz + a1[s] + bz);
        float nn = tanhf(xn + rr*(a2[s] + bn_));
        float hn = (1.f - zz)*nn + zz*hstage[s*HS + jg];
        llc_storef(&hwr[(size_t)b*Hh + jg], hn);
        msum[s] += hn;
      }
    }
    __builtin_amdgcn_s_waitcnt(0);   // per-wave: drain this wave's h stores
    __syncthreads();                 // all waves' stores now at LLC
    if (tid == 0){
      __hip_atomic_fetch_add(cnt, 1u, __ATOMIC_RELAXED, __HIP_MEMORY_SCOPE_AGENT);
      u32 target = (u32)NJC * (u32)(tt+1);
      int guard = 0;
      while (__hip_atomic_load(cnt, __ATOMIC_RELAXED, __HIP_MEMORY_SCOPE_AGENT) < target){
        __builtin_amdgcn_s_sleep(4);
        if (++guard > 1000000) break;   // failsafe: wrong result > GPU hang
      }
    }
    __syncthreads();
  }
  if (comp && ckq == 0){
    #pragma unroll
    for (int s=0;s<4;s++)
      meanOut[(size_t)(bg*4+s)*mean_stride + (j0+cj)] = msum[s] / (float)T;
  }
}

// ---------------------------------------------------------------------------
// mask_att + fact_sep fused: per (b, 8-t chunk).
// ---------------------------------------------------------------------------
__global__ __launch_bounds__(256)
void mask_att_k(const float* ctx, const float* vh, float* simOut, float* diffOut)
{
  __shared__ float vhl[50*300];
  __shared__ float ctxl[8*300];
  __shared__ float attl[8*52];
  __shared__ float scenl[8*300];
  __shared__ float ratio[8];
  int tid = threadIdx.x;
  int b = blockIdx.y, tc = blockIdx.x;
  size_t cbase = ((size_t)b*Tn + tc*8) * 300;
  for (int i = tid; i < 15000; i += 256) vhl[i] = vh[(size_t)b*15000 + i];
  for (int i = tid; i < 2400; i += 256)  ctxl[i] = ctx[cbase + i];
  __syncthreads();
  for (int p = tid; p < 400; p += 256){
    int ttl = p / 50, v = p % 50;
    const float* cp = ctxl + ttl*300;
    const float* vp = vhl + v*300;
    float acc = 0.f;
    for (int d = 0; d < 300; d++) acc += cp[d]*vp[d];
    attl[ttl*52 + v] = acc;
  }
  __syncthreads();
  if (tid < 8){
    float mx = -INFINITY;
    for (int v=0; v<50; v++){
      float a = attl[tid*52+v];
      float msk = (a == 0.f) ? -INFINITY : a;
      attl[tid*52+v] = msk;
      mx = fmaxf(mx, msk);
    }
    if (mx == -INFINITY){
      for (int v=0; v<50; v++) attl[tid*52+v] = 0.f;
    } else {
      float sum = 0.f;
      for (int v=0; v<50; v++){ float e = expf(attl[tid*52+v] - mx); attl[tid*52+v] = e; sum += e; }
      float inv = 1.f/sum;
      for (int v=0; v<50; v++) attl[tid*52+v] *= inv;
    }
  }
  __syncthreads();
  for (int p = tid; p < 2400; p += 256){
    int ttl = p / 300, d = p % 300;
    float acc = 0.f;
    for (int v=0; v<50; v++) acc += attl[ttl*52+v] * vhl[v*300+d];
    scenl[p] = acc;
  }
  __syncthreads();
  if (tid < 8){
    float x3=0.f, x4=0.f;
    for (int d=0; d<300; d++){ float s = scenl[tid*300+d]; x3 += ctxl[tid*300+d]*s; x4 += s*s; }
    ratio[tid] = x3 / (x4 + 1e-10f);
  }
  __syncthreads();
  for (int p = tid; p < 2400; p += 256){
    float sim = ratio[p/300] * scenl[p];
    simOut[cbase + p]  = sim;
    diffOut[cbase + p] = ctxl[p] - sim;
  }
}

// ---------------------------------------------------------------------------
// code_wise helpers
// ---------------------------------------------------------------------------
__global__ void rowmax_k(const float* S, float* out, int M, int N){
  int row = blockIdx.x*4 + (threadIdx.x >> 6);
  int lane = threadIdx.x & 63;
  if (row >= M) return;
  float mx = -INFINITY;
  for (int n = lane; n < N; n += 64) mx = fmaxf(mx, S[(size_t)row*N + n]);
  for (int off = 32; off; off >>= 1) mx = fmaxf(mx, __shfl_xor(mx, off, 64));
  if (lane == 0) out[row] = mx;
}

__global__ __launch_bounds__(256)
void softmaxT_k(const float* m, float* att){
  __shared__ float red[256];
  int b = blockIdx.x, tid = threadIdx.x;
  float v1 = m[b*512 + tid], v2 = m[b*512 + 256 + tid];
  red[tid] = fmaxf(v1, v2); __syncthreads();
  for (int s=128; s; s>>=1){ if (tid<s) red[tid] = fmaxf(red[tid], red[tid+s]); __syncthreads(); }
  float M = red[0]; __syncthreads();
  float e1 = expf(v1-M), e2 = expf(v2-M);
  red[tid] = e1+e2; __syncthreads();
  for (int s=128; s; s>>=1){ if (tid<s) red[tid] += red[tid+s]; __syncthreads(); }
  float inv = 1.f / red[0];
  att[b*512+tid] = e1*inv; att[b*512+256+tid] = e2*inv;
}

__global__ __launch_bounds__(256)
void wsum_k(const float* att, const float* dh, float* out){
  int b = blockIdx.x, tid = threadIdx.x;
  for (int d = tid; d < 300; d += 256){
    float acc = 0.f;
    for (int t = 0; t < 512; t++)
      acc += att[b*512+t] * dh[((size_t)b*512 + t)*300 + d];
    out[b*300+d] = acc;
  }
}

// ---------------------------------------------------------------------------
// graph_decomp helpers
// ---------------------------------------------------------------------------
__global__ void count_k(const int* src, int E, float* counts){
  int e = blockIdx.x*256 + threadIdx.x;
  if (e < E) atomicAdd(&counts[src[e]], 1.f);
}
__global__ void coef_k(const float* L, const int* src, const int* dst, int E, float* coef){
  int e = blockIdx.x*4 + (threadIdx.x >> 6);
  int lane = threadIdx.x & 63;
  if (e >= E) return;
  const float* Li = L + (size_t)src[e]*300;
  const float* Lj = L + (size_t)dst[e]*300;
  float num = 0.f, den = 0.f;
  for (int d = lane; d < 300; d += 64){ float lj = Lj[d]; num += Li[d]*lj; den += lj*lj; }
  for (int off = 32; off; off >>= 1){ num += __shfl_xor(num, off, 64); den += __shfl_xor(den, off, 64); }
  if (lane == 0) coef[e] = num / (den + 1e-10f);
}
__global__ void agg_k(const float* L, const int* src, const int* dst, const float* coef, int E, float* agg){
  int e = blockIdx.x;
  float c = coef[e];
  const float* Lj = L + (size_t)dst[e]*300;
  float* ag = agg + (size_t)src[e]*300;
  for (int d = threadIdx.x; d < 300; d += 256) atomicAdd(&ag[d], c*Lj[d]);
}
__global__ void upd_k(const float* L, const float* agg, const float* counts, float* out, int n){
  int i = blockIdx.x;
  float c = counts[i];
  for (int d = threadIdx.x; d < 300; d += 256){
    float v = L[(size_t)i*300+d];
    out[(size_t)i*300+d] = (c > 0.f) ? v - agg[(size_t)i*300+d]/fmaxf(c, 1.f) : v;
  }
}

// ---------------------------------------------------------------------------
// classifier heads (write f32 logits straight into d_out), argmax, gather
// ---------------------------------------------------------------------------
__global__ __launch_bounds__(128)
void logits_k(const float* A0, const float* A1, const float* A2, int srcw,
              const float* W, const float* bias, int C, int K,
              float* outF){
  int b = blockIdx.x, tid = threadIdx.x;
  for (int c = tid; c < C; c += 128){
    float acc = bias[c];
    const float* wp = W + (size_t)c*K;
    for (int k = 0; k < K; k++){
      int s = k / srcw; int kk = k - s*srcw;
      const float* Ap = (s==0) ? A0 : ((s==1) ? A1 : A2);
      acc += Ap[(size_t)b*srcw + kk] * wp[k];
    }
    outF[b*C + c] = acc;
  }
}
__global__ void argmax_k(const float* lf, int C, int* pred){
  int b = threadIdx.x;
  if (b < 32){
    const float* p = lf + (size_t)b*C;
    int best = 0; float bv = p[0];
    for (int c = 1; c < C; c++){ float v = p[c]; if (v > bv){ bv = v; best = c; } }
    pred[b] = best;
  }
}
__global__ void vtok_k(const int* table, const int* pred, int* vt, int L){
  int i = blockIdx.x*256 + threadIdx.x;
  if (i < 32*L) vt[i] = table[pred[i/L]*L + i%L];
}

// ---------------------------------------------------------------------------
extern "C" void kernel_launch(void* const* d_in, const int* in_sizes, int n_in,
                              void* d_out, int out_size, void* d_ws, size_t ws_size,
                              hipStream_t stream)
{
  (void)in_sizes; (void)n_in; (void)out_size;
  const float* E        = (const float*)d_in[0];
  const int* chTok    = (const int*)d_in[1];
  const int* arTok    = (const int*)d_in[2];
  const int* docs     = (const int*)d_in[3];
  const int* chVerd   = (const int*)d_in[4];
  const int* arVerd   = (const int*)d_in[5];
  const int* c_src    = (const int*)d_in[6];
  const int* c_dst    = (const int*)d_in[7];
  const int* a_src    = (const int*)d_in[8];
  const int* a_dst    = (const int*)d_in[9];
  const float* enc_Wih  = (const float*)d_in[10];
  const float* enc_Whh  = (const float*)d_in[11];
  const float* enc_bih  = (const float*)d_in[12];
  const float* enc_bhh  = (const float*)d_in[13];
  const float* ech_Wih  = (const float*)d_in[14];
  const float* ech_Whh  = (const float*)d_in[15];
  const float* ech_bih  = (const float*)d_in[16];
  const float* ech_bhh  = (const float*)d_in[17];
  const float* term_Wih = (const float*)d_in[18];
  const float* term_Whh = (const float*)d_in[19];
  const float* term_bih = (const float*)d_in[20];
  const float* term_bhh = (const float*)d_in[21];
  const float* art_Wih  = (const float*)d_in[22];
  const float* art_Whh  = (const float*)d_in[23];
  const float* art_bih  = (const float*)d_in[24];
  const float* art_bhh  = (const float*)d_in[25];
  const float* W_charge = (const float*)d_in[26];
  const float* b_charge = (const float*)d_in[27];
  const float* W_article= (const float*)d_in[28];
  const float* b_article= (const float*)d_in[29];
  const float* W_time   = (const float*)d_in[30];
  const float* b_time   = (const float*)d_in[31];
  float* out = (float*)d_out;
  float* OUTC = out;            // [32][119]
  float* OUTA = out + 3808;     // [32][103]
  float* OUTT = out + 7104;     // [32][11]

  char* wsb = (char*)d_ws;
  size_t off = 0;
  auto alloc = [&](size_t nf)->float* {
    float* p = (float*)(wsb + off);
    off += ((nf*4 + 255) & ~(size_t)255);
    return p;
  };
  float* ARENA = alloc(29491200ULL);        // 16384*1800 max (118 MB)
  float* SBUF  = ARENA;                     // alias: disjoint lifetime
  float* DH    = alloc(4915200);            // d_hidden [32][512][300]
  float* ADC   = alloc(4915200);            // adc, later dsc
  float* SEC   = alloc(4915200);
  float* SSC   = alloc(4915200);
  float* VHYS  = alloc(480000);             // [32][50][300]
  float* MECH  = alloc(66600);              // encch means [222][300]
  float* LC1   = alloc(35700);
  float* LC0   = alloc(35700);
  float* LA1   = alloc(30900);
  float* LA0   = alloc(30900);
  float* AGG   = alloc(35700);
  float* CNTS  = alloc(256);                // counts_c @0, counts_a @128
  float* COEF  = alloc(640);
  float* DHC   = alloc(9600);
  float* DA    = alloc(9600);
  float* DHNA  = alloc(9600);
  float* DB    = alloc(9600);
  float* MDH   = alloc(9600);               // mean_t d_hidden [32][300]
  float* MFA   = alloc(38400);              // fa mean [32][1200]
  float* MTH   = alloc(28800);              // th mean [32][900]
  float* RB    = alloc(115200);             // art rowbias [32][3600]
  float* RMX   = alloc(16384);
  float* ATTB  = alloc(16384);
  float* HBUF  = alloc(38400);              // [2][32][600] max
  u32*   CTRS  = (u32*)alloc(4*8*CTR_STRIDE);  // 4 launches x 8 groups x 256B
  int*   PREDC = (int*)alloc(64);
  int*   PREDA = (int*)alloc(64);
  int*   VTOK  = (int*)alloc(1600);
  int*   TCC   = (int*)alloc(11104);

  if (off > ws_size) return;   // diagnostic: leaves out==0 -> absmax==max|ref|

  hipMemsetAsync(CTRS, 0, 4*8*CTR_STRIDE*4, stream);
  hipMemsetAsync(CNTS, 0, 256*4, stream);

  // --- encch on charge+article token sequences (222 seqs, L=50) ---
  hipMemcpyAsync(TCC, chTok, NCn*LCn*4, hipMemcpyDeviceToDevice, stream);
  hipMemcpyAsync(TCC + NCn*LCn, arTok, NAn*LCn*4, hipMemcpyDeviceToDevice, stream);
  {
    dim3 g((900+127)/128, (11100+127)/128);
    gemm_k<1><<<g,256,0,stream>>>(nullptr,nullptr,nullptr, E, TCC,
        ech_Wih, 200, 0,0,0, ech_bih, nullptr, 1, 1, ARENA, 11100, 900, 200);
  }
  gru_small_k<<<dim3(222,2),192,0,stream>>>(ARENA, 900, ech_Whh, ech_bhh, nullptr, MECH, 50);

  // --- enc on documents ---
  {
    dim3 g((900+127)/128, (16384+127)/128);
    gemm_k<1><<<g,256,0,stream>>>(nullptr,nullptr,nullptr, E, docs,
        enc_Wih, 200, 0,0,0, enc_bih, nullptr, 1, 1, ARENA, 16384, 900, 200);
  }
  gru_small_k<<<dim3(32,2),192,0,stream>>>(ARENA, 900, enc_Whh, enc_bhh, DH, MDH, 512);

  // --- graph_decomp (charge, article), 2 layers each ---
  count_k<<<3,256,0,stream>>>(c_src, ECn, CNTS);
  count_k<<<2,256,0,stream>>>(a_src, EAn, CNTS+128);
  coef_k<<<150,256,0,stream>>>(MECH, c_src, c_dst, ECn, COEF);
  hipMemsetAsync(AGG, 0, 35700*4, stream);
  agg_k<<<ECn,256,0,stream>>>(MECH, c_src, c_dst, COEF, ECn, AGG);
  upd_k<<<NCn,256,0,stream>>>(MECH, AGG, CNTS, LC1, NCn);
  coef_k<<<150,256,0,stream>>>(LC1, c_src, c_dst, ECn, COEF);
  hipMemsetAsync(AGG, 0, 35700*4, stream);
  agg_k<<<ECn,256,0,stream>>>(LC1, c_src, c_dst, COEF, ECn, AGG);
  upd_k<<<NCn,256,0,stream>>>(LC1, AGG, CNTS, LC0, NCn);

  const float* MEAR = MECH + (size_t)NCn*300;
  coef_k<<<125,256,0,stream>>>(MEAR, a_src, a_dst, EAn, COEF);
  hipMemsetAsync(AGG, 0, 30900*4, stream);
  agg_k<<<EAn,256,0,stream>>>(MEAR, a_src, a_dst, COEF, EAn, AGG);
  upd_k<<<NAn,256,0,stream>>>(MEAR, AGG, CNTS+128, LA1, NAn);
  coef_k<<<125,256,0,stream>>>(LA1, a_src, a_dst, EAn, COEF);
  hipMemsetAsync(AGG, 0, 30900*4, stream);
  agg_k<<<EAn,256,0,stream>>>(LA1, a_src, a_dst, COEF, EAn, AGG);
  upd_k<<<NAn,256,0,stream>>>(LA1, AGG, CNTS+128, LA0, NAn);

  // --- code_wise x4 (S-buffer aliased into ARENA) ---
  auto codewise = [&](const float* q, int Nq, float* outv){
    dim3 g((Nq+127)/128, 128);
    gemm_k<0><<<g,256,0,stream>>>(DH, nullptr, nullptr, nullptr, nullptr,
        q, 300, 0,0,0, nullptr, nullptr, 1, 1, SBUF, 16384, Nq, 300);
    rowmax_k<<<4096,256,0,stream>>>(SBUF, RMX, 16384, Nq);
    softmaxT_k<<<32,256,0,stream>>>(RMX, ATTB);
    wsum_k<<<32,256,0,stream>>>(ATTB, DH, outv);
  };
  codewise(LC0,  NCn, DHC);    // new_charge
  codewise(MECH, NCn, DA);     // ori charge
  codewise(LA0,  NAn, DHNA);   // new_article
  codewise(MEAR, NAn, DB);     // ori article

  // --- charge head ---
  logits_k<<<32,128,0,stream>>>(MDH, DHC, DA, 300, W_charge, b_charge, NCn, 900, OUTC);
  argmax_k<<<1,64,0,stream>>>(OUTC, NCn, PREDC);

  // --- fact_sep #1 ---
  vtok_k<<<7,256,0,stream>>>(chVerd, PREDC, VTOK, LVn);
  {
    dim3 g((900+127)/128, (1600+127)/128);
    gemm_k<1><<<g,256,0,stream>>>(nullptr,nullptr,nullptr, E, VTOK,
        enc_Wih, 200, 0,0,0, enc_bih, nullptr, 1, 1, ARENA, 1600, 900, 200);
  }
  gru_small_k<<<dim3(32,2),192,0,stream>>>(ARENA, 900, enc_Whh, enc_bhh, VHYS, nullptr, 50);
  mask_att_k<<<dim3(64,32),256,0,stream>>>(DH, VHYS, ADC, SEC);

  // --- article bigru: rowbias (t-constant concat halves), then per-dir ---
  {
    dim3 g((3600+127)/128, 1);
    gemm_k<0><<<g,256,0,stream>>>(DHNA, DB, nullptr, nullptr, nullptr,
        art_Wih, 1200, 300, 900, 0, art_bih, nullptr, 1, 1, RB, 32, 3600, 600);
  }
  for (int dir = 0; dir < 2; dir++){
    dim3 g((1800+127)/128, 128);
    gemm_k<0><<<g,256,0,stream>>>(DH, ADC, nullptr, nullptr, nullptr,
        art_Wih + (size_t)dir*1800*1200, 1200, 0, 600, 0,
        nullptr, RB + dir*1800, 512, 3600, ARENA, 16384, 1800, 600);
    gru_big_k<<<dim3(15,8),192,0,stream>>>(ARENA,
        art_Whh + (size_t)dir*1800*600, art_bhh + dir*1800,
        HBUF, MFA + dir*600, 1200, CTRS + (size_t)dir*8*CTR_STRIDE,
        512, 600, 40, 604, 15, 600, dir);
  }
  logits_k<<<32,128,0,stream>>>(MFA, nullptr, nullptr, 1200, W_article, b_article, NAn, 1200, OUTA);
  argmax_k<<<1,64,0,stream>>>(OUTA, NAn, PREDA);

  // --- fact_sep #2 (context = sec_vector) ---
  vtok_k<<<7,256,0,stream>>>(arVerd, PREDA, VTOK, LVn);
  {
    dim3 g((900+127)/128, (1600+127)/128);
    gemm_k<1><<<g,256,0,stream>>>(nullptr,nullptr,nullptr, E, VTOK,
        enc_Wih, 200, 0,0,0, enc_bih, nullptr, 1, 1, ARENA, 1600, 900, 200);
  }
  gru_small_k<<<dim3(32,2),192,0,stream>>>(ARENA, 900, enc_Whh, enc_bhh, VHYS, nullptr, 50);
  mask_att_k<<<dim3(64,32),256,0,stream>>>(SEC, VHYS, SSC, ADC);   // ssc, dsc(=ADC)

  // --- term bigru, per-dir ---
  for (int dir = 0; dir < 2; dir++){
    dim3 g((1350+127)/128, 128);
    gemm_k<0><<<g,256,0,stream>>>(DH, SSC, ADC, nullptr, nullptr,
        term_Wih + (size_t)dir*1350*900, 900, 0, 300, 600,
        term_bih + dir*1350, nullptr, 1, 1, ARENA, 16384, 1350, 900);
    gru_big_k<<<dim3(10,8),192,0,stream>>>(ARENA,
        term_Whh + (size_t)dir*1350*450, term_bhh + dir*1350,
        HBUF, MTH + dir*450, 900, CTRS + (size_t)(2+dir)*8*CTR_STRIDE,
        512, 450, 45, 460, 10, 452, dir);
  }
  logits_k<<<32,128,0,stream>>>(MTH, nullptr, nullptr, 900, W_time, b_time, NTn, 900, OUTT);
}

// Round 6
// 25432.811 us; speedup vs baseline: 1.9998x; 1.6438x over previous
//
#include <hip/hip_runtime.h>
#include <stdint.h>
#include <math.h>

typedef unsigned int u32;
typedef _Float16 f16;
typedef _Float16 h4 __attribute__((ext_vector_type(4)));
typedef _Float16 h2 __attribute__((ext_vector_type(2)));

// Problem constants
#define Vn     50000
#define DEMBn  200
#define Hn     150
#define NCn    119
#define NAn    103
#define NTn    11
#define Bn     32
#define Tn     512
#define LCn    50
#define LVn    50
#define ECn    600
#define EAn    500

#define CTR_STRIDE 64   // u32s = 256 B per barrier-group counter region
#define IDIV 1073741824 // identity arow mapping

__device__ __forceinline__ float sigm(float x){ return 1.0f / (1.0f + expf(-x)); }

// LLC-coherent agent-scope ops. Loads: sc-flagged (bypass L1/L2, served at LLC).
// Stores: atomic_exchange — the RMW executes AT the LLC and allocates the
// line there, so the vmcnt drain acks at LLC and consumer loads hit LLC
// (round-5 WRITE_SIZE=40MB showed plain sc1 stores drained to HBM).
__device__ __forceinline__ float llc_loadf(const float* p){
  u32 v = __hip_atomic_load((const u32*)p, __ATOMIC_RELAXED, __HIP_MEMORY_SCOPE_AGENT);
  union { u32 i; float f; } u; u.i = v; return u.f;
}
__device__ __forceinline__ void llc_swapf(float* p, float v){
  union { float f; u32 i; } u; u.f = v;
  (void)__hip_atomic_exchange((u32*)p, u.i, __ATOMIC_RELAXED, __HIP_MEMORY_SCOPE_AGENT);
}

// ---------------------------------------------------------------------------
// Tiled fp32 GEMM: C[M][N] = A[arow(m)][K] @ B[N][K]^T (+bias +rowbias)
// AMODE 0: A = up to 3 f32 sources, each [...][300]; source s = k/300;
//          B column for element k is bc[s] + (k - s*300).
//          A row = (m/arow_div)*arow_stride + (m%arow_div) + arow_off
//          (identity: arow_div=IDIV, stride=0, off=0) — lets xs be built in
//          half-T chunks for the time-sliced bigru.
// AMODE 1: A[m][k] = Etab[tok[m]][k] (f32 embedding gather), B col = k
// ---------------------------------------------------------------------------
template<int AMODE>
__global__ __launch_bounds__(256)
void gemm_k(const float* A0, const float* A1, const float* A2,
            const float* Etab, const int* tok,
            const float* Bm, int ldb, int bc0, int bc1, int bc2,
            const float* bias, const float* rowbias, int rb_div, int rb_stride,
            int arow_div, int arow_stride, int arow_off,
            float* C, int M, int N, int K)
{
  __shared__ float As[8][132];
  __shared__ float Bs[8][132];
  __shared__ int tokS[128];
  int tid = threadIdx.x;
  int m0 = blockIdx.y * 128, n0 = blockIdx.x * 128;
  if (AMODE == 1){
    for (int i = tid; i < 128; i += 256){
      int m = m0 + i;
      tokS[i] = (m < M) ? tok[m] : 0;
    }
  }
  __syncthreads();
  float acc[8][8];
  #pragma unroll
  for (int i=0;i<8;i++)
    #pragma unroll
    for (int j=0;j<8;j++) acc[i][j] = 0.f;

  int tx = tid & 15, ty = tid >> 4;

  for (int k0 = 0; k0 < K; k0 += 8){
    #pragma unroll
    for (int r = 0; r < 4; r++){
      int i = tid + 256*r;          // [0,1024)
      int ml = i >> 3, kl = i & 7;
      int k = k0 + kl;
      {
        int m = m0 + ml;
        float v = 0.f;
        if (m < M && k < K){
          if (AMODE == 0){
            int s = k / 300; int kk = k - s*300;
            const float* Ap = (s==0) ? A0 : ((s==1) ? A1 : A2);
            int ar = (m / arow_div)*arow_stride + (m % arow_div) + arow_off;
            v = Ap[(size_t)ar*300 + kk];
          } else {
            v = Etab[(size_t)tokS[ml]*DEMBn + k];
          }
        }
        As[kl][ml] = v;
      }
      {
        int n = n0 + ml;
        float v = 0.f;
        if (n < N && k < K){
          int col;
          if (AMODE == 0){ int s = k / 300; int kk = k - s*300; col = ((s==0)?bc0:((s==1)?bc1:bc2)) + kk; }
          else col = k;
          v = Bm[(size_t)n*ldb + col];
        }
        Bs[kl][ml] = v;
      }
    }
    __syncthreads();
    #pragma unroll
    for (int kk = 0; kk < 8; kk++){
      float a[8], b[8];
      #pragma unroll
      for (int i=0;i<8;i++) a[i] = As[kk][ty*8+i];
      #pragma unroll
      for (int i=0;i<8;i++) b[i] = Bs[kk][tx*8+i];
      #pragma unroll
      for (int i=0;i<8;i++)
        #pragma unroll
        for (int j=0;j<8;j++) acc[i][j] += a[i]*b[j];
    }
    __syncthreads();
  }
  #pragma unroll
  for (int i=0;i<8;i++){
    int m = m0 + ty*8 + i; if (m >= M) continue;
    #pragma unroll
    for (int j=0;j<8;j++){
      int n = n0 + tx*8 + j; if (n >= N) continue;
      float v = acc[i][j];
      if (bias)    v += bias[n];
      if (rowbias) v += rowbias[(size_t)(m / rb_div)*rb_stride + n];
      C[(size_t)m*N + n] = v;
    }
  }
}

// ---------------------------------------------------------------------------
// Small-GRU recurrence (H=150): one block per (seq, dir). Whh f16 in LDS.
// ---------------------------------------------------------------------------
__global__ __launch_bounds__(192)
void gru_small_k(const float* xs, int ncols,
                 const float* Whh, const float* bhh,
                 float* ys, float* meanOut, int T)
{
  const int KP = 156;
  __shared__ f16 Wl[3*150*156];     // 140,400 B
  __shared__ float bhl[456];
  __shared__ __align__(16) float hl[152];
  int tid = threadIdx.x;
  int seq = blockIdx.x, dir = blockIdx.y;

  for (int idx = tid; idx < 3*150*150; idx += 192){
    int g = idx / 22500, r = idx % 22500;
    int j = r / 150, k = r % 150;
    Wl[(g*150 + j)*KP + k] = (f16)Whh[(size_t)dir*67500 + idx];
  }
  for (int idx = tid; idx < 450; idx += 192) bhl[idx] = bhh[dir*450 + idx];
  if (tid < 152) hl[tid] = 0.f;
  __syncthreads();

  const f16 *wr = nullptr, *wz = nullptr, *wn = nullptr;
  float bR=0.f, bZ=0.f, bN=0.f;
  if (tid < 150){
    wr = &Wl[(0*150+tid)*KP];
    wz = &Wl[(1*150+tid)*KP];
    wn = &Wl[(2*150+tid)*KP];
    bR = bhl[tid]; bZ = bhl[150+tid]; bN = bhl[300+tid];
  }
  float msum = 0.f;
  size_t rowbase = (size_t)seq * T;
  for (int tt = 0; tt < T; tt++){
    int t = dir ? (T-1-tt) : tt;
    float aR=0.f, aZ=0.f, aN=0.f;
    if (tid < 150){
      for (int k = 0; k < 148; k += 4){
        float4 hv = *(const float4*)(hl + k);
        h4 r4 = *(const h4*)(wr + k);
        h4 z4 = *(const h4*)(wz + k);
        h4 n4 = *(const h4*)(wn + k);
        aR += (float)r4.x*hv.x + (float)r4.y*hv.y + (float)r4.z*hv.z + (float)r4.w*hv.w;
        aZ += (float)z4.x*hv.x + (float)z4.y*hv.y + (float)z4.z*hv.z + (float)z4.w*hv.w;
        aN += (float)n4.x*hv.x + (float)n4.y*hv.y + (float)n4.z*hv.z + (float)n4.w*hv.w;
      }
      {
        float2 hv = *(const float2*)(hl + 148);
        h2 r2 = *(const h2*)(wr + 148);
        h2 z2 = *(const h2*)(wz + 148);
        h2 n2 = *(const h2*)(wn + 148);
        aR += (float)r2.x*hv.x + (float)r2.y*hv.y;
        aZ += (float)z2.x*hv.x + (float)z2.y*hv.y;
        aN += (float)n2.x*hv.x + (float)n2.y*hv.y;
      }
    }
    __syncthreads();           // all reads of hl done
    if (tid < 150){
      const float* xp = xs + (rowbase + t)*(size_t)ncols + dir*450;
      float xr = xp[tid], xz = xp[150+tid], xn = xp[300+tid];
      float rr = sigm(xr + aR + bR);
      float zz = sigm(xz + aZ + bZ);
      float nn = tanhf(xn + rr*(aN + bN));
      float hn = (1.f - zz)*nn + zz*hl[tid];
      hl[tid] = hn;
      msum += hn;
      if (ys) ys[(rowbase + t)*(size_t)300 + dir*150 + tid] = hn;
    }
    __syncthreads();
  }
  if (meanOut && tid < 150)
    meanOut[(size_t)seq*300 + dir*150 + tid] = msum / (float)T;
}

// ---------------------------------------------------------------------------
// Big-GRU recurrence, BOTH dirs per launch (grid NJC x 8 x 2), time-sliced:
// processes TC steps starting at global step t0 (xs built per half-T chunk:
// xs0 = fwd-dir chunk, xs1 = rev-dir chunk, each [B][TC][3*Hh]).
// h carried across launches in hbuf[par][dir]. meanOut accumulated (+=).
// Transport: llc_loadf / llc_swapf (LLC-allocating). Barrier: per-(dir,bg)
// counter in its own 256B region; xs prefetched at step top.
// ---------------------------------------------------------------------------
__global__ __launch_bounds__(192)
void gru_big_k(const float* xs0, const float* xs1,
               const float* Whh,         // [2][3*Hh][Hh]
               const float* bhh,         // [2][3*Hh]
               float* hbuf,              // [2][2][B][Hh]
               float* meanOut, int mean_stride,   // += msum/TT at col dir*Hh+j
               u32* counters,            // 16 x CTR_STRIDE u32, zeroed
               int TT, int TC, int t0,
               int Hh, int JB, int KPAD, int NJC, int HS)
{
  __shared__ f16 Wl[72480];                 // 144,960 B (art: 3*40*604)
  __shared__ float bhl[136];
  __shared__ __align__(16) float hstage[2400];
  int tid = threadIdx.x;
  int jc = blockIdx.x, bg = blockIdx.y, dir = blockIdx.z;
  int j0 = jc * JB;
  int H3 = 3 * Hh;
  const float* Wd = Whh + (size_t)dir*H3*Hh;
  const float* bd = bhh + (size_t)dir*H3;
  const float* xs = dir ? xs1 : xs0;
  int xoff = dir ? (TT - TC - t0) : t0;

  for (int idx = tid; idx < 3*JB*Hh; idx += 192){
    int row = idx / Hh, k = idx - row*Hh;
    int g = row / JB, jj = row - g*JB;
    Wl[row*KPAD + k] = (f16)Wd[((size_t)g*Hh + j0 + jj)*(size_t)Hh + k];
  }
  for (int idx = tid; idx < 3*JB; idx += 192){
    int g = idx / JB, jj = idx - g*JB;
    bhl[idx] = bd[g*Hh + j0 + jj];
  }
  __syncthreads();

  u32* cnt = counters + (size_t)(dir*8 + bg) * CTR_STRIDE;
  int cj = tid >> 2, ckq = tid & 3;
  bool comp = (cj < JB);
  int k0 = 0, k1 = 0;
  if (comp){
    k0 = (ckq == 0) ? 0 : ((ckq*Hh/4) & ~3);
    k1 = (ckq == 3) ? Hh : ((((ckq+1)*Hh)/4) & ~3);
  }
  float br = 0.f, bz = 0.f, bn_ = 0.f;
  if (comp && ckq == 0){
    br = bhl[cj]; bz = bhl[JB+cj]; bn_ = bhl[2*JB+cj];
  }
  float msum[4] = {0.f, 0.f, 0.f, 0.f};
  int jg = j0 + cj;

  for (int tt = 0; tt < TC; tt++){
    int g = t0 + tt;                       // global step index
    int t = dir ? (TT-1-g) : g;            // time position consumed
    int par = g & 1;
    const float* hrd = hbuf + (size_t)(par*2 + dir)*Bn*Hh;
    float*       hwr = hbuf + (size_t)((1-par)*2 + dir)*Bn*Hh;

    // xs prefetch (h-independent): issue before the gemv to hide HBM latency
    float xr[4], xz[4], xn[4];
    if (comp && ckq == 0){
      #pragma unroll
      for (int s=0;s<4;s++){
        const float* xp = xs + ((size_t)(bg*4+s)*TC + (t - xoff))*(size_t)H3;
        xr[s] = xp[jg]; xz[s] = xp[Hh+jg]; xn[s] = xp[2*Hh+jg];
      }
    }

    if (g == 0){
      for (int idx = tid; idx < 4*Hh; idx += 192){
        int s = idx / Hh, k = idx - s*Hh;
        hstage[s*HS + k] = 0.f;
      }
    } else {
      for (int idx = tid; idx < 4*Hh; idx += 192){
        int s = idx / Hh, k = idx - s*Hh;
        hstage[s*HS + k] = llc_loadf(&hrd[(size_t)(bg*4 + s)*Hh + k]);
      }
    }
    __syncthreads();
    float a0[4] = {0,0,0,0}, a1[4] = {0,0,0,0}, a2[4] = {0,0,0,0};
    if (comp){
      const f16* pr = &Wl[(0*JB+cj)*KPAD];
      const f16* pz = &Wl[(1*JB+cj)*KPAD];
      const f16* pn = &Wl[(2*JB+cj)*KPAD];
      int k = k0;
      for (; k + 4 <= k1; k += 4){
        h4 r4 = *(const h4*)(pr + k);
        h4 z4 = *(const h4*)(pz + k);
        h4 n4 = *(const h4*)(pn + k);
        float wr0=(float)r4.x, wr1=(float)r4.y, wr2=(float)r4.z, wr3=(float)r4.w;
        float wz0=(float)z4.x, wz1=(float)z4.y, wz2=(float)z4.z, wz3=(float)z4.w;
        float wn0=(float)n4.x, wn1=(float)n4.y, wn2=(float)n4.z, wn3=(float)n4.w;
        #pragma unroll
        for (int s=0;s<4;s++){
          float4 hv = *(const float4*)(hstage + s*HS + k);
          a0[s] += wr0*hv.x + wr1*hv.y + wr2*hv.z + wr3*hv.w;
          a1[s] += wz0*hv.x + wz1*hv.y + wz2*hv.z + wz3*hv.w;
          a2[s] += wn0*hv.x + wn1*hv.y + wn2*hv.z + wn3*hv.w;
        }
      }
      for (; k < k1; k++){
        float wr0=(float)pr[k], wz0=(float)pz[k], wn0=(float)pn[k];
        #pragma unroll
        for (int s=0;s<4;s++){
          float hv = hstage[s*HS + k];
          a0[s] += wr0*hv; a1[s] += wz0*hv; a2[s] += wn0*hv;
        }
      }
    }
    // quad reduction over ckq lanes (quads never straddle waves)
    #pragma unroll
    for (int s=0;s<4;s++){
      a0[s] += __shfl_xor(a0[s], 1); a0[s] += __shfl_xor(a0[s], 2);
      a1[s] += __shfl_xor(a1[s], 1); a1[s] += __shfl_xor(a1[s], 2);
      a2[s] += __shfl_xor(a2[s], 1); a2[s] += __shfl_xor(a2[s], 2);
    }
    if (comp && ckq == 0){
      #pragma unroll
      for (int s=0;s<4;s++){
        int b = bg*4 + s;
        float rr = sigm(xr[s] + a0[s] + br);
        float zz = sigm(xz[s] + a1[s] + bz);
        float nn = tanhf(xn[s] + rr*(a2[s] + bn_));
        float hn = (1.f - zz)*nn + zz*hstage[s*HS + jg];
        llc_swapf(&hwr[(size_t)b*Hh + jg], hn);
        msum[s] += hn;
      }
    }
    __builtin_amdgcn_s_waitcnt(0);   // per-wave: drain h swaps (ack at LLC)
    __syncthreads();
    if (tid == 0){
      __hip_atomic_fetch_add(cnt, 1u, __ATOMIC_RELAXED, __HIP_MEMORY_SCOPE_AGENT);
      u32 target = (u32)NJC * (u32)(tt+1);
      int guard = 0;
      while (__hip_atomic_load(cnt, __ATOMIC_RELAXED, __HIP_MEMORY_SCOPE_AGENT) < target){
        __builtin_amdgcn_s_sleep(2);
        if (++guard > 2000000) break;   // failsafe: wrong result > GPU hang
      }
    }
    __syncthreads();
  }
  if (comp && ckq == 0){
    #pragma unroll
    for (int s=0;s<4;s++){
      float* mp = meanOut + (size_t)(bg*4+s)*mean_stride + dir*Hh + jg;
      *mp += msum[s] / (float)TT;
    }
  }
}

// ---------------------------------------------------------------------------
// mask_att + fact_sep fused: per (b, 8-t chunk).
// ---------------------------------------------------------------------------
__global__ __launch_bounds__(256)
void mask_att_k(const float* ctx, const float* vh, float* simOut, float* diffOut)
{
  __shared__ float vhl[50*300];
  __shared__ float ctxl[8*300];
  __shared__ float attl[8*52];
  __shared__ float scenl[8*300];
  __shared__ float ratio[8];
  int tid = threadIdx.x;
  int b = blockIdx.y, tc = blockIdx.x;
  size_t cbase = ((size_t)b*Tn + tc*8) * 300;
  for (int i = tid; i < 15000; i += 256) vhl[i] = vh[(size_t)b*15000 + i];
  for (int i = tid; i < 2400; i += 256)  ctxl[i] = ctx[cbase + i];
  __syncthreads();
  for (int p = tid; p < 400; p += 256){
    int ttl = p / 50, v = p % 50;
    const float* cp = ctxl + ttl*300;
    const float* vp = vhl + v*300;
    float acc = 0.f;
    for (int d = 0; d < 300; d++) acc += cp[d]*vp[d];
    attl[ttl*52 + v] = acc;
  }
  __syncthreads();
  if (tid < 8){
    float mx = -INFINITY;
    for (int v=0; v<50; v++){
      float a = attl[tid*52+v];
      float msk = (a == 0.f) ? -INFINITY : a;
      attl[tid*52+v] = msk;
      mx = fmaxf(mx, msk);
    }
    if (mx == -INFINITY){
      for (int v=0; v<50; v++) attl[tid*52+v] = 0.f;
    } else {
      float sum = 0.f;
      for (int v=0; v<50; v++){ float e = expf(attl[tid*52+v] - mx); attl[tid*52+v] = e; sum += e; }
      float inv = 1.f/sum;
      for (int v=0; v<50; v++) attl[tid*52+v] *= inv;
    }
  }
  __syncthreads();
  for (int p = tid; p < 2400; p += 256){
    int ttl = p / 300, d = p % 300;
    float acc = 0.f;
    for (int v=0; v<50; v++) acc += attl[ttl*52+v] * vhl[v*300+d];
    scenl[p] = acc;
  }
  __syncthreads();
  if (tid < 8){
    float x3=0.f, x4=0.f;
    for (int d=0; d<300; d++){ float s = scenl[tid*300+d]; x3 += ctxl[tid*300+d]*s; x4 += s*s; }
    ratio[tid] = x3 / (x4 + 1e-10f);
  }
  __syncthreads();
  for (int p = tid; p < 2400; p += 256){
    float sim = ratio[p/300] * scenl[p];
    simOut[cbase + p]  = sim;
    diffOut[cbase + p] = ctxl[p] - sim;
  }
}

// ---------------------------------------------------------------------------
// code_wise helpers
// ---------------------------------------------------------------------------
__global__ void rowmax_k(const float* S, float* out, int M, int N){
  int row = blockIdx.x*4 + (threadIdx.x >> 6);
  int lane = threadIdx.x & 63;
  if (row >= M) return;
  float mx = -INFINITY;
  for (int n = lane; n < N; n += 64) mx = fmaxf(mx, S[(size_t)row*N + n]);
  for (int off = 32; off; off >>= 1) mx = fmaxf(mx, __shfl_xor(mx, off, 64));
  if (lane == 0) out[row] = mx;
}

__global__ __launch_bounds__(256)
void softmaxT_k(const float* m, float* att){
  __shared__ float red[256];
  int b = blockIdx.x, tid = threadIdx.x;
  float v1 = m[b*512 + tid], v2 = m[b*512 + 256 + tid];
  red[tid] = fmaxf(v1, v2); __syncthreads();
  for (int s=128; s; s>>=1){ if (tid<s) red[tid] = fmaxf(red[tid], red[tid+s]); __syncthreads(); }
  float M = red[0]; __syncthreads();
  float e1 = expf(v1-M), e2 = expf(v2-M);
  red[tid] = e1+e2; __syncthreads();
  for (int s=128; s; s>>=1){ if (tid<s) red[tid] += red[tid+s]; __syncthreads(); }
  float inv = 1.f / red[0];
  att[b*512+tid] = e1*inv; att[b*512+256+tid] = e2*inv;
}

__global__ __launch_bounds__(256)
void wsum_k(const float* att, const float* dh, float* out){
  int b = blockIdx.x, tid = threadIdx.x;
  for (int d = tid; d < 300; d += 256){
    float acc = 0.f;
    for (int t = 0; t < 512; t++)
      acc += att[b*512+t] * dh[((size_t)b*512 + t)*300 + d];
    out[b*300+d] = acc;
  }
}

// ---------------------------------------------------------------------------
// graph_decomp helpers
// ---------------------------------------------------------------------------
__global__ void count_k(const int* src, int E, float* counts){
  int e = blockIdx.x*256 + threadIdx.x;
  if (e < E) atomicAdd(&counts[src[e]], 1.f);
}
__global__ void coef_k(const float* L, const int* src, const int* dst, int E, float* coef){
  int e = blockIdx.x*4 + (threadIdx.x >> 6);
  int lane = threadIdx.x & 63;
  if (e >= E) return;
  const float* Li = L + (size_t)src[e]*300;
  const float* Lj = L + (size_t)dst[e]*300;
  float num = 0.f, den = 0.f;
  for (int d = lane; d < 300; d += 64){ float lj = Lj[d]; num += Li[d]*lj; den += lj*lj; }
  for (int off = 32; off; off >>= 1){ num += __shfl_xor(num, off, 64); den += __shfl_xor(den, off, 64); }
  if (lane == 0) coef[e] = num / (den + 1e-10f);
}
__global__ void agg_k(const float* L, const int* src, const int* dst, const float* coef, int E, float* agg){
  int e = blockIdx.x;
  float c = coef[e];
  const float* Lj = L + (size_t)dst[e]*300;
  float* ag = agg + (size_t)src[e]*300;
  for (int d = threadIdx.x; d < 300; d += 256) atomicAdd(&ag[d], c*Lj[d]);
}
__global__ void upd_k(const float* L, const float* agg, const float* counts, float* out, int n){
  int i = blockIdx.x;
  float c = counts[i];
  for (int d = threadIdx.x; d < 300; d += 256){
    float v = L[(size_t)i*300+d];
    out[(size_t)i*300+d] = (c > 0.f) ? v - agg[(size_t)i*300+d]/fmaxf(c, 1.f) : v;
  }
}

// ---------------------------------------------------------------------------
// classifier heads (write f32 logits straight into d_out), argmax, gather
// ---------------------------------------------------------------------------
__global__ __launch_bounds__(128)
void logits_k(const float* A0, const float* A1, const float* A2, int srcw,
              const float* W, const float* bias, int C, int K,
              float* outF){
  int b = blockIdx.x, tid = threadIdx.x;
  for (int c = tid; c < C; c += 128){
    float acc = bias[c];
    const float* wp = W + (size_t)c*K;
    for (int k = 0; k < K; k++){
      int s = k / srcw; int kk = k - s*srcw;
      const float* Ap = (s==0) ? A0 : ((s==1) ? A1 : A2);
      acc += Ap[(size_t)b*srcw + kk] * wp[k];
    }
    outF[b*C + c] = acc;
  }
}
__global__ void argmax_k(const float* lf, int C, int* pred){
  int b = threadIdx.x;
  if (b < 32){
    const float* p = lf + (size_t)b*C;
    int best = 0; float bv = p[0];
    for (int c = 1; c < C; c++){ float v = p[c]; if (v > bv){ bv = v; best = c; } }
    pred[b] = best;
  }
}
__global__ void vtok_k(const int* table, const int* pred, int* vt, int L){
  int i = blockIdx.x*256 + threadIdx.x;
  if (i < 32*L) vt[i] = table[pred[i/L]*L + i%L];
}

// ---------------------------------------------------------------------------
extern "C" void kernel_launch(void* const* d_in, const int* in_sizes, int n_in,
                              void* d_out, int out_size, void* d_ws, size_t ws_size,
                              hipStream_t stream)
{
  (void)in_sizes; (void)n_in; (void)out_size;
  const float* E        = (const float*)d_in[0];
  const int* chTok    = (const int*)d_in[1];
  const int* arTok    = (const int*)d_in[2];
  const int* docs     = (const int*)d_in[3];
  const int* chVerd   = (const int*)d_in[4];
  const int* arVerd   = (const int*)d_in[5];
  const int* c_src    = (const int*)d_in[6];
  const int* c_dst    = (const int*)d_in[7];
  const int* a_src    = (const int*)d_in[8];
  const int* a_dst    = (const int*)d_in[9];
  const float* enc_Wih  = (const float*)d_in[10];
  const float* enc_Whh  = (const float*)d_in[11];
  const float* enc_bih  = (const float*)d_in[12];
  const float* enc_bhh  = (const float*)d_in[13];
  const float* ech_Wih  = (const float*)d_in[14];
  const float* ech_Whh  = (const float*)d_in[15];
  const float* ech_bih  = (const float*)d_in[16];
  const float* ech_bhh  = (const float*)d_in[17];
  const float* term_Wih = (const float*)d_in[18];
  const float* term_Whh = (const float*)d_in[19];
  const float* term_bih = (const float*)d_in[20];
  const float* term_bhh = (const float*)d_in[21];
  const float* art_Wih  = (const float*)d_in[22];
  const float* art_Whh  = (const float*)d_in[23];
  const float* art_bih  = (const float*)d_in[24];
  const float* art_bhh  = (const float*)d_in[25];
  const float* W_charge = (const float*)d_in[26];
  const float* b_charge = (const float*)d_in[27];
  const float* W_article= (const float*)d_in[28];
  const float* b_article= (const float*)d_in[29];
  const float* W_time   = (const float*)d_in[30];
  const float* b_time   = (const float*)d_in[31];
  float* out = (float*)d_out;
  float* OUTC = out;            // [32][119]
  float* OUTA = out + 3808;     // [32][103]
  float* OUTT = out + 7104;     // [32][11]

  char* wsb = (char*)d_ws;
  size_t off = 0;
  auto alloc = [&](size_t nf)->float* {
    float* p = (float*)(wsb + off);
    off += ((nf*4 + 255) & ~(size_t)255);
    return p;
  };
  // XS0/XS1: half-T per-dir xs chunks [B][256][1800] f32 (art; term 1350).
  // XS0 also hosts: encch xs (40MB), enc-doc xs (59.0MB exactly), vh xs,
  // and the codewise S buffer (aliased, disjoint lifetimes).
  float* XS0   = alloc(14745600ULL);        // 59.0 MB
  float* XS1   = alloc(14745600ULL);        // 59.0 MB
  float* SBUF  = XS0;                       // alias: disjoint lifetime
  float* DH    = alloc(4915200);            // d_hidden [32][512][300]
  float* ADC   = alloc(4915200);            // adc, later dsc
  float* SEC   = alloc(4915200);
  float* SSC   = alloc(4915200);
  float* VHYS  = alloc(480000);             // [32][50][300]
  float* MECH  = alloc(66600);              // encch means [222][300]
  float* LC1   = alloc(35700);
  float* LC0   = alloc(35700);
  float* LA1   = alloc(30900);
  float* LA0   = alloc(30900);
  float* AGG   = alloc(35700);
  float* CNTS  = alloc(256);                // counts_c @0, counts_a @128
  float* COEF  = alloc(640);
  float* DHC   = alloc(9600);
  float* DA    = alloc(9600);
  float* DHNA  = alloc(9600);
  float* DB    = alloc(9600);
  float* MDH   = alloc(9600);               // mean_t d_hidden [32][300]
  float* MFA   = alloc(38400);              // fa mean [32][1200] (accumulated)
  float* MTH   = alloc(28800);              // th mean [32][900] (accumulated)
  float* RB    = alloc(115200);             // art rowbias [32][3600]
  float* RMX   = alloc(16384);
  float* ATTB  = alloc(16384);
  float* HBUF  = alloc(76800);              // [2][2][32][600]
  u32*   CTRS  = (u32*)alloc(4*16*CTR_STRIDE);  // 4 gru launches x 16 groups
  int*   PREDC = (int*)alloc(64);
  int*   PREDA = (int*)alloc(64);
  int*   VTOK  = (int*)alloc(1600);
  int*   TCC   = (int*)alloc(11104);

  if (off > ws_size) return;   // diagnostic: leaves out==0 -> absmax==max|ref|

  hipMemsetAsync(CTRS, 0, 4*16*CTR_STRIDE*4, stream);
  hipMemsetAsync(CNTS, 0, 256*4, stream);

  // --- encch on charge+article token sequences (222 seqs, L=50) ---
  hipMemcpyAsync(TCC, chTok, NCn*LCn*4, hipMemcpyDeviceToDevice, stream);
  hipMemcpyAsync(TCC + NCn*LCn, arTok, NAn*LCn*4, hipMemcpyDeviceToDevice, stream);
  {
    dim3 g((900+127)/128, (11100+127)/128);
    gemm_k<1><<<g,256,0,stream>>>(nullptr,nullptr,nullptr, E, TCC,
        ech_Wih, 200, 0,0,0, ech_bih, nullptr, 1, 1, IDIV,0,0,
        XS0, 11100, 900, 200);
  }
  gru_small_k<<<dim3(222,2),192,0,stream>>>(XS0, 900, ech_Whh, ech_bhh, nullptr, MECH, 50);

  // --- enc on documents ---
  {
    dim3 g((900+127)/128, (16384+127)/128);
    gemm_k<1><<<g,256,0,stream>>>(nullptr,nullptr,nullptr, E, docs,
        enc_Wih, 200, 0,0,0, enc_bih, nullptr, 1, 1, IDIV,0,0,
        XS0, 16384, 900, 200);
  }
  gru_small_k<<<dim3(32,2),192,0,stream>>>(XS0, 900, enc_Whh, enc_bhh, DH, MDH, 512);

  // --- graph_decomp (charge, article), 2 layers each ---
  count_k<<<3,256,0,stream>>>(c_src, ECn, CNTS);
  count_k<<<2,256,0,stream>>>(a_src, EAn, CNTS+128);
  coef_k<<<150,256,0,stream>>>(MECH, c_src, c_dst, ECn, COEF);
  hipMemsetAsync(AGG, 0, 35700*4, stream);
  agg_k<<<ECn,256,0,stream>>>(MECH, c_src, c_dst, COEF, ECn, AGG);
  upd_k<<<NCn,256,0,stream>>>(MECH, AGG, CNTS, LC1, NCn);
  coef_k<<<150,256,0,stream>>>(LC1, c_src, c_dst, ECn, COEF);
  hipMemsetAsync(AGG, 0, 35700*4, stream);
  agg_k<<<ECn,256,0,stream>>>(LC1, c_src, c_dst, COEF, ECn, AGG);
  upd_k<<<NCn,256,0,stream>>>(LC1, AGG, CNTS, LC0, NCn);

  const float* MEAR = MECH + (size_t)NCn*300;
  coef_k<<<125,256,0,stream>>>(MEAR, a_src, a_dst, EAn, COEF);
  hipMemsetAsync(AGG, 0, 30900*4, stream);
  agg_k<<<EAn,256,0,stream>>>(MEAR, a_src, a_dst, COEF, EAn, AGG);
  upd_k<<<NAn,256,0,stream>>>(MEAR, AGG, CNTS+128, LA1, NAn);
  coef_k<<<125,256,0,stream>>>(LA1, a_src, a_dst, EAn, COEF);
  hipMemsetAsync(AGG, 0, 30900*4, stream);
  agg_k<<<EAn,256,0,stream>>>(LA1, a_src, a_dst, COEF, EAn, AGG);
  upd_k<<<NAn,256,0,stream>>>(LA1, AGG, CNTS+128, LA0, NAn);

  // --- code_wise x4 (S-buffer aliased into XS0) ---
  auto codewise = [&](const float* q, int Nq, float* outv){
    dim3 g((Nq+127)/128, 128);
    gemm_k<0><<<g,256,0,stream>>>(DH, nullptr, nullptr, nullptr, nullptr,
        q, 300, 0,0,0, nullptr, nullptr, 1, 1, IDIV,0,0,
        SBUF, 16384, Nq, 300);
    rowmax_k<<<4096,256,0,stream>>>(SBUF, RMX, 16384, Nq);
    softmaxT_k<<<32,256,0,stream>>>(RMX, ATTB);
    wsum_k<<<32,256,0,stream>>>(ATTB, DH, outv);
  };
  codewise(LC0,  NCn, DHC);    // new_charge
  codewise(MECH, NCn, DA);     // ori charge
  codewise(LA0,  NAn, DHNA);   // new_article
  codewise(MEAR, NAn, DB);     // ori article

  // --- charge head ---
  logits_k<<<32,128,0,stream>>>(MDH, DHC, DA, 300, W_charge, b_charge, NCn, 900, OUTC);
  argmax_k<<<1,64,0,stream>>>(OUTC, NCn, PREDC);

  // --- fact_sep #1 ---
  vtok_k<<<7,256,0,stream>>>(chVerd, PREDC, VTOK, LVn);
  {
    dim3 g((900+127)/128, (1600+127)/128);
    gemm_k<1><<<g,256,0,stream>>>(nullptr,nullptr,nullptr, E, VTOK,
        enc_Wih, 200, 0,0,0, enc_bih, nullptr, 1, 1, IDIV,0,0,
        XS0, 1600, 900, 200);
  }
  gru_small_k<<<dim3(32,2),192,0,stream>>>(XS0, 900, enc_Whh, enc_bhh, VHYS, nullptr, 50);
  mask_att_k<<<dim3(64,32),256,0,stream>>>(DH, VHYS, ADC, SEC);

  // --- article bigru: rowbias, then time-sliced dual-dir chunks ---
  {
    dim3 g((3600+127)/128, 1);
    gemm_k<0><<<g,256,0,stream>>>(DHNA, DB, nullptr, nullptr, nullptr,
        art_Wih, 1200, 300, 900, 0, art_bih, nullptr, 1, 1, IDIV,0,0,
        RB, 32, 3600, 600);
  }
  hipMemsetAsync(MFA, 0, 38400*4, stream);
  for (int L = 0; L < 2; L++){
    dim3 g((1800+127)/128, 64);
    // fwd chunk: t in [256L, 256L+256), dir0 weights
    gemm_k<0><<<g,256,0,stream>>>(DH, ADC, nullptr, nullptr, nullptr,
        art_Wih, 1200, 0, 600, 0,
        nullptr, RB, 256, 3600, 256, 512, 256*L,
        XS0, 8192, 1800, 600);
    // rev chunk: t in [256(1-L), ...), dir1 weights
    gemm_k<0><<<g,256,0,stream>>>(DH, ADC, nullptr, nullptr, nullptr,
        art_Wih + (size_t)1800*1200, 1200, 0, 600, 0,
        nullptr, RB + 1800, 256, 3600, 256, 512, 256*(1-L),
        XS1, 8192, 1800, 600);
    gru_big_k<<<dim3(15,8,2),192,0,stream>>>(XS0, XS1, art_Whh, art_bhh,
        HBUF, MFA, 1200, CTRS + (size_t)L*16*CTR_STRIDE,
        512, 256, 256*L, 600, 40, 604, 15, 600);
  }
  logits_k<<<32,128,0,stream>>>(MFA, nullptr, nullptr, 1200, W_article, b_article, NAn, 1200, OUTA);
  argmax_k<<<1,64,0,stream>>>(OUTA, NAn, PREDA);

  // --- fact_sep #2 (context = sec_vector) ---
  vtok_k<<<7,256,0,stream>>>(arVerd, PREDA, VTOK, LVn);
  {
    dim3 g((900+127)/128, (1600+127)/128);
    gemm_k<1><<<g,256,0,stream>>>(nullptr,nullptr,nullptr, E, VTOK,
        enc_Wih, 200, 0,0,0, enc_bih, nullptr, 1, 1, IDIV,0,0,
        XS0, 1600, 900, 200);
  }
  gru_small_k<<<dim3(32,2),192,0,stream>>>(XS0, 900, enc_Whh, enc_bhh, VHYS, nullptr, 50);
  mask_att_k<<<dim3(64,32),256,0,stream>>>(SEC, VHYS, SSC, ADC);   // ssc, dsc(=ADC)

  // --- term bigru, time-sliced dual-dir chunks ---
  hipMemsetAsync(MTH, 0, 28800*4, stream);
  for (int L = 0; L < 2; L++){
    dim3 g((1350+127)/128, 64);
    gemm_k<0><<<g,256,0,stream>>>(DH, SSC, ADC, nullptr, nullptr,
        term_Wih, 900, 0, 300, 600,
        term_bih, nullptr, 1, 1, 256, 512, 256*L,
        XS0, 8192, 1350, 900);
    gemm_k<0><<<g,256,0,stream>>>(DH, SSC, ADC, nullptr, nullptr,
        term_Wih + (size_t)1350*900, 900, 0, 300, 600,
        term_bih + 1350, nullptr, 1, 1, 256, 512, 256*(1-L),
        XS1, 8192, 1350, 900);
    gru_big_k<<<dim3(10,8,2),192,0,stream>>>(XS0, XS1, term_Whh, term_bhh,
        HBUF, MTH, 900, CTRS + (size_t)(2+L)*16*CTR_STRIDE,
        512, 256, 256*L, 450, 45, 460, 10, 452);
  }
  logits_k<<<32,128,0,stream>>>(MTH, nullptr, nullptr, 900, W_time, b_time, NTn, 900, OUTT);
}

// Round 7
// 22938.147 us; speedup vs baseline: 2.2173x; 1.1088x over previous
//
#include <hip/hip_runtime.h>
#include <stdint.h>
#include <math.h>

typedef unsigned int u32;
typedef _Float16 f16;
typedef _Float16 h4 __attribute__((ext_vector_type(4)));
typedef _Float16 h2 __attribute__((ext_vector_type(2)));

// Problem constants
#define Vn     50000
#define DEMBn  200
#define Hn     150
#define NCn    119
#define NAn    103
#define NTn    11
#define Bn     32
#define Tn     512
#define LCn    50
#define LVn    50
#define ECn    600
#define EAn    500

#define CTR_STRIDE 64   // u32s = 256 B per barrier-group counter region
#define IDIV 1073741824 // identity arow mapping

__device__ __forceinline__ float sigm(float x){ return 1.0f / (1.0f + expf(-x)); }

// LLC-coherent agent-scope ops (sc-flagged, bypass non-coherent L1/L2).
__device__ __forceinline__ float llc_loadf(const float* p){
  u32 v = __hip_atomic_load((const u32*)p, __ATOMIC_RELAXED, __HIP_MEMORY_SCOPE_AGENT);
  union { u32 i; float f; } u; u.i = v; return u.f;
}
__device__ __forceinline__ void llc_storef(float* p, float v){
  union { float f; u32 i; } u; u.f = v;
  __hip_atomic_store((u32*)p, u.i, __ATOMIC_RELAXED, __HIP_MEMORY_SCOPE_AGENT);
}

// ---------------------------------------------------------------------------
// Tiled fp32 GEMM: C[M][N] = A[arow(m)][K] @ B[N][K]^T (+bias +rowbias)
// AMODE 0: A = up to 3 f32 sources, each [...][300]; source s = k/300;
//          B column for element k is bc[s] + (k - s*300).
//          A row = (m/arow_div)*arow_stride + (m%arow_div) + arow_off
// AMODE 1: A[m][k] = Etab[tok[m]][k] (f32 embedding gather), B col = k
// ---------------------------------------------------------------------------
template<int AMODE>
__global__ __launch_bounds__(256)
void gemm_k(const float* A0, const float* A1, const float* A2,
            const float* Etab, const int* tok,
            const float* Bm, int ldb, int bc0, int bc1, int bc2,
            const float* bias, const float* rowbias, int rb_div, int rb_stride,
            int arow_div, int arow_stride, int arow_off,
            float* C, int M, int N, int K)
{
  __shared__ float As[8][132];
  __shared__ float Bs[8][132];
  __shared__ int tokS[128];
  int tid = threadIdx.x;
  int m0 = blockIdx.y * 128, n0 = blockIdx.x * 128;
  if (AMODE == 1){
    for (int i = tid; i < 128; i += 256){
      int m = m0 + i;
      tokS[i] = (m < M) ? tok[m] : 0;
    }
  }
  __syncthreads();
  float acc[8][8];
  #pragma unroll
  for (int i=0;i<8;i++)
    #pragma unroll
    for (int j=0;j<8;j++) acc[i][j] = 0.f;

  int tx = tid & 15, ty = tid >> 4;

  for (int k0 = 0; k0 < K; k0 += 8){
    #pragma unroll
    for (int r = 0; r < 4; r++){
      int i = tid + 256*r;          // [0,1024)
      int ml = i >> 3, kl = i & 7;
      int k = k0 + kl;
      {
        int m = m0 + ml;
        float v = 0.f;
        if (m < M && k < K){
          if (AMODE == 0){
            int s = k / 300; int kk = k - s*300;
            const float* Ap = (s==0) ? A0 : ((s==1) ? A1 : A2);
            int ar = (m / arow_div)*arow_stride + (m % arow_div) + arow_off;
            v = Ap[(size_t)ar*300 + kk];
          } else {
            v = Etab[(size_t)tokS[ml]*DEMBn + k];
          }
        }
        As[kl][ml] = v;
      }
      {
        int n = n0 + ml;
        float v = 0.f;
        if (n < N && k < K){
          int col;
          if (AMODE == 0){ int s = k / 300; int kk = k - s*300; col = ((s==0)?bc0:((s==1)?bc1:bc2)) + kk; }
          else col = k;
          v = Bm[(size_t)n*ldb + col];
        }
        Bs[kl][ml] = v;
      }
    }
    __syncthreads();
    #pragma unroll
    for (int kk = 0; kk < 8; kk++){
      float a[8], b[8];
      #pragma unroll
      for (int i=0;i<8;i++) a[i] = As[kk][ty*8+i];
      #pragma unroll
      for (int i=0;i<8;i++) b[i] = Bs[kk][tx*8+i];
      #pragma unroll
      for (int i=0;i<8;i++)
        #pragma unroll
        for (int j=0;j<8;j++) acc[i][j] += a[i]*b[j];
    }
    __syncthreads();
  }
  #pragma unroll
  for (int i=0;i<8;i++){
    int m = m0 + ty*8 + i; if (m >= M) continue;
    #pragma unroll
    for (int j=0;j<8;j++){
      int n = n0 + tx*8 + j; if (n >= N) continue;
      float v = acc[i][j];
      if (bias)    v += bias[n];
      if (rowbias) v += rowbias[(size_t)(m / rb_div)*rb_stride + n];
      C[(size_t)m*N + n] = v;
    }
  }
}

// ---------------------------------------------------------------------------
// Small-GRU recurrence (H=150): one block per (seq, dir). Whh f16 in LDS.
// ---------------------------------------------------------------------------
__global__ __launch_bounds__(192)
void gru_small_k(const float* xs, int ncols,
                 const float* Whh, const float* bhh,
                 float* ys, float* meanOut, int T)
{
  const int KP = 156;
  __shared__ f16 Wl[3*150*156];     // 140,400 B
  __shared__ float bhl[456];
  __shared__ __align__(16) float hl[152];
  int tid = threadIdx.x;
  int seq = blockIdx.x, dir = blockIdx.y;

  for (int idx = tid; idx < 3*150*150; idx += 192){
    int g = idx / 22500, r = idx % 22500;
    int j = r / 150, k = r % 150;
    Wl[(g*150 + j)*KP + k] = (f16)Whh[(size_t)dir*67500 + idx];
  }
  for (int idx = tid; idx < 450; idx += 192) bhl[idx] = bhh[dir*450 + idx];
  if (tid < 152) hl[tid] = 0.f;
  __syncthreads();

  const f16 *wr = nullptr, *wz = nullptr, *wn = nullptr;
  float bR=0.f, bZ=0.f, bN=0.f;
  if (tid < 150){
    wr = &Wl[(0*150+tid)*KP];
    wz = &Wl[(1*150+tid)*KP];
    wn = &Wl[(2*150+tid)*KP];
    bR = bhl[tid]; bZ = bhl[150+tid]; bN = bhl[300+tid];
  }
  float msum = 0.f;
  size_t rowbase = (size_t)seq * T;
  for (int tt = 0; tt < T; tt++){
    int t = dir ? (T-1-tt) : tt;
    float aR=0.f, aZ=0.f, aN=0.f;
    if (tid < 150){
      for (int k = 0; k < 148; k += 4){
        float4 hv = *(const float4*)(hl + k);
        h4 r4 = *(const h4*)(wr + k);
        h4 z4 = *(const h4*)(wz + k);
        h4 n4 = *(const h4*)(wn + k);
        aR += (float)r4.x*hv.x + (float)r4.y*hv.y + (float)r4.z*hv.z + (float)r4.w*hv.w;
        aZ += (float)z4.x*hv.x + (float)z4.y*hv.y + (float)z4.z*hv.z + (float)z4.w*hv.w;
        aN += (float)n4.x*hv.x + (float)n4.y*hv.y + (float)n4.z*hv.z + (float)n4.w*hv.w;
      }
      {
        float2 hv = *(const float2*)(hl + 148);
        h2 r2 = *(const h2*)(wr + 148);
        h2 z2 = *(const h2*)(wz + 148);
        h2 n2 = *(const h2*)(wn + 148);
        aR += (float)r2.x*hv.x + (float)r2.y*hv.y;
        aZ += (float)z2.x*hv.x + (float)z2.y*hv.y;
        aN += (float)n2.x*hv.x + (float)n2.y*hv.y;
      }
    }
    __syncthreads();           // all reads of hl done
    if (tid < 150){
      const float* xp = xs + (rowbase + t)*(size_t)ncols + dir*450;
      float xr = xp[tid], xz = xp[150+tid], xn = xp[300+tid];
      float rr = sigm(xr + aR + bR);
      float zz = sigm(xz + aZ + bZ);
      float nn = tanhf(xn + rr*(aN + bN));
      float hn = (1.f - zz)*nn + zz*hl[tid];
      hl[tid] = hn;
      msum += hn;
      if (ys) ys[(rowbase + t)*(size_t)300 + dir*150 + tid] = hn;
    }
    __syncthreads();
  }
  if (meanOut && tid < 150)
    meanOut[(size_t)seq*300 + dir*150 + tid] = msum / (float)T;
}

// ---------------------------------------------------------------------------
// Big-GRU recurrence, BOTH dirs per launch (grid NJC x 8 x 2), time-sliced:
// processes TC steps starting at global step t0. h carried across launches in
// hbuf[par][dir]. meanOut accumulated (+=). h-staging is BATCHED: all ~13
// loads issued into registers (one vmcnt drain), then LDS writes — the
// round-6 per-iteration load->ds_write pattern serialized ~12 HBM round
// trips (~8us/step, the dominant stall).
// ---------------------------------------------------------------------------
__global__ __launch_bounds__(192)
void gru_big_k(const float* xs0, const float* xs1,
               const float* Whh,         // [2][3*Hh][Hh]
               const float* bhh,         // [2][3*Hh]
               float* hbuf,              // [2][2][B][Hh]
               float* meanOut, int mean_stride,   // += msum/TT at col dir*Hh+j
               u32* counters,            // 16 x CTR_STRIDE u32, zeroed
               int TT, int TC, int t0,
               int Hh, int JB, int KPAD, int NJC, int HS)
{
  __shared__ f16 Wl[72480];                 // 144,960 B (art: 3*40*604)
  __shared__ float bhl[136];
  __shared__ __align__(16) float hstage[2400];
  int tid = threadIdx.x;
  int jc = blockIdx.x, bg = blockIdx.y, dir = blockIdx.z;
  int j0 = jc * JB;
  int H3 = 3 * Hh;
  const float* Wd = Whh + (size_t)dir*H3*Hh;
  const float* bd = bhh + (size_t)dir*H3;
  const float* xs = dir ? xs1 : xs0;
  int xoff = dir ? (TT - TC - t0) : t0;

  for (int idx = tid; idx < 3*JB*Hh; idx += 192){
    int row = idx / Hh, k = idx - row*Hh;
    int g = row / JB, jj = row - g*JB;
    Wl[row*KPAD + k] = (f16)Wd[((size_t)g*Hh + j0 + jj)*(size_t)Hh + k];
  }
  for (int idx = tid; idx < 3*JB; idx += 192){
    int g = idx / JB, jj = idx - g*JB;
    bhl[idx] = bd[g*Hh + j0 + jj];
  }
  __syncthreads();

  u32* cnt = counters + (size_t)(dir*8 + bg) * CTR_STRIDE;
  int cj = tid >> 2, ckq = tid & 3;
  bool comp = (cj < JB);
  int k0 = 0, k1 = 0;
  if (comp){
    k0 = (ckq == 0) ? 0 : ((ckq*Hh/4) & ~3);
    k1 = (ckq == 3) ? Hh : ((((ckq+1)*Hh)/4) & ~3);
  }
  float br = 0.f, bz = 0.f, bn_ = 0.f;
  if (comp && ckq == 0){
    br = bhl[cj]; bz = bhl[JB+cj]; bn_ = bhl[2*JB+cj];
  }
  float msum[4] = {0.f, 0.f, 0.f, 0.f};
  int jg = j0 + cj;
  int HT = 4*Hh;                 // h elems per bgroup (2400 art / 1800 term)

  for (int tt = 0; tt < TC; tt++){
    int g = t0 + tt;                       // global step index
    int t = dir ? (TT-1-g) : g;            // time position consumed
    int par = g & 1;
    const float* hrd = hbuf + (size_t)(par*2 + dir)*Bn*Hh;
    float*       hwr = hbuf + (size_t)((1-par)*2 + dir)*Bn*Hh;

    // xs prefetch (h-independent): issue before the gemv to hide HBM latency
    float xr[4], xz[4], xn[4];
    if (comp && ckq == 0){
      #pragma unroll
      for (int s=0;s<4;s++){
        const float* xp = xs + ((size_t)(bg*4+s)*TC + (t - xoff))*(size_t)H3;
        xr[s] = xp[jg]; xz[s] = xp[Hh+jg]; xn[s] = xp[2*Hh+jg];
      }
    }

    // h staging: batched loads (all in flight), then LDS writes
    if (g == 0){
      for (int idx = tid; idx < HT; idx += 192){
        int s = idx / Hh, k = idx - s*Hh;
        hstage[s*HS + k] = 0.f;
      }
    } else {
      float tmp[13];
      const float* hb = hrd + (size_t)(bg*4)*Hh;   // rows contiguous
      #pragma unroll
      for (int r = 0; r < 13; r++){
        int idx = tid + r*192;
        if (idx < HT) tmp[r] = llc_loadf(&hb[idx]);
      }
      #pragma unroll
      for (int r = 0; r < 13; r++){
        int idx = tid + r*192;
        if (idx < HT){ int s = idx / Hh, k = idx - s*Hh; hstage[s*HS + k] = tmp[r]; }
      }
    }
    __syncthreads();
    float a0[4] = {0,0,0,0}, a1[4] = {0,0,0,0}, a2[4] = {0,0,0,0};
    if (comp){
      const f16* pr = &Wl[(0*JB+cj)*KPAD];
      const f16* pz = &Wl[(1*JB+cj)*KPAD];
      const f16* pn = &Wl[(2*JB+cj)*KPAD];
      int k = k0;
      for (; k + 4 <= k1; k += 4){
        h4 r4 = *(const h4*)(pr + k);
        h4 z4 = *(const h4*)(pz + k);
        h4 n4 = *(const h4*)(pn + k);
        float wr0=(float)r4.x, wr1=(float)r4.y, wr2=(float)r4.z, wr3=(float)r4.w;
        float wz0=(float)z4.x, wz1=(float)z4.y, wz2=(float)z4.z, wz3=(float)z4.w;
        float wn0=(float)n4.x, wn1=(float)n4.y, wn2=(float)n4.z, wn3=(float)n4.w;
        #pragma unroll
        for (int s=0;s<4;s++){
          float4 hv = *(const float4*)(hstage + s*HS + k);
          a0[s] += wr0*hv.x + wr1*hv.y + wr2*hv.z + wr3*hv.w;
          a1[s] += wz0*hv.x + wz1*hv.y + wz2*hv.z + wz3*hv.w;
          a2[s] += wn0*hv.x + wn1*hv.y + wn2*hv.z + wn3*hv.w;
        }
      }
      for (; k < k1; k++){
        float wr0=(float)pr[k], wz0=(float)pz[k], wn0=(float)pn[k];
        #pragma unroll
        for (int s=0;s<4;s++){
          float hv = hstage[s*HS + k];
          a0[s] += wr0*hv; a1[s] += wz0*hv; a2[s] += wn0*hv;
        }
      }
    }
    // quad reduction over ckq lanes (quads never straddle waves)
    #pragma unroll
    for (int s=0;s<4;s++){
      a0[s] += __shfl_xor(a0[s], 1); a0[s] += __shfl_xor(a0[s], 2);
      a1[s] += __shfl_xor(a1[s], 1); a1[s] += __shfl_xor(a1[s], 2);
      a2[s] += __shfl_xor(a2[s], 1); a2[s] += __shfl_xor(a2[s], 2);
    }
    if (comp && ckq == 0){
      #pragma unroll
      for (int s=0;s<4;s++){
        int b = bg*4 + s;
        float rr = sigm(xr[s] + a0[s] + br);
        float zz = sigm(xz[s] + a1[s] + bz);
        float nn = tanhf(xn[s] + rr*(a2[s] + bn_));
        float hn = (1.f - zz)*nn + zz*hstage[s*HS + jg];
        llc_storef(&hwr[(size_t)b*Hh + jg], hn);
        msum[s] += hn;
      }
    }
    __builtin_amdgcn_s_waitcnt(0);   // per-wave: drain h stores
    __syncthreads();
    if (tid == 0){
      __hip_atomic_fetch_add(cnt, 1u, __ATOMIC_RELAXED, __HIP_MEMORY_SCOPE_AGENT);
      u32 target = (u32)NJC * (u32)(tt+1);
      int guard = 0;
      while (__hip_atomic_load(cnt, __ATOMIC_RELAXED, __HIP_MEMORY_SCOPE_AGENT) < target){
        __builtin_amdgcn_s_sleep(2);
        if (++guard > 2000000) break;   // failsafe: wrong result > GPU hang
      }
    }
    __syncthreads();
  }
  if (comp && ckq == 0){
    #pragma unroll
    for (int s=0;s<4;s++){
      float* mp = meanOut + (size_t)(bg*4+s)*mean_stride + dir*Hh + jg;
      *mp += msum[s] / (float)TT;
    }
  }
}

// ---------------------------------------------------------------------------
// mask_att + fact_sep fused: per (b, 8-t chunk).
// ---------------------------------------------------------------------------
__global__ __launch_bounds__(256)
void mask_att_k(const float* ctx, const float* vh, float* simOut, float* diffOut)
{
  __shared__ float vhl[50*300];
  __shared__ float ctxl[8*300];
  __shared__ float attl[8*52];
  __shared__ float scenl[8*300];
  __shared__ float ratio[8];
  int tid = threadIdx.x;
  int b = blockIdx.y, tc = blockIdx.x;
  size_t cbase = ((size_t)b*Tn + tc*8) * 300;
  for (int i = tid; i < 15000; i += 256) vhl[i] = vh[(size_t)b*15000 + i];
  for (int i = tid; i < 2400; i += 256)  ctxl[i] = ctx[cbase + i];
  __syncthreads();
  for (int p = tid; p < 400; p += 256){
    int ttl = p / 50, v = p % 50;
    const float* cp = ctxl + ttl*300;
    const float* vp = vhl + v*300;
    float acc = 0.f;
    for (int d = 0; d < 300; d++) acc += cp[d]*vp[d];
    attl[ttl*52 + v] = acc;
  }
  __syncthreads();
  if (tid < 8){
    float mx = -INFINITY;
    for (int v=0; v<50; v++){
      float a = attl[tid*52+v];
      float msk = (a == 0.f) ? -INFINITY : a;
      attl[tid*52+v] = msk;
      mx = fmaxf(mx, msk);
    }
    if (mx == -INFINITY){
      for (int v=0; v<50; v++) attl[tid*52+v] = 0.f;
    } else {
      float sum = 0.f;
      for (int v=0; v<50; v++){ float e = expf(attl[tid*52+v] - mx); attl[tid*52+v] = e; sum += e; }
      float inv = 1.f/sum;
      for (int v=0; v<50; v++) attl[tid*52+v] *= inv;
    }
  }
  __syncthreads();
  for (int p = tid; p < 2400; p += 256){
    int ttl = p / 300, d = p % 300;
    float acc = 0.f;
    for (int v=0; v<50; v++) acc += attl[ttl*52+v] * vhl[v*300+d];
    scenl[p] = acc;
  }
  __syncthreads();
  if (tid < 8){
    float x3=0.f, x4=0.f;
    for (int d=0; d<300; d++){ float s = scenl[tid*300+d]; x3 += ctxl[tid*300+d]*s; x4 += s*s; }
    ratio[tid] = x3 / (x4 + 1e-10f);
  }
  __syncthreads();
  for (int p = tid; p < 2400; p += 256){
    float sim = ratio[p/300] * scenl[p];
    simOut[cbase + p]  = sim;
    diffOut[cbase + p] = ctxl[p] - sim;
  }
}

// ---------------------------------------------------------------------------
// code_wise helpers
// ---------------------------------------------------------------------------
__global__ void rowmax_k(const float* S, float* out, int M, int N){
  int row = blockIdx.x*4 + (threadIdx.x >> 6);
  int lane = threadIdx.x & 63;
  if (row >= M) return;
  float mx = -INFINITY;
  for (int n = lane; n < N; n += 64) mx = fmaxf(mx, S[(size_t)row*N + n]);
  for (int off = 32; off; off >>= 1) mx = fmaxf(mx, __shfl_xor(mx, off, 64));
  if (lane == 0) out[row] = mx;
}

__global__ __launch_bounds__(256)
void softmaxT_k(const float* m, float* att){
  __shared__ float red[256];
  int b = blockIdx.x, tid = threadIdx.x;
  float v1 = m[b*512 + tid], v2 = m[b*512 + 256 + tid];
  red[tid] = fmaxf(v1, v2); __syncthreads();
  for (int s=128; s; s>>=1){ if (tid<s) red[tid] = fmaxf(red[tid], red[tid+s]); __syncthreads(); }
  float M = red[0]; __syncthreads();
  float e1 = expf(v1-M), e2 = expf(v2-M);
  red[tid] = e1+e2; __syncthreads();
  for (int s=128; s; s>>=1){ if (tid<s) red[tid] += red[tid+s]; __syncthreads(); }
  float inv = 1.f / red[0];
  att[b*512+tid] = e1*inv; att[b*512+256+tid] = e2*inv;
}

__global__ __launch_bounds__(256)
void wsum_k(const float* att, const float* dh, float* out){
  int b = blockIdx.x, tid = threadIdx.x;
  for (int d = tid; d < 300; d += 256){
    float acc = 0.f;
    for (int t = 0; t < 512; t++)
      acc += att[b*512+t] * dh[((size_t)b*512 + t)*300 + d];
    out[b*300+d] = acc;
  }
}

// ---------------------------------------------------------------------------
// graph_decomp helpers
// ---------------------------------------------------------------------------
__global__ void count_k(const int* src, int E, float* counts){
  int e = blockIdx.x*256 + threadIdx.x;
  if (e < E) atomicAdd(&counts[src[e]], 1.f);
}
__global__ void coef_k(const float* L, const int* src, const int* dst, int E, float* coef){
  int e = blockIdx.x*4 + (threadIdx.x >> 6);
  int lane = threadIdx.x & 63;
  if (e >= E) return;
  const float* Li = L + (size_t)src[e]*300;
  const float* Lj = L + (size_t)dst[e]*300;
  float num = 0.f, den = 0.f;
  for (int d = lane; d < 300; d += 64){ float lj = Lj[d]; num += Li[d]*lj; den += lj*lj; }
  for (int off = 32; off; off >>= 1){ num += __shfl_xor(num, off, 64); den += __shfl_xor(den, off, 64); }
  if (lane == 0) coef[e] = num / (den + 1e-10f);
}
__global__ void agg_k(const float* L, const int* src, const int* dst, const float* coef, int E, float* agg){
  int e = blockIdx.x;
  float c = coef[e];
  const float* Lj = L + (size_t)dst[e]*300;
  float* ag = agg + (size_t)src[e]*300;
  for (int d = threadIdx.x; d < 300; d += 256) atomicAdd(&ag[d], c*Lj[d]);
}
__global__ void upd_k(const float* L, const float* agg, const float* counts, float* out, int n){
  int i = blockIdx.x;
  float c = counts[i];
  for (int d = threadIdx.x; d < 300; d += 256){
    float v = L[(size_t)i*300+d];
    out[(size_t)i*300+d] = (c > 0.f) ? v - agg[(size_t)i*300+d]/fmaxf(c, 1.f) : v;
  }
}

// ---------------------------------------------------------------------------
// classifier heads (write f32 logits straight into d_out), argmax, gather
// ---------------------------------------------------------------------------
__global__ __launch_bounds__(128)
void logits_k(const float* A0, const float* A1, const float* A2, int srcw,
              const float* W, const float* bias, int C, int K,
              float* outF){
  int b = blockIdx.x, tid = threadIdx.x;
  for (int c = tid; c < C; c += 128){
    float acc = bias[c];
    const float* wp = W + (size_t)c*K;
    for (int k = 0; k < K; k++){
      int s = k / srcw; int kk = k - s*srcw;
      const float* Ap = (s==0) ? A0 : ((s==1) ? A1 : A2);
      acc += Ap[(size_t)b*srcw + kk] * wp[k];
    }
    outF[b*C + c] = acc;
  }
}
__global__ void argmax_k(const float* lf, int C, int* pred){
  int b = threadIdx.x;
  if (b < 32){
    const float* p = lf + (size_t)b*C;
    int best = 0; float bv = p[0];
    for (int c = 1; c < C; c++){ float v = p[c]; if (v > bv){ bv = v; best = c; } }
    pred[b] = best;
  }
}
__global__ void vtok_k(const int* table, const int* pred, int* vt, int L){
  int i = blockIdx.x*256 + threadIdx.x;
  if (i < 32*L) vt[i] = table[pred[i/L]*L + i%L];
}

// ---------------------------------------------------------------------------
extern "C" void kernel_launch(void* const* d_in, const int* in_sizes, int n_in,
                              void* d_out, int out_size, void* d_ws, size_t ws_size,
                              hipStream_t stream)
{
  (void)in_sizes; (void)n_in; (void)out_size;
  const float* E        = (const float*)d_in[0];
  const int* chTok    = (const int*)d_in[1];
  const int* arTok    = (const int*)d_in[2];
  const int* docs     = (const int*)d_in[3];
  const int* chVerd   = (const int*)d_in[4];
  const int* arVerd   = (const int*)d_in[5];
  const int* c_src    = (const int*)d_in[6];
  const int* c_dst    = (const int*)d_in[7];
  const int* a_src    = (const int*)d_in[8];
  const int* a_dst    = (const int*)d_in[9];
  const float* enc_Wih  = (const float*)d_in[10];
  const float* enc_Whh  = (const float*)d_in[11];
  const float* enc_bih  = (const float*)d_in[12];
  const float* enc_bhh  = (const float*)d_in[13];
  const float* ech_Wih  = (const float*)d_in[14];
  const float* ech_Whh  = (const float*)d_in[15];
  const float* ech_bih  = (const float*)d_in[16];
  const float* ech_bhh  = (const float*)d_in[17];
  const float* term_Wih = (const float*)d_in[18];
  const float* term_Whh = (const float*)d_in[19];
  const float* term_bih = (const float*)d_in[20];
  const float* term_bhh = (const float*)d_in[21];
  const float* art_Wih  = (const float*)d_in[22];
  const float* art_Whh  = (const float*)d_in[23];
  const float* art_bih  = (const float*)d_in[24];
  const float* art_bhh  = (const float*)d_in[25];
  const float* W_charge = (const float*)d_in[26];
  const float* b_charge = (const float*)d_in[27];
  const float* W_article= (const float*)d_in[28];
  const float* b_article= (const float*)d_in[29];
  const float* W_time   = (const float*)d_in[30];
  const float* b_time   = (const float*)d_in[31];
  float* out = (float*)d_out;
  float* OUTC = out;            // [32][119]
  float* OUTA = out + 3808;     // [32][103]
  float* OUTT = out + 7104;     // [32][11]

  char* wsb = (char*)d_ws;
  size_t off = 0;
  auto alloc = [&](size_t nf)->float* {
    float* p = (float*)(wsb + off);
    off += ((nf*4 + 255) & ~(size_t)255);
    return p;
  };
  float* XS0   = alloc(14745600ULL);        // 59.0 MB
  float* XS1   = alloc(14745600ULL);        // 59.0 MB
  float* SBUF  = XS0;                       // alias: disjoint lifetime
  float* DH    = alloc(4915200);            // d_hidden [32][512][300]
  float* ADC   = alloc(4915200);            // adc, later dsc
  float* SEC   = alloc(4915200);
  float* SSC   = alloc(4915200);
  float* VHYS  = alloc(480000);             // [32][50][300]
  float* MECH  = alloc(66600);              // encch means [222][300]
  float* LC1   = alloc(35700);
  float* LC0   = alloc(35700);
  float* LA1   = alloc(30900);
  float* LA0   = alloc(30900);
  float* AGG   = alloc(35700);
  float* CNTS  = alloc(256);                // counts_c @0, counts_a @128
  float* COEF  = alloc(640);
  float* DHC   = alloc(9600);
  float* DA    = alloc(9600);
  float* DHNA  = alloc(9600);
  float* DB    = alloc(9600);
  float* MDH   = alloc(9600);               // mean_t d_hidden [32][300]
  float* MFA   = alloc(38400);              // fa mean [32][1200] (accumulated)
  float* MTH   = alloc(28800);              // th mean [32][900] (accumulated)
  float* RB    = alloc(115200);             // art rowbias [32][3600]
  float* RMX   = alloc(16384);
  float* ATTB  = alloc(16384);
  float* HBUF  = alloc(76800);              // [2][2][32][600]
  u32*   CTRS  = (u32*)alloc(4*16*CTR_STRIDE);  // 4 gru launches x 16 groups
  int*   PREDC = (int*)alloc(64);
  int*   PREDA = (int*)alloc(64);
  int*   VTOK  = (int*)alloc(1600);
  int*   TCC   = (int*)alloc(11104);

  if (off > ws_size) return;   // diagnostic: leaves out==0 -> absmax==max|ref|

  hipMemsetAsync(CTRS, 0, 4*16*CTR_STRIDE*4, stream);
  hipMemsetAsync(CNTS, 0, 256*4, stream);

  // --- encch on charge+article token sequences (222 seqs, L=50) ---
  hipMemcpyAsync(TCC, chTok, NCn*LCn*4, hipMemcpyDeviceToDevice, stream);
  hipMemcpyAsync(TCC + NCn*LCn, arTok, NAn*LCn*4, hipMemcpyDeviceToDevice, stream);
  {
    dim3 g((900+127)/128, (11100+127)/128);
    gemm_k<1><<<g,256,0,stream>>>(nullptr,nullptr,nullptr, E, TCC,
        ech_Wih, 200, 0,0,0, ech_bih, nullptr, 1, 1, IDIV,0,0,
        XS0, 11100, 900, 200);
  }
  gru_small_k<<<dim3(222,2),192,0,stream>>>(XS0, 900, ech_Whh, ech_bhh, nullptr, MECH, 50);

  // --- enc on documents ---
  {
    dim3 g((900+127)/128, (16384+127)/128);
    gemm_k<1><<<g,256,0,stream>>>(nullptr,nullptr,nullptr, E, docs,
        enc_Wih, 200, 0,0,0, enc_bih, nullptr, 1, 1, IDIV,0,0,
        XS0, 16384, 900, 200);
  }
  gru_small_k<<<dim3(32,2),192,0,stream>>>(XS0, 900, enc_Whh, enc_bhh, DH, MDH, 512);

  // --- graph_decomp (charge, article), 2 layers each ---
  count_k<<<3,256,0,stream>>>(c_src, ECn, CNTS);
  count_k<<<2,256,0,stream>>>(a_src, EAn, CNTS+128);
  coef_k<<<150,256,0,stream>>>(MECH, c_src, c_dst, ECn, COEF);
  hipMemsetAsync(AGG, 0, 35700*4, stream);
  agg_k<<<ECn,256,0,stream>>>(MECH, c_src, c_dst, COEF, ECn, AGG);
  upd_k<<<NCn,256,0,stream>>>(MECH, AGG, CNTS, LC1, NCn);
  coef_k<<<150,256,0,stream>>>(LC1, c_src, c_dst, ECn, COEF);
  hipMemsetAsync(AGG, 0, 35700*4, stream);
  agg_k<<<ECn,256,0,stream>>>(LC1, c_src, c_dst, COEF, ECn, AGG);
  upd_k<<<NCn,256,0,stream>>>(LC1, AGG, CNTS, LC0, NCn);

  const float* MEAR = MECH + (size_t)NCn*300;
  coef_k<<<125,256,0,stream>>>(MEAR, a_src, a_dst, EAn, COEF);
  hipMemsetAsync(AGG, 0, 30900*4, stream);
  agg_k<<<EAn,256,0,stream>>>(MEAR, a_src, a_dst, COEF, EAn, AGG);
  upd_k<<<NAn,256,0,stream>>>(MEAR, AGG, CNTS+128, LA1, NAn);
  coef_k<<<125,256,0,stream>>>(LA1, a_src, a_dst, EAn, COEF);
  hipMemsetAsync(AGG, 0, 30900*4, stream);
  agg_k<<<EAn,256,0,stream>>>(LA1, a_src, a_dst, COEF, EAn, AGG);
  upd_k<<<NAn,256,0,stream>>>(LA1, AGG, CNTS+128, LA0, NAn);

  // --- code_wise x4 (S-buffer aliased into XS0) ---
  auto codewise = [&](const float* q, int Nq, float* outv){
    dim3 g((Nq+127)/128, 128);
    gemm_k<0><<<g,256,0,stream>>>(DH, nullptr, nullptr, nullptr, nullptr,
        q, 300, 0,0,0, nullptr, nullptr, 1, 1, IDIV,0,0,
        SBUF, 16384, Nq, 300);
    rowmax_k<<<4096,256,0,stream>>>(SBUF, RMX, 16384, Nq);
    softmaxT_k<<<32,256,0,stream>>>(RMX, ATTB);
    wsum_k<<<32,256,0,stream>>>(ATTB, DH, outv);
  };
  codewise(LC0,  NCn, DHC);    // new_charge
  codewise(MECH, NCn, DA);     // ori charge
  codewise(LA0,  NAn, DHNA);   // new_article
  codewise(MEAR, NAn, DB);     // ori article

  // --- charge head ---
  logits_k<<<32,128,0,stream>>>(MDH, DHC, DA, 300, W_charge, b_charge, NCn, 900, OUTC);
  argmax_k<<<1,64,0,stream>>>(OUTC, NCn, PREDC);

  // --- fact_sep #1 ---
  vtok_k<<<7,256,0,stream>>>(chVerd, PREDC, VTOK, LVn);
  {
    dim3 g((900+127)/128, (1600+127)/128);
    gemm_k<1><<<g,256,0,stream>>>(nullptr,nullptr,nullptr, E, VTOK,
        enc_Wih, 200, 0,0,0, enc_bih, nullptr, 1, 1, IDIV,0,0,
        XS0, 1600, 900, 200);
  }
  gru_small_k<<<dim3(32,2),192,0,stream>>>(XS0, 900, enc_Whh, enc_bhh, VHYS, nullptr, 50);
  mask_att_k<<<dim3(64,32),256,0,stream>>>(DH, VHYS, ADC, SEC);

  // --- article bigru: rowbias, then time-sliced dual-dir chunks ---
  {
    dim3 g((3600+127)/128, 1);
    gemm_k<0><<<g,256,0,stream>>>(DHNA, DB, nullptr, nullptr, nullptr,
        art_Wih, 1200, 300, 900, 0, art_bih, nullptr, 1, 1, IDIV,0,0,
        RB, 32, 3600, 600);
  }
  hipMemsetAsync(MFA, 0, 38400*4, stream);
  for (int L = 0; L < 2; L++){
    dim3 g((1800+127)/128, 64);
    gemm_k<0><<<g,256,0,stream>>>(DH, ADC, nullptr, nullptr, nullptr,
        art_Wih, 1200, 0, 600, 0,
        nullptr, RB, 256, 3600, 256, 512, 256*L,
        XS0, 8192, 1800, 600);
    gemm_k<0><<<g,256,0,stream>>>(DH, ADC, nullptr, nullptr, nullptr,
        art_Wih + (size_t)1800*1200, 1200, 0, 600, 0,
        nullptr, RB + 1800, 256, 3600, 256, 512, 256*(1-L),
        XS1, 8192, 1800, 600);
    gru_big_k<<<dim3(15,8,2),192,0,stream>>>(XS0, XS1, art_Whh, art_bhh,
        HBUF, MFA, 1200, CTRS + (size_t)L*16*CTR_STRIDE,
        512, 256, 256*L, 600, 40, 604, 15, 600);
  }
  logits_k<<<32,128,0,stream>>>(MFA, nullptr, nullptr, 1200, W_article, b_article, NAn, 1200, OUTA);
  argmax_k<<<1,64,0,stream>>>(OUTA, NAn, PREDA);

  // --- fact_sep #2 (context = sec_vector) ---
  vtok_k<<<7,256,0,stream>>>(arVerd, PREDA, VTOK, LVn);
  {
    dim3 g((900+127)/128, (1600+127)/128);
    gemm_k<1><<<g,256,0,stream>>>(nullptr,nullptr,nullptr, E, VTOK,
        enc_Wih, 200, 0,0,0, enc_bih, nullptr, 1, 1, IDIV,0,0,
        XS0, 1600, 900, 200);
  }
  gru_small_k<<<dim3(32,2),192,0,stream>>>(XS0, 900, enc_Whh, enc_bhh, VHYS, nullptr, 50);
  mask_att_k<<<dim3(64,32),256,0,stream>>>(SEC, VHYS, SSC, ADC);   // ssc, dsc(=ADC)

  // --- term bigru, time-sliced dual-dir chunks ---
  hipMemsetAsync(MTH, 0, 28800*4, stream);
  for (int L = 0; L < 2; L++){
    dim3 g((1350+127)/128, 64);
    gemm_k<0><<<g,256,0,stream>>>(DH, SSC, ADC, nullptr, nullptr,
        term_Wih, 900, 0, 300, 600,
        term_bih, nullptr, 1, 1, 256, 512, 256*L,
        XS0, 8192, 1350, 900);
    gemm_k<0><<<g,256,0,stream>>>(DH, SSC, ADC, nullptr, nullptr,
        term_Wih + (size_t)1350*900, 900, 0, 300, 600,
        term_bih + 1350, nullptr, 1, 1, 256, 512, 256*(1-L),
        XS1, 8192, 1350, 900);
    gru_big_k<<<dim3(10,8,2),192,0,stream>>>(XS0, XS1, term_Whh, term_bhh,
        HBUF, MTH, 900, CTRS + (size_t)(2+L)*16*CTR_STRIDE,
        512, 256, 256*L, 450, 45, 460, 10, 452);
  }
  logits_k<<<32,128,0,stream>>>(MTH, nullptr, nullptr, 900, W_time, b_time, NTn, 900, OUTT);
}

// Round 8
// 22443.901 us; speedup vs baseline: 2.2662x; 1.0220x over previous
//
#include <hip/hip_runtime.h>
#include <stdint.h>
#include <math.h>

typedef unsigned int u32;
typedef _Float16 f16;
typedef _Float16 h4 __attribute__((ext_vector_type(4)));
typedef _Float16 h2 __attribute__((ext_vector_type(2)));

// Problem constants
#define Vn     50000
#define DEMBn  200
#define Hn     150
#define NCn    119
#define NAn    103
#define NTn    11
#define Bn     32
#define Tn     512
#define LCn    50
#define LVn    50
#define ECn    600
#define EAn    500

#define CTR_STRIDE 64   // u32s = 256 B per barrier-group counter region
#define IDIV 1073741824 // identity arow mapping

__device__ __forceinline__ float sigm(float x){ return 1.0f / (1.0f + expf(-x)); }

// f16-pair dot with f32 accumulate (v_dot2_f32_f16); fallback cvt+fma.
#if __has_builtin(__builtin_amdgcn_fdot2)
__device__ __forceinline__ float FDOT2(h2 a, h2 b, float c){
  return __builtin_amdgcn_fdot2(a, b, c, false);
}
#else
__device__ __forceinline__ float FDOT2(h2 a, h2 b, float c){
  return c + (float)a.x*(float)b.x + (float)a.y*(float)b.y;
}
#endif

// LLC-coherent agent-scope ops (sc-flagged, bypass non-coherent L1/L2).
__device__ __forceinline__ float llc_loadf(const float* p){
  u32 v = __hip_atomic_load((const u32*)p, __ATOMIC_RELAXED, __HIP_MEMORY_SCOPE_AGENT);
  union { u32 i; float f; } u; u.i = v; return u.f;
}
__device__ __forceinline__ void llc_storef(float* p, float v){
  union { float f; u32 i; } u; u.f = v;
  __hip_atomic_store((u32*)p, u.i, __ATOMIC_RELAXED, __HIP_MEMORY_SCOPE_AGENT);
}

// ---------------------------------------------------------------------------
// Tiled fp32 GEMM: C[M][N] = A[arow(m)][K] @ B[N][K]^T (+bias +rowbias)
// AMODE 0: A = up to 3 f32 sources, each [...][300]; source s = k/300;
//          B column for element k is bc[s] + (k - s*300).
//          A row = (m/arow_div)*arow_stride + (m%arow_div) + arow_off
// AMODE 1: A[m][k] = Etab[tok[m]][k] (f32 embedding gather), B col = k
// ---------------------------------------------------------------------------
template<int AMODE>
__global__ __launch_bounds__(256)
void gemm_k(const float* A0, const float* A1, const float* A2,
            const float* Etab, const int* tok,
            const float* Bm, int ldb, int bc0, int bc1, int bc2,
            const float* bias, const float* rowbias, int rb_div, int rb_stride,
            int arow_div, int arow_stride, int arow_off,
            float* C, int M, int N, int K)
{
  __shared__ float As[8][132];
  __shared__ float Bs[8][132];
  __shared__ int tokS[128];
  int tid = threadIdx.x;
  int m0 = blockIdx.y * 128, n0 = blockIdx.x * 128;
  if (AMODE == 1){
    for (int i = tid; i < 128; i += 256){
      int m = m0 + i;
      tokS[i] = (m < M) ? tok[m] : 0;
    }
  }
  __syncthreads();
  float acc[8][8];
  #pragma unroll
  for (int i=0;i<8;i++)
    #pragma unroll
    for (int j=0;j<8;j++) acc[i][j] = 0.f;

  int tx = tid & 15, ty = tid >> 4;

  for (int k0 = 0; k0 < K; k0 += 8){
    #pragma unroll
    for (int r = 0; r < 4; r++){
      int i = tid + 256*r;          // [0,1024)
      int ml = i >> 3, kl = i & 7;
      int k = k0 + kl;
      {
        int m = m0 + ml;
        float v = 0.f;
        if (m < M && k < K){
          if (AMODE == 0){
            int s = k / 300; int kk = k - s*300;
            const float* Ap = (s==0) ? A0 : ((s==1) ? A1 : A2);
            int ar = (m / arow_div)*arow_stride + (m % arow_div) + arow_off;
            v = Ap[(size_t)ar*300 + kk];
          } else {
            v = Etab[(size_t)tokS[ml]*DEMBn + k];
          }
        }
        As[kl][ml] = v;
      }
      {
        int n = n0 + ml;
        float v = 0.f;
        if (n < N && k < K){
          int col;
          if (AMODE == 0){ int s = k / 300; int kk = k - s*300; col = ((s==0)?bc0:((s==1)?bc1:bc2)) + kk; }
          else col = k;
          v = Bm[(size_t)n*ldb + col];
        }
        Bs[kl][ml] = v;
      }
    }
    __syncthreads();
    #pragma unroll
    for (int kk = 0; kk < 8; kk++){
      float a[8], b[8];
      #pragma unroll
      for (int i=0;i<8;i++) a[i] = As[kk][ty*8+i];
      #pragma unroll
      for (int i=0;i<8;i++) b[i] = Bs[kk][tx*8+i];
      #pragma unroll
      for (int i=0;i<8;i++)
        #pragma unroll
        for (int j=0;j<8;j++) acc[i][j] += a[i]*b[j];
    }
    __syncthreads();
  }
  #pragma unroll
  for (int i=0;i<8;i++){
    int m = m0 + ty*8 + i; if (m >= M) continue;
    #pragma unroll
    for (int j=0;j<8;j++){
      int n = n0 + tx*8 + j; if (n >= N) continue;
      float v = acc[i][j];
      if (bias)    v += bias[n];
      if (rowbias) v += rowbias[(size_t)(m / rb_div)*rb_stride + n];
      C[(size_t)m*N + n] = v;
    }
  }
}

// ---------------------------------------------------------------------------
// Small-GRU recurrence (H=150): one block per (seq, dir). Whh f16 in LDS.
// ---------------------------------------------------------------------------
__global__ __launch_bounds__(192)
void gru_small_k(const float* xs, int ncols,
                 const float* Whh, const float* bhh,
                 float* ys, float* meanOut, int T)
{
  const int KP = 156;
  __shared__ f16 Wl[3*150*156];     // 140,400 B
  __shared__ float bhl[456];
  __shared__ __align__(16) float hl[152];
  int tid = threadIdx.x;
  int seq = blockIdx.x, dir = blockIdx.y;

  for (int idx = tid; idx < 3*150*150; idx += 192){
    int g = idx / 22500, r = idx % 22500;
    int j = r / 150, k = r % 150;
    Wl[(g*150 + j)*KP + k] = (f16)Whh[(size_t)dir*67500 + idx];
  }
  for (int idx = tid; idx < 450; idx += 192) bhl[idx] = bhh[dir*450 + idx];
  if (tid < 152) hl[tid] = 0.f;
  __syncthreads();

  const f16 *wr = nullptr, *wz = nullptr, *wn = nullptr;
  float bR=0.f, bZ=0.f, bN=0.f;
  if (tid < 150){
    wr = &Wl[(0*150+tid)*KP];
    wz = &Wl[(1*150+tid)*KP];
    wn = &Wl[(2*150+tid)*KP];
    bR = bhl[tid]; bZ = bhl[150+tid]; bN = bhl[300+tid];
  }
  float msum = 0.f;
  size_t rowbase = (size_t)seq * T;
  for (int tt = 0; tt < T; tt++){
    int t = dir ? (T-1-tt) : tt;
    float aR=0.f, aZ=0.f, aN=0.f;
    if (tid < 150){
      for (int k = 0; k < 148; k += 4){
        float4 hv = *(const float4*)(hl + k);
        h4 r4 = *(const h4*)(wr + k);
        h4 z4 = *(const h4*)(wz + k);
        h4 n4 = *(const h4*)(wn + k);
        aR += (float)r4.x*hv.x + (float)r4.y*hv.y + (float)r4.z*hv.z + (float)r4.w*hv.w;
        aZ += (float)z4.x*hv.x + (float)z4.y*hv.y + (float)z4.z*hv.z + (float)z4.w*hv.w;
        aN += (float)n4.x*hv.x + (float)n4.y*hv.y + (float)n4.z*hv.z + (float)n4.w*hv.w;
      }
      {
        float2 hv = *(const float2*)(hl + 148);
        h2 r2 = *(const h2*)(wr + 148);
        h2 z2 = *(const h2*)(wz + 148);
        h2 n2 = *(const h2*)(wn + 148);
        aR += (float)r2.x*hv.x + (float)r2.y*hv.y;
        aZ += (float)z2.x*hv.x + (float)z2.y*hv.y;
        aN += (float)n2.x*hv.x + (float)n2.y*hv.y;
      }
    }
    __syncthreads();           // all reads of hl done
    if (tid < 150){
      const float* xp = xs + (rowbase + t)*(size_t)ncols + dir*450;
      float xr = xp[tid], xz = xp[150+tid], xn = xp[300+tid];
      float rr = sigm(xr + aR + bR);
      float zz = sigm(xz + aZ + bZ);
      float nn = tanhf(xn + rr*(aN + bN));
      float hn = (1.f - zz)*nn + zz*hl[tid];
      hl[tid] = hn;
      msum += hn;
      if (ys) ys[(rowbase + t)*(size_t)300 + dir*150 + tid] = hn;
    }
    __syncthreads();
  }
  if (meanOut && tid < 150)
    meanOut[(size_t)seq*300 + dir*150 + tid] = msum / (float)T;
}

// ---------------------------------------------------------------------------
// Big-GRU recurrence, BOTH dirs per launch (grid NJC x 8 x 2), time-sliced.
// Round-8 changes:
//  - gemv uses v_dot2_f32_f16 (f32 accum) with h staged as f16 in LDS —
//    removes all f16->f32 cvts (half the gemv VALU ops) and halves LDS
//    read width (fewer bank conflicts).
//  - recurrence leak term z*h_old uses an EXACT f32 register copy of the
//    thread's own h (same (j,batch) ownership every step; re-seeded from
//    hbuf at chunk boundaries) — state is never quantized.
//  - per-wave barrier: each wave drains its own stores, lane0-of-wave does
//    fetch_add + poll (target NW*NJC*(tt+1)); NO block syncthreads around
//    the barrier (safe: a wave adds only after its gemv reads are done).
// ---------------------------------------------------------------------------
__global__ __launch_bounds__(192)
void gru_big_k(const float* xs0, const float* xs1,
               const float* Whh,         // [2][3*Hh][Hh]
               const float* bhh,         // [2][3*Hh]
               float* hbuf,              // [2][2][B][Hh]
               float* meanOut, int mean_stride,   // += msum/TT at col dir*Hh+j
               u32* counters,            // 16 x CTR_STRIDE u32, zeroed
               int TT, int TC, int t0,
               int Hh, int JB, int KPAD, int NJC, int HS)
{
  __shared__ f16 Wl[72480];                 // 144,960 B (art: 3*40*604)
  __shared__ float bhl[136];
  __shared__ __align__(16) f16 hstage[2400];
  int tid = threadIdx.x;
  int jc = blockIdx.x, bg = blockIdx.y, dir = blockIdx.z;
  int j0 = jc * JB;
  int H3 = 3 * Hh;
  const int NW = 3;                         // waves per block (192/64)
  const float* Wd = Whh + (size_t)dir*H3*Hh;
  const float* bd = bhh + (size_t)dir*H3;
  const float* xs = dir ? xs1 : xs0;
  int xoff = dir ? (TT - TC - t0) : t0;

  for (int idx = tid; idx < 3*JB*Hh; idx += 192){
    int row = idx / Hh, k = idx - row*Hh;
    int g = row / JB, jj = row - g*JB;
    Wl[row*KPAD + k] = (f16)Wd[((size_t)g*Hh + j0 + jj)*(size_t)Hh + k];
  }
  for (int idx = tid; idx < 3*JB; idx += 192){
    int g = idx / JB, jj = idx - g*JB;
    bhl[idx] = bd[g*Hh + j0 + jj];
  }
  __syncthreads();

  u32* cnt = counters + (size_t)(dir*8 + bg) * CTR_STRIDE;
  int cj = tid >> 2, ckq = tid & 3;
  bool comp = (cj < JB);
  int k0 = 0, k1 = 0;
  if (comp){
    k0 = (ckq == 0) ? 0 : ((ckq*Hh/4) & ~3);
    k1 = (ckq == 3) ? Hh : ((((ckq+1)*Hh)/4) & ~3);
  }
  float br = 0.f, bz = 0.f, bn_ = 0.f;
  if (comp && ckq == 0){
    br = bhl[cj]; bz = bhl[JB+cj]; bn_ = bhl[2*JB+cj];
  }
  float msum[4] = {0.f, 0.f, 0.f, 0.f};
  int jg = j0 + cj;
  int HT = 4*Hh;                 // h elems per bgroup (2400 art / 1800 term)

  // exact f32 h_old for owned (jg, s): seed from hbuf at chunk boundary
  float hold[4] = {0.f, 0.f, 0.f, 0.f};
  if (t0 > 0 && comp && ckq == 0){
    const float* hseed = hbuf + (size_t)((t0 & 1)*2 + dir)*Bn*Hh;
    #pragma unroll
    for (int s=0;s<4;s++) hold[s] = llc_loadf(&hseed[(size_t)(bg*4+s)*Hh + jg]);
  }

  for (int tt = 0; tt < TC; tt++){
    int g = t0 + tt;                       // global step index
    int t = dir ? (TT-1-g) : g;            // time position consumed
    int par = g & 1;
    const float* hrd = hbuf + (size_t)(par*2 + dir)*Bn*Hh;
    float*       hwr = hbuf + (size_t)((1-par)*2 + dir)*Bn*Hh;

    // xs prefetch (h-independent): issue before the gemv to hide HBM latency
    float xr[4], xz[4], xn[4];
    if (comp && ckq == 0){
      #pragma unroll
      for (int s=0;s<4;s++){
        const float* xp = xs + ((size_t)(bg*4+s)*TC + (t - xoff))*(size_t)H3;
        xr[s] = xp[jg]; xz[s] = xp[Hh+jg]; xn[s] = xp[2*Hh+jg];
      }
    }

    // h staging: batched loads (all in flight), then f16 LDS writes
    if (g == 0){
      for (int idx = tid; idx < HT; idx += 192){
        int s = idx / Hh, k = idx - s*Hh;
        hstage[s*HS + k] = (f16)0.f;
      }
    } else {
      float tmp[13];
      const float* hb = hrd + (size_t)(bg*4)*Hh;   // rows contiguous
      #pragma unroll
      for (int r = 0; r < 13; r++){
        int idx = tid + r*192;
        if (idx < HT) tmp[r] = llc_loadf(&hb[idx]);
      }
      #pragma unroll
      for (int r = 0; r < 13; r++){
        int idx = tid + r*192;
        if (idx < HT){ int s = idx / Hh, k = idx - s*Hh; hstage[s*HS + k] = (f16)tmp[r]; }
      }
    }
    __syncthreads();       // staging visible to all waves before gemv
    float a0[4] = {0,0,0,0}, a1[4] = {0,0,0,0}, a2[4] = {0,0,0,0};
    if (comp){
      const f16* pr = &Wl[(0*JB+cj)*KPAD];
      const f16* pz = &Wl[(1*JB+cj)*KPAD];
      const f16* pn = &Wl[(2*JB+cj)*KPAD];
      int k = k0;
      for (; k + 4 <= k1; k += 4){
        h4 r4 = *(const h4*)(pr + k);
        h4 z4 = *(const h4*)(pz + k);
        h4 n4 = *(const h4*)(pn + k);
        h2 rlo = {r4.x, r4.y}, rhi = {r4.z, r4.w};
        h2 zlo = {z4.x, z4.y}, zhi = {z4.z, z4.w};
        h2 nlo = {n4.x, n4.y}, nhi = {n4.z, n4.w};
        #pragma unroll
        for (int s=0;s<4;s++){
          h4 hv = *(const h4*)(hstage + s*HS + k);
          h2 hlo = {hv.x, hv.y}, hhi = {hv.z, hv.w};
          a0[s] = FDOT2(rlo, hlo, a0[s]); a0[s] = FDOT2(rhi, hhi, a0[s]);
          a1[s] = FDOT2(zlo, hlo, a1[s]); a1[s] = FDOT2(zhi, hhi, a1[s]);
          a2[s] = FDOT2(nlo, hlo, a2[s]); a2[s] = FDOT2(nhi, hhi, a2[s]);
        }
      }
      for (; k < k1; k++){
        float wr0=(float)pr[k], wz0=(float)pz[k], wn0=(float)pn[k];
        #pragma unroll
        for (int s=0;s<4;s++){
          float hv = (float)hstage[s*HS + k];
          a0[s] += wr0*hv; a1[s] += wz0*hv; a2[s] += wn0*hv;
        }
      }
    }
    // quad reduction over ckq lanes (quads never straddle waves)
    #pragma unroll
    for (int s=0;s<4;s++){
      a0[s] += __shfl_xor(a0[s], 1); a0[s] += __shfl_xor(a0[s], 2);
      a1[s] += __shfl_xor(a1[s], 1); a1[s] += __shfl_xor(a1[s], 2);
      a2[s] += __shfl_xor(a2[s], 1); a2[s] += __shfl_xor(a2[s], 2);
    }
    if (comp && ckq == 0){
      #pragma unroll
      for (int s=0;s<4;s++){
        int b = bg*4 + s;
        float rr = sigm(xr[s] + a0[s] + br);
        float zz = sigm(xz[s] + a1[s] + bz);
        float nn = tanhf(xn[s] + rr*(a2[s] + bn_));
        float hn = (1.f - zz)*nn + zz*hold[s];
        hold[s] = hn;
        llc_storef(&hwr[(size_t)b*Hh + jg], hn);
        msum[s] += hn;
      }
    }
    // per-wave barrier: drain own stores, add, poll (no block syncthreads)
    __builtin_amdgcn_s_waitcnt(0);
    u32 target = (u32)(NW*NJC) * (u32)(tt+1);
    if ((tid & 63) == 0){
      __hip_atomic_fetch_add(cnt, 1u, __ATOMIC_RELAXED, __HIP_MEMORY_SCOPE_AGENT);
      int guard = 0;
      while (__hip_atomic_load(cnt, __ATOMIC_RELAXED, __HIP_MEMORY_SCOPE_AGENT) < target){
        __builtin_amdgcn_s_sleep(2);
        if (++guard > 2000000) break;   // failsafe: wrong result > GPU hang
      }
    }
  }
  if (comp && ckq == 0){
    #pragma unroll
    for (int s=0;s<4;s++){
      float* mp = meanOut + (size_t)(bg*4+s)*mean_stride + dir*Hh + jg;
      *mp += msum[s] / (float)TT;
    }
  }
}

// ---------------------------------------------------------------------------
// mask_att + fact_sep fused: per (b, 8-t chunk).
// ---------------------------------------------------------------------------
__global__ __launch_bounds__(256)
void mask_att_k(const float* ctx, const float* vh, float* simOut, float* diffOut)
{
  __shared__ float vhl[50*300];
  __shared__ float ctxl[8*300];
  __shared__ float attl[8*52];
  __shared__ float scenl[8*300];
  __shared__ float ratio[8];
  int tid = threadIdx.x;
  int b = blockIdx.y, tc = blockIdx.x;
  size_t cbase = ((size_t)b*Tn + tc*8) * 300;
  for (int i = tid; i < 15000; i += 256) vhl[i] = vh[(size_t)b*15000 + i];
  for (int i = tid; i < 2400; i += 256)  ctxl[i] = ctx[cbase + i];
  __syncthreads();
  for (int p = tid; p < 400; p += 256){
    int ttl = p / 50, v = p % 50;
    const float* cp = ctxl + ttl*300;
    const float* vp = vhl + v*300;
    float acc = 0.f;
    for (int d = 0; d < 300; d++) acc += cp[d]*vp[d];
    attl[ttl*52 + v] = acc;
  }
  __syncthreads();
  if (tid < 8){
    float mx = -INFINITY;
    for (int v=0; v<50; v++){
      float a = attl[tid*52+v];
      float msk = (a == 0.f) ? -INFINITY : a;
      attl[tid*52+v] = msk;
      mx = fmaxf(mx, msk);
    }
    if (mx == -INFINITY){
      for (int v=0; v<50; v++) attl[tid*52+v] = 0.f;
    } else {
      float sum = 0.f;
      for (int v=0; v<50; v++){ float e = expf(attl[tid*52+v] - mx); attl[tid*52+v] = e; sum += e; }
      float inv = 1.f/sum;
      for (int v=0; v<50; v++) attl[tid*52+v] *= inv;
    }
  }
  __syncthreads();
  for (int p = tid; p < 2400; p += 256){
    int ttl = p / 300, d = p % 300;
    float acc = 0.f;
    for (int v=0; v<50; v++) acc += attl[ttl*52+v] * vhl[v*300+d];
    scenl[p] = acc;
  }
  __syncthreads();
  if (tid < 8){
    float x3=0.f, x4=0.f;
    for (int d=0; d<300; d++){ float s = scenl[tid*300+d]; x3 += ctxl[tid*300+d]*s; x4 += s*s; }
    ratio[tid] = x3 / (x4 + 1e-10f);
  }
  __syncthreads();
  for (int p = tid; p < 2400; p += 256){
    float sim = ratio[p/300] * scenl[p];
    simOut[cbase + p]  = sim;
    diffOut[cbase + p] = ctxl[p] - sim;
  }
}

// ---------------------------------------------------------------------------
// code_wise helpers
// ---------------------------------------------------------------------------
__global__ void rowmax_k(const float* S, float* out, int M, int N){
  int row = blockIdx.x*4 + (threadIdx.x >> 6);
  int lane = threadIdx.x & 63;
  if (row >= M) return;
  float mx = -INFINITY;
  for (int n = lane; n < N; n += 64) mx = fmaxf(mx, S[(size_t)row*N + n]);
  for (int off = 32; off; off >>= 1) mx = fmaxf(mx, __shfl_xor(mx, off, 64));
  if (lane == 0) out[row] = mx;
}

__global__ __launch_bounds__(256)
void softmaxT_k(const float* m, float* att){
  __shared__ float red[256];
  int b = blockIdx.x, tid = threadIdx.x;
  float v1 = m[b*512 + tid], v2 = m[b*512 + 256 + tid];
  red[tid] = fmaxf(v1, v2); __syncthreads();
  for (int s=128; s; s>>=1){ if (tid<s) red[tid] = fmaxf(red[tid], red[tid+s]); __syncthreads(); }
  float M = red[0]; __syncthreads();
  float e1 = expf(v1-M), e2 = expf(v2-M);
  red[tid] = e1+e2; __syncthreads();
  for (int s=128; s; s>>=1){ if (tid<s) red[tid] += red[tid+s]; __syncthreads(); }
  float inv = 1.f / red[0];
  att[b*512+tid] = e1*inv; att[b*512+256+tid] = e2*inv;
}

__global__ __launch_bounds__(256)
void wsum_k(const float* att, const float* dh, float* out){
  int b = blockIdx.x, tid = threadIdx.x;
  for (int d = tid; d < 300; d += 256){
    float acc = 0.f;
    for (int t = 0; t < 512; t++)
      acc += att[b*512+t] * dh[((size_t)b*512 + t)*300 + d];
    out[b*300+d] = acc;
  }
}

// ---------------------------------------------------------------------------
// graph_decomp helpers
// ---------------------------------------------------------------------------
__global__ void count_k(const int* src, int E, float* counts){
  int e = blockIdx.x*256 + threadIdx.x;
  if (e < E) atomicAdd(&counts[src[e]], 1.f);
}
__global__ void coef_k(const float* L, const int* src, const int* dst, int E, float* coef){
  int e = blockIdx.x*4 + (threadIdx.x >> 6);
  int lane = threadIdx.x & 63;
  if (e >= E) return;
  const float* Li = L + (size_t)src[e]*300;
  const float* Lj = L + (size_t)dst[e]*300;
  float num = 0.f, den = 0.f;
  for (int d = lane; d < 300; d += 64){ float lj = Lj[d]; num += Li[d]*lj; den += lj*lj; }
  for (int off = 32; off; off >>= 1){ num += __shfl_xor(num, off, 64); den += __shfl_xor(den, off, 64); }
  if (lane == 0) coef[e] = num / (den + 1e-10f);
}
__global__ void agg_k(const float* L, const int* src, const int* dst, const float* coef, int E, float* agg){
  int e = blockIdx.x;
  float c = coef[e];
  const float* Lj = L + (size_t)dst[e]*300;
  float* ag = agg + (size_t)src[e]*300;
  for (int d = threadIdx.x; d < 300; d += 256) atomicAdd(&ag[d], c*Lj[d]);
}
__global__ void upd_k(const float* L, const float* agg, const float* counts, float* out, int n){
  int i = blockIdx.x;
  float c = counts[i];
  for (int d = threadIdx.x; d < 300; d += 256){
    float v = L[(size_t)i*300+d];
    out[(size_t)i*300+d] = (c > 0.f) ? v - agg[(size_t)i*300+d]/fmaxf(c, 1.f) : v;
  }
}

// ---------------------------------------------------------------------------
// classifier heads (write f32 logits straight into d_out), argmax, gather
// ---------------------------------------------------------------------------
__global__ __launch_bounds__(128)
void logits_k(const float* A0, const float* A1, const float* A2, int srcw,
              const float* W, const float* bias, int C, int K,
              float* outF){
  int b = blockIdx.x, tid = threadIdx.x;
  for (int c = tid; c < C; c += 128){
    float acc = bias[c];
    const float* wp = W + (size_t)c*K;
    for (int k = 0; k < K; k++){
      int s = k / srcw; int kk = k - s*srcw;
      const float* Ap = (s==0) ? A0 : ((s==1) ? A1 : A2);
      acc += Ap[(size_t)b*srcw + kk] * wp[k];
    }
    outF[b*C + c] = acc;
  }
}
__global__ void argmax_k(const float* lf, int C, int* pred){
  int b = threadIdx.x;
  if (b < 32){
    const float* p = lf + (size_t)b*C;
    int best = 0; float bv = p[0];
    for (int c = 1; c < C; c++){ float v = p[c]; if (v > bv){ bv = v; best = c; } }
    pred[b] = best;
  }
}
__global__ void vtok_k(const int* table, const int* pred, int* vt, int L){
  int i = blockIdx.x*256 + threadIdx.x;
  if (i < 32*L) vt[i] = table[pred[i/L]*L + i%L];
}

// ---------------------------------------------------------------------------
extern "C" void kernel_launch(void* const* d_in, const int* in_sizes, int n_in,
                              void* d_out, int out_size, void* d_ws, size_t ws_size,
                              hipStream_t stream)
{
  (void)in_sizes; (void)n_in; (void)out_size;
  const float* E        = (const float*)d_in[0];
  const int* chTok    = (const int*)d_in[1];
  const int* arTok    = (const int*)d_in[2];
  const int* docs     = (const int*)d_in[3];
  const int* chVerd   = (const int*)d_in[4];
  const int* arVerd   = (const int*)d_in[5];
  const int* c_src    = (const int*)d_in[6];
  const int* c_dst    = (const int*)d_in[7];
  const int* a_src    = (const int*)d_in[8];
  const int* a_dst    = (const int*)d_in[9];
  const float* enc_Wih  = (const float*)d_in[10];
  const float* enc_Whh  = (const float*)d_in[11];
  const float* enc_bih  = (const float*)d_in[12];
  const float* enc_bhh  = (const float*)d_in[13];
  const float* ech_Wih  = (const float*)d_in[14];
  const float* ech_Whh  = (const float*)d_in[15];
  const float* ech_bih  = (const float*)d_in[16];
  const float* ech_bhh  = (const float*)d_in[17];
  const float* term_Wih = (const float*)d_in[18];
  const float* term_Whh = (const float*)d_in[19];
  const float* term_bih = (const float*)d_in[20];
  const float* term_bhh = (const float*)d_in[21];
  const float* art_Wih  = (const float*)d_in[22];
  const float* art_Whh  = (const float*)d_in[23];
  const float* art_bih  = (const float*)d_in[24];
  const float* art_bhh  = (const float*)d_in[25];
  const float* W_charge = (const float*)d_in[26];
  const float* b_charge = (const float*)d_in[27];
  const float* W_article= (const float*)d_in[28];
  const float* b_article= (const float*)d_in[29];
  const float* W_time   = (const float*)d_in[30];
  const float* b_time   = (const float*)d_in[31];
  float* out = (float*)d_out;
  float* OUTC = out;            // [32][119]
  float* OUTA = out + 3808;     // [32][103]
  float* OUTT = out + 7104;     // [32][11]

  char* wsb = (char*)d_ws;
  size_t off = 0;
  auto alloc = [&](size_t nf)->float* {
    float* p = (float*)(wsb + off);
    off += ((nf*4 + 255) & ~(size_t)255);
    return p;
  };
  float* XS0   = alloc(14745600ULL);        // 59.0 MB
  float* XS1   = alloc(14745600ULL);        // 59.0 MB
  float* SBUF  = XS0;                       // alias: disjoint lifetime
  float* DH    = alloc(4915200);            // d_hidden [32][512][300]
  float* ADC   = alloc(4915200);            // adc, later dsc
  float* SEC   = alloc(4915200);
  float* SSC   = alloc(4915200);
  float* VHYS  = alloc(480000);             // [32][50][300]
  float* MECH  = alloc(66600);              // encch means [222][300]
  float* LC1   = alloc(35700);
  float* LC0   = alloc(35700);
  float* LA1   = alloc(30900);
  float* LA0   = alloc(30900);
  float* AGG   = alloc(35700);
  float* CNTS  = alloc(256);                // counts_c @0, counts_a @128
  float* COEF  = alloc(640);
  float* DHC   = alloc(9600);
  float* DA    = alloc(9600);
  float* DHNA  = alloc(9600);
  float* DB    = alloc(9600);
  float* MDH   = alloc(9600);               // mean_t d_hidden [32][300]
  float* MFA   = alloc(38400);              // fa mean [32][1200] (accumulated)
  float* MTH   = alloc(28800);              // th mean [32][900] (accumulated)
  float* RB    = alloc(115200);             // art rowbias [32][3600]
  float* RMX   = alloc(16384);
  float* ATTB  = alloc(16384);
  float* HBUF  = alloc(76800);              // [2][2][32][600]
  u32*   CTRS  = (u32*)alloc(4*16*CTR_STRIDE);  // 4 gru launches x 16 groups
  int*   PREDC = (int*)alloc(64);
  int*   PREDA = (int*)alloc(64);
  int*   VTOK  = (int*)alloc(1600);
  int*   TCC   = (int*)alloc(11104);

  if (off > ws_size) return;   // diagnostic: leaves out==0 -> absmax==max|ref|

  hipMemsetAsync(CTRS, 0, 4*16*CTR_STRIDE*4, stream);
  hipMemsetAsync(CNTS, 0, 256*4, stream);

  // --- encch on charge+article token sequences (222 seqs, L=50) ---
  hipMemcpyAsync(TCC, chTok, NCn*LCn*4, hipMemcpyDeviceToDevice, stream);
  hipMemcpyAsync(TCC + NCn*LCn, arTok, NAn*LCn*4, hipMemcpyDeviceToDevice, stream);
  {
    dim3 g((900+127)/128, (11100+127)/128);
    gemm_k<1><<<g,256,0,stream>>>(nullptr,nullptr,nullptr, E, TCC,
        ech_Wih, 200, 0,0,0, ech_bih, nullptr, 1, 1, IDIV,0,0,
        XS0, 11100, 900, 200);
  }
  gru_small_k<<<dim3(222,2),192,0,stream>>>(XS0, 900, ech_Whh, ech_bhh, nullptr, MECH, 50);

  // --- enc on documents ---
  {
    dim3 g((900+127)/128, (16384+127)/128);
    gemm_k<1><<<g,256,0,stream>>>(nullptr,nullptr,nullptr, E, docs,
        enc_Wih, 200, 0,0,0, enc_bih, nullptr, 1, 1, IDIV,0,0,
        XS0, 16384, 900, 200);
  }
  gru_small_k<<<dim3(32,2),192,0,stream>>>(XS0, 900, enc_Whh, enc_bhh, DH, MDH, 512);

  // --- graph_decomp (charge, article), 2 layers each ---
  count_k<<<3,256,0,stream>>>(c_src, ECn, CNTS);
  count_k<<<2,256,0,stream>>>(a_src, EAn, CNTS+128);
  coef_k<<<150,256,0,stream>>>(MECH, c_src, c_dst, ECn, COEF);
  hipMemsetAsync(AGG, 0, 35700*4, stream);
  agg_k<<<ECn,256,0,stream>>>(MECH, c_src, c_dst, COEF, ECn, AGG);
  upd_k<<<NCn,256,0,stream>>>(MECH, AGG, CNTS, LC1, NCn);
  coef_k<<<150,256,0,stream>>>(LC1, c_src, c_dst, ECn, COEF);
  hipMemsetAsync(AGG, 0, 35700*4, stream);
  agg_k<<<ECn,256,0,stream>>>(LC1, c_src, c_dst, COEF, ECn, AGG);
  upd_k<<<NCn,256,0,stream>>>(LC1, AGG, CNTS, LC0, NCn);

  const float* MEAR = MECH + (size_t)NCn*300;
  coef_k<<<125,256,0,stream>>>(MEAR, a_src, a_dst, EAn, COEF);
  hipMemsetAsync(AGG, 0, 30900*4, stream);
  agg_k<<<EAn,256,0,stream>>>(MEAR, a_src, a_dst, COEF, EAn, AGG);
  upd_k<<<NAn,256,0,stream>>>(MEAR, AGG, CNTS+128, LA1, NAn);
  coef_k<<<125,256,0,stream>>>(LA1, a_src, a_dst, EAn, COEF);
  hipMemsetAsync(AGG, 0, 30900*4, stream);
  agg_k<<<EAn,256,0,stream>>>(LA1, a_src, a_dst, COEF, EAn, AGG);
  upd_k<<<NAn,256,0,stream>>>(LA1, AGG, CNTS+128, LA0, NAn);

  // --- code_wise x4 (S-buffer aliased into XS0) ---
  auto codewise = [&](const float* q, int Nq, float* outv){
    dim3 g((Nq+127)/128, 128);
    gemm_k<0><<<g,256,0,stream>>>(DH, nullptr, nullptr, nullptr, nullptr,
        q, 300, 0,0,0, nullptr, nullptr, 1, 1, IDIV,0,0,
        SBUF, 16384, Nq, 300);
    rowmax_k<<<4096,256,0,stream>>>(SBUF, RMX, 16384, Nq);
    softmaxT_k<<<32,256,0,stream>>>(RMX, ATTB);
    wsum_k<<<32,256,0,stream>>>(ATTB, DH, outv);
  };
  codewise(LC0,  NCn, DHC);    // new_charge
  codewise(MECH, NCn, DA);     // ori charge
  codewise(LA0,  NAn, DHNA);   // new_article
  codewise(MEAR, NAn, DB);     // ori article

  // --- charge head ---
  logits_k<<<32,128,0,stream>>>(MDH, DHC, DA, 300, W_charge, b_charge, NCn, 900, OUTC);
  argmax_k<<<1,64,0,stream>>>(OUTC, NCn, PREDC);

  // --- fact_sep #1 ---
  vtok_k<<<7,256,0,stream>>>(chVerd, PREDC, VTOK, LVn);
  {
    dim3 g((900+127)/128, (1600+127)/128);
    gemm_k<1><<<g,256,0,stream>>>(nullptr,nullptr,nullptr, E, VTOK,
        enc_Wih, 200, 0,0,0, enc_bih, nullptr, 1, 1, IDIV,0,0,
        XS0, 1600, 900, 200);
  }
  gru_small_k<<<dim3(32,2),192,0,stream>>>(XS0, 900, enc_Whh, enc_bhh, VHYS, nullptr, 50);
  mask_att_k<<<dim3(64,32),256,0,stream>>>(DH, VHYS, ADC, SEC);

  // --- article bigru: rowbias, then time-sliced dual-dir chunks ---
  {
    dim3 g((3600+127)/128, 1);
    gemm_k<0><<<g,256,0,stream>>>(DHNA, DB, nullptr, nullptr, nullptr,
        art_Wih, 1200, 300, 900, 0, art_bih, nullptr, 1, 1, IDIV,0,0,
        RB, 32, 3600, 600);
  }
  hipMemsetAsync(MFA, 0, 38400*4, stream);
  for (int L = 0; L < 2; L++){
    dim3 g((1800+127)/128, 64);
    gemm_k<0><<<g,256,0,stream>>>(DH, ADC, nullptr, nullptr, nullptr,
        art_Wih, 1200, 0, 600, 0,
        nullptr, RB, 256, 3600, 256, 512, 256*L,
        XS0, 8192, 1800, 600);
    gemm_k<0><<<g,256,0,stream>>>(DH, ADC, nullptr, nullptr, nullptr,
        art_Wih + (size_t)1800*1200, 1200, 0, 600, 0,
        nullptr, RB + 1800, 256, 3600, 256, 512, 256*(1-L),
        XS1, 8192, 1800, 600);
    gru_big_k<<<dim3(15,8,2),192,0,stream>>>(XS0, XS1, art_Whh, art_bhh,
        HBUF, MFA, 1200, CTRS + (size_t)L*16*CTR_STRIDE,
        512, 256, 256*L, 600, 40, 604, 15, 600);
  }
  logits_k<<<32,128,0,stream>>>(MFA, nullptr, nullptr, 1200, W_article, b_article, NAn, 1200, OUTA);
  argmax_k<<<1,64,0,stream>>>(OUTA, NAn, PREDA);

  // --- fact_sep #2 (context = sec_vector) ---
  vtok_k<<<7,256,0,stream>>>(arVerd, PREDA, VTOK, LVn);
  {
    dim3 g((900+127)/128, (1600+127)/128);
    gemm_k<1><<<g,256,0,stream>>>(nullptr,nullptr,nullptr, E, VTOK,
        enc_Wih, 200, 0,0,0, enc_bih, nullptr, 1, 1, IDIV,0,0,
        XS0, 1600, 900, 200);
  }
  gru_small_k<<<dim3(32,2),192,0,stream>>>(XS0, 900, enc_Whh, enc_bhh, VHYS, nullptr, 50);
  mask_att_k<<<dim3(64,32),256,0,stream>>>(SEC, VHYS, SSC, ADC);   // ssc, dsc(=ADC)

  // --- term bigru, time-sliced dual-dir chunks ---
  hipMemsetAsync(MTH, 0, 28800*4, stream);
  for (int L = 0; L < 2; L++){
    dim3 g((1350+127)/128, 64);
    gemm_k<0><<<g,256,0,stream>>>(DH, SSC, ADC, nullptr, nullptr,
        term_Wih, 900, 0, 300, 600,
        term_bih, nullptr, 1, 1, 256, 512, 256*L,
        XS0, 8192, 1350, 900);
    gemm_k<0><<<g,256,0,stream>>>(DH, SSC, ADC, nullptr, nullptr,
        term_Wih + (size_t)1350*900, 900, 0, 300, 600,
        term_bih + 1350, nullptr, 1, 1, 256, 512, 256*(1-L),
        XS1, 8192, 1350, 900);
    gru_big_k<<<dim3(10,8,2),192,0,stream>>>(XS0, XS1, term_Whh, term_bhh,
        HBUF, MTH, 900, CTRS + (size_t)(2+L)*16*CTR_STRIDE,
        512, 256, 256*L, 450, 45, 460, 10, 452);
  }
  logits_k<<<32,128,0,stream>>>(MTH, nullptr, nullptr, 900, W_time, b_time, NTn, 900, OUTT);
}